// Round 2
// baseline (508.292 us; speedup 1.0000x reference)
//
#include <hip/hip_runtime.h>
#include <hip/hip_bf16.h>

#define NNODES 32768
#define DEG 16

__device__ __forceinline__ float sigmoidf_(float x) { return 1.f / (1.f + __expf(-x)); }
__device__ __forceinline__ float tanhf_(float x) { return 1.f - 2.f / (__expf(2.f * x) + 1.f); }

typedef __attribute__((ext_vector_type(8))) short bf16x8;
typedef __attribute__((ext_vector_type(4))) float f32x4;

__device__ __forceinline__ unsigned short f2bf_(float x) {
  __hip_bfloat16 b = __float2bfloat16(x);
  union { __hip_bfloat16 b; unsigned short u; } cv;
  cv.b = b;
  return cv.u;
}
__device__ __forceinline__ float bf2f_(unsigned short u) {
  union { unsigned short u; __hip_bfloat16 b; } cv;
  cv.u = u;
  return __bfloat162float(cv.b);
}
__device__ __forceinline__ void pack_hilo_(const float* v, bf16x8& hi, bf16x8& lo) {
#pragma unroll
  for (int j = 0; j < 8; j++) {
    unsigned short h = f2bf_(v[j]);
    float resid = v[j] - bf2f_(h);
    hi[j] = (short)h;
    lo[j] = (short)f2bf_(resid);
  }
}

// Packed-weight offsets (shorts); hi block then lo block per matrix.
#define WP_G1    0        // 3 x (128x128): stride 32768
#define WP_G2    98304    // 3 x (128x32):  stride 8192
#define WP_S2WIH 122880   // 32x128 (transposed use)
#define WP_TOTAL 131072

// ===========================================================================
// Device bodies (byte-identical arithmetic to the round-0 PASSING kernels;
// only the block-index parameter is abstracted so bodies can be grid-fused).
// ===========================================================================

// --- GATv2 H=4 body (R0-exact) ---
__device__ __forceinline__ void gat4_body(int vbid, const float* __restrict__ fs,
                                          const float* __restrict__ fd,
                                          const float* __restrict__ lin,
                                          const int* __restrict__ src,
                                          const float* __restrict__ attn,
                                          const float* __restrict__ bias,
                                          float* __restrict__ out) {
  constexpr int F = 128;
  const int lane = threadIdx.x & 63;
  const int wave = threadIdx.x >> 6;
  const int li = lane & 15;
  const int node = vbid * 4 + wave;
  const int f0 = 2 * lane;
  const int srcv = src[(size_t)node * DEG + li];
  const float2 fdv = *(const float2*)&fd[(size_t)node * F + f0];
  const float a0 = attn[f0];
  const float a1 = attn[f0 + 1];
  float m = -1e30f, s = 0.f, acc0 = 0.f, acc1 = 0.f;
  int sd = __shfl(srcv, (lane & 48), 64);
  float2 fsv = *(const float2*)&fs[(size_t)sd * F + f0];
#pragma unroll
  for (int d = 0; d < DEG; d++) {
    float2 cur = fsv;
    if (d < DEG - 1) {
      int sn = __shfl(srcv, (lane & 48) | (d + 1), 64);
      fsv = *(const float2*)&fs[(size_t)sn * F + f0];
    }
    float e0 = cur.x + fdv.x; e0 = (e0 > 0.f) ? e0 : 0.2f * e0;
    float e1 = cur.y + fdv.y; e1 = (e1 > 0.f) ? e1 : 0.2f * e1;
    float p = e0 * a0 + e1 * a1;
    p += __shfl_xor(p, 1, 64);
    p += __shfl_xor(p, 2, 64);
    p += __shfl_xor(p, 4, 64);
    p += __shfl_xor(p, 8, 64);
    float nm = fmaxf(m, p);
    float ex = __expf(p - nm);
    float sc = __expf(m - nm);
    s = s * sc + ex;
    acc0 = acc0 * sc + ex * cur.x;
    acc1 = acc1 * sc + ex * cur.y;
    m = nm;
  }
  float inv = 1.f / s;
  float2 lv = *(const float2*)&lin[(size_t)node * F + f0];
  float o0 = acc0 * inv + lv.x + bias[f0];
  float o1 = acc1 * inv + lv.y + bias[f0 + 1];
  o0 = (o0 > 0.f) ? o0 : __expf(o0) - 1.f;
  o1 = (o1 > 0.f) ? o1 : __expf(o1) - 1.f;
  *(float2*)&out[(size_t)node * F + f0] = make_float2(o0, o1);
}

// --- GATv2 H=1 body (no ELU, R0-exact) ---
__device__ __forceinline__ void gat1_body(int vbid, const float* __restrict__ fs,
                                          const float* __restrict__ fd,
                                          const float* __restrict__ lin,
                                          const int* __restrict__ src,
                                          const float* __restrict__ attn,
                                          const float* __restrict__ bias,
                                          float* __restrict__ out) {
  constexpr int F = 32;
  const int lane = threadIdx.x & 63;
  const int wave = threadIdx.x >> 6;
  const int G = lane >> 4, li = lane & 15;
  const int node = vbid * 16 + wave * 4 + G;
  const int f0 = 2 * li;
  const int srcv = src[(size_t)node * DEG + li];
  const float2 fdv = *(const float2*)&fd[(size_t)node * F + f0];
  const float a0 = attn[f0];
  const float a1 = attn[f0 + 1];
  float m = -1e30f, s = 0.f, acc0 = 0.f, acc1 = 0.f;
  int sd = __shfl(srcv, (lane & 48), 64);
  float2 fsv = *(const float2*)&fs[(size_t)sd * F + f0];
#pragma unroll
  for (int d = 0; d < DEG; d++) {
    float2 cur = fsv;
    if (d < DEG - 1) {
      int sn = __shfl(srcv, (lane & 48) | (d + 1), 64);
      fsv = *(const float2*)&fs[(size_t)sn * F + f0];
    }
    float e0 = cur.x + fdv.x; e0 = (e0 > 0.f) ? e0 : 0.2f * e0;
    float e1 = cur.y + fdv.y; e1 = (e1 > 0.f) ? e1 : 0.2f * e1;
    float p = e0 * a0 + e1 * a1;
    p += __shfl_xor(p, 1, 64);
    p += __shfl_xor(p, 2, 64);
    p += __shfl_xor(p, 4, 64);
    p += __shfl_xor(p, 8, 64);
    float nm = fmaxf(m, p);
    float ex = __expf(p - nm);
    float sc = __expf(m - nm);
    s = s * sc + ex;
    acc0 = acc0 * sc + ex * cur.x;
    acc1 = acc1 * sc + ex * cur.y;
    m = nm;
  }
  float inv = 1.f / s;
  float2 lv = *(const float2*)&lin[(size_t)node * F + f0];
  float o0 = acc0 * inv + lv.x + bias[f0];
  float o1 = acc1 * inv + lv.y + bias[f0 + 1];
  *(float2*)&out[(size_t)node * F + f0] = make_float2(o0, o1);
}

// --- MFMA FC body (R0-exact) ---
template <int KS, int FOT, int NZ>  // FI=32*KS, FO=16*FOT
__device__ __forceinline__ void mfma_fc_body(int vbid, const float* __restrict__ in,
                                             const short* __restrict__ Wp,
                                             const float* __restrict__ B0,
                                             const float* __restrict__ B1,
                                             const float* __restrict__ B2,
                                             float* __restrict__ O0,
                                             float* __restrict__ O1,
                                             float* __restrict__ O2) {
  constexpr int FI = 32 * KS;
  constexpr int FO = 16 * FOT;
  const int tid = threadIdx.x;
  const int wid = tid >> 6;
  const int lane = tid & 63;
  const int q = lane >> 4, n = lane & 15;
  const int n0 = vbid * 64 + wid * 16;
  bf16x8 Ahi[KS], Alo[KS];
#pragma unroll
  for (int ks = 0; ks < KS; ks++) {
    float av[8];
    *(float4*)&av[0] = *(const float4*)&in[(size_t)(n0 + n) * FI + 32 * ks + 8 * q];
    *(float4*)&av[4] = *(const float4*)&in[(size_t)(n0 + n) * FI + 32 * ks + 8 * q + 4];
    pack_hilo_(av, Ahi[ks], Alo[ks]);
  }
#pragma unroll
  for (int z = 0; z < NZ; z++) {
    const short* wz = Wp + (size_t)z * FI * FO * 2;
    const float* bz = (z == 0) ? B0 : (z == 1) ? B1 : B2;
    float* oz = (z == 0) ? O0 : (z == 1) ? O1 : O2;
#pragma unroll
    for (int f = 0; f < FOT; f++) {
      float bv = bz[16 * f + n];
      f32x4 acc = {bv, bv, bv, bv};
#pragma unroll
      for (int ks = 0; ks < KS; ks++) {
        bf16x8 Bhi = *(const bf16x8*)&wz[((size_t)(f * KS + ks) * 64 + lane) * 8];
        bf16x8 Blo = *(const bf16x8*)&wz[(size_t)FI * FO + ((size_t)(f * KS + ks) * 64 + lane) * 8];
        acc = __builtin_amdgcn_mfma_f32_16x16x32_bf16(Ahi[ks], Bhi, acc, 0, 0, 0);
        acc = __builtin_amdgcn_mfma_f32_16x16x32_bf16(Alo[ks], Bhi, acc, 0, 0, 0);
        acc = __builtin_amdgcn_mfma_f32_16x16x32_bf16(Ahi[ks], Blo, acc, 0, 0, 0);
      }
#pragma unroll
      for (int r = 0; r < 4; r++)
        oz[(size_t)(n0 + 4 * q + r) * FO + 16 * f + n] = acc[r];
    }
  }
}

// --- fw1 body (feat @ s1_wih.T + s1_b, R0-exact) ---
__device__ __forceinline__ void fw1_body(int vbid, const float* __restrict__ feat,
                                         const float* __restrict__ wih,
                                         const float* __restrict__ wb,
                                         float* __restrict__ fwout,
                                         float* w_s, float* b_s) {
  if (threadIdx.x < 100) w_s[threadIdx.x] = wih[threadIdx.x];
  if (threadIdx.x < 20) b_s[threadIdx.x] = wb[threadIdx.x];
  __syncthreads();
  const int n = vbid * 256 + threadIdx.x;
  float f[5];
#pragma unroll
  for (int k = 0; k < 5; k++) f[k] = feat[(size_t)n * 5 + k];
#pragma unroll
  for (int j = 0; j < 20; j++) {
    float a = b_s[j];
#pragma unroll
    for (int k = 0; k < 5; k++) a += f[k] * w_s[j * 5 + k];
    fwout[(size_t)n * 20 + j] = a;
  }
}

// --- SAGE-1 LSTM body (R0-exact) ---
__device__ __forceinline__ void lstm1s_body(int vbid, const float* __restrict__ FW,
                                            const int* __restrict__ src,
                                            const float* __restrict__ whh,
                                            const float* __restrict__ feat,
                                            const float* __restrict__ wself,
                                            const float* __restrict__ wneigh,
                                            const float* __restrict__ bias,
                                            float* __restrict__ x1out,
                                            float* w_s, float* ws_s, float* wn_s,
                                            float* b_s) {
  if (threadIdx.x < 100) w_s[threadIdx.x] = whh[threadIdx.x];
  if (threadIdx.x < 160) {
    ws_s[threadIdx.x] = wself[threadIdx.x];
    wn_s[threadIdx.x] = wneigh[threadIdx.x];
  }
  if (threadIdx.x < 32) b_s[threadIdx.x] = bias[threadIdx.x];
  __syncthreads();
  const int n = vbid * 256 + threadIdx.x;
  const int* sp = src + (size_t)n * DEG;
  float f[5];
#pragma unroll
  for (int k = 0; k < 5; k++) f[k] = feat[(size_t)n * 5 + k];
  float h[5] = {0, 0, 0, 0, 0}, c[5] = {0, 0, 0, 0, 0};
  int sd = sp[0];
  float4 p0 = *(const float4*)&FW[(size_t)sd * 20 + 0];
  float4 p1 = *(const float4*)&FW[(size_t)sd * 20 + 4];
  float4 p2 = *(const float4*)&FW[(size_t)sd * 20 + 8];
  float4 p3 = *(const float4*)&FW[(size_t)sd * 20 + 12];
  float4 p4 = *(const float4*)&FW[(size_t)sd * 20 + 16];
  for (int d = 0; d < DEG; d++) {
    float g[20];
    g[0] = p0.x; g[1] = p0.y; g[2] = p0.z; g[3] = p0.w;
    g[4] = p1.x; g[5] = p1.y; g[6] = p1.z; g[7] = p1.w;
    g[8] = p2.x; g[9] = p2.y; g[10] = p2.z; g[11] = p2.w;
    g[12] = p3.x; g[13] = p3.y; g[14] = p3.z; g[15] = p3.w;
    g[16] = p4.x; g[17] = p4.y; g[18] = p4.z; g[19] = p4.w;
    if (d < DEG - 1) {
      int sn = sp[d + 1];
      p0 = *(const float4*)&FW[(size_t)sn * 20 + 0];
      p1 = *(const float4*)&FW[(size_t)sn * 20 + 4];
      p2 = *(const float4*)&FW[(size_t)sn * 20 + 8];
      p3 = *(const float4*)&FW[(size_t)sn * 20 + 12];
      p4 = *(const float4*)&FW[(size_t)sn * 20 + 16];
    }
#pragma unroll
    for (int j = 0; j < 20; j++) {
#pragma unroll
      for (int k = 0; k < 5; k++) g[j] += h[k] * w_s[j * 5 + k];
    }
#pragma unroll
    for (int k = 0; k < 5; k++) {
      float iv = sigmoidf_(g[k]);
      float fv = sigmoidf_(g[5 + k]);
      float gv = tanhf_(g[10 + k]);
      float ov = sigmoidf_(g[15 + k]);
      c[k] = fv * c[k] + iv * gv;
      h[k] = ov * tanhf_(c[k]);
    }
  }
#pragma unroll
  for (int j = 0; j < 32; j++) {
    float a = b_s[j];
#pragma unroll
    for (int k = 0; k < 5; k++) a += f[k] * ws_s[k * 32 + j] + h[k] * wn_s[k * 32 + j];
    x1out[(size_t)n * 32 + j] = fmaxf(a, 0.f);
  }
}

// --- SAGE-2 LSTM MFMA body (R9/R0-EXACT: gathers materialized XW rows) ---
__device__ __forceinline__ void lstm2_body(int vbid, const float* __restrict__ XW,
                                           const int* __restrict__ src,
                                           const float* __restrict__ whh,
                                           float* __restrict__ hn_out,
                                           float* h_lds_all, int* src_lds_all) {
  const int tid = threadIdx.x;
  const int wid = tid >> 6;
  const int lane = tid & 63;
  const int q = lane >> 4;   // quad
  const int n = lane & 15;   // node within group / fragment col
  const int n0 = (vbid * 4 + wid) * 16;
  float* h_lds = &h_lds_all[wid * 16 * 36];
  int* src_lds = &src_lds_all[wid * 256];

  {
    int4 sv = *(const int4*)&src[(size_t)(n0 + (lane >> 2)) * DEG + 4 * (lane & 3)];
    src_lds[(4 * (lane & 3) + 0) * 16 + (lane >> 2)] = sv.x;
    src_lds[(4 * (lane & 3) + 1) * 16 + (lane >> 2)] = sv.y;
    src_lds[(4 * (lane & 3) + 2) * 16 + (lane >> 2)] = sv.z;
    src_lds[(4 * (lane & 3) + 3) * 16 + (lane >> 2)] = sv.w;
  }

  bf16x8 Whi[8], Wlo[8];
#pragma unroll
  for (int gt = 0; gt < 8; gt++) {
    float wv[8];
    *(float4*)&wv[0] = *(const float4*)&whh[(size_t)(16 * gt + n) * 32 + 8 * q];
    *(float4*)&wv[4] = *(const float4*)&whh[(size_t)(16 * gt + n) * 32 + 8 * q + 4];
    pack_hilo_(wv, Whi[gt], Wlo[gt]);
  }

  bf16x8 Bhi, Blo;
#pragma unroll
  for (int j = 0; j < 8; j++) { Bhi[j] = 0; Blo[j] = 0; }
  float cst[8];
#pragma unroll
  for (int i = 0; i < 8; i++) cst[i] = 0.f;

  float4 tc[8], tn[8];
  {
    int s0 = src_lds[0 * 16 + n];
    const float* gb = XW + (size_t)s0 * 128;
#pragma unroll
    for (int i = 0; i < 8; i++) tc[i] = *(const float4*)&gb[16 * i + 4 * q];
  }

  float hv[8];
#pragma unroll
  for (int d = 0; d < DEG; d++) {
    f32x4 D[4][2];
#pragma unroll
    for (int p = 0; p < 4; p++) {
#pragma unroll
      for (int hh = 0; hh < 2; hh++) {
        int gt = p * 2 + hh;
        f32x4 acc = {0.f, 0.f, 0.f, 0.f};
        acc = __builtin_amdgcn_mfma_f32_16x16x32_bf16(Whi[gt], Bhi, acc, 0, 0, 0);
        acc = __builtin_amdgcn_mfma_f32_16x16x32_bf16(Wlo[gt], Bhi, acc, 0, 0, 0);
        acc = __builtin_amdgcn_mfma_f32_16x16x32_bf16(Whi[gt], Blo, acc, 0, 0, 0);
        D[p][hh] = acc;
      }
    }
    if (d < DEG - 1) {
      int s = src_lds[(d + 1) * 16 + n];
      const float* gb = XW + (size_t)s * 128;
#pragma unroll
      for (int i = 0; i < 8; i++) tn[i] = *(const float4*)&gb[16 * i + 4 * q];
    }
#pragma unroll
    for (int hh = 0; hh < 2; hh++) {
      float4 xi = tc[0 + hh];
      float4 xf = tc[2 + hh];
      float4 xg = tc[4 + hh];
      float4 xo = tc[6 + hh];
#pragma unroll
      for (int r = 0; r < 4; r++) {
        float xiv = (r == 0) ? xi.x : (r == 1) ? xi.y : (r == 2) ? xi.z : xi.w;
        float xfv = (r == 0) ? xf.x : (r == 1) ? xf.y : (r == 2) ? xf.z : xf.w;
        float xgv = (r == 0) ? xg.x : (r == 1) ? xg.y : (r == 2) ? xg.z : xg.w;
        float xov = (r == 0) ? xo.x : (r == 1) ? xo.y : (r == 2) ? xo.z : xo.w;
        int ci = hh * 4 + r;
        float iv = sigmoidf_(D[0][hh][r] + xiv);
        float fv = sigmoidf_(D[1][hh][r] + xfv);
        float gv = tanhf_(D[2][hh][r] + xgv);
        float ov = sigmoidf_(D[3][hh][r] + xov);
        cst[ci] = fv * cst[ci] + iv * gv;
        hv[ci] = ov * tanhf_(cst[ci]);
      }
    }
    if (d < DEG - 1) {
      *(float4*)&h_lds[n * 36 + 0 + 4 * q] = make_float4(hv[0], hv[1], hv[2], hv[3]);
      *(float4*)&h_lds[n * 36 + 16 + 4 * q] = make_float4(hv[4], hv[5], hv[6], hv[7]);
      float hb[8];
      *(float4*)&hb[0] = *(const float4*)&h_lds[n * 36 + 8 * q];
      *(float4*)&hb[4] = *(const float4*)&h_lds[n * 36 + 8 * q + 4];
      pack_hilo_(hb, Bhi, Blo);
#pragma unroll
      for (int i = 0; i < 8; i++) tc[i] = tn[i];
    }
  }
  *(float4*)&hn_out[(size_t)(n0 + n) * 32 + 0 + 4 * q] = make_float4(hv[0], hv[1], hv[2], hv[3]);
  *(float4*)&hn_out[(size_t)(n0 + n) * 32 + 16 + 4 * q] = make_float4(hv[4], hv[5], hv[6], hv[7]);
}

// --- SAGE output body (R0-exact, FI=32) ---
__device__ __forceinline__ void sage_body(int vbid, const float* __restrict__ in,
                                          const float* __restrict__ hn,
                                          const float* __restrict__ wself,
                                          const float* __restrict__ wneigh,
                                          const float* __restrict__ bias,
                                          float* __restrict__ out,
                                          float* ws_s, float* wn_s, float* b_s) {
  constexpr int FI = 32;
  for (int idx = threadIdx.x; idx < FI * 32; idx += 256) {
    ws_s[idx] = wself[idx];
    wn_s[idx] = wneigh[idx];
  }
  if (threadIdx.x < 32) b_s[threadIdx.x] = bias[threadIdx.x];
  __syncthreads();
  const int n = vbid * 8 + (threadIdx.x >> 5);
  const int j = threadIdx.x & 31;
  float a = b_s[j];
#pragma unroll
  for (int k = 0; k < FI; k++) a += in[(size_t)n * FI + k] * ws_s[k * 32 + j];
#pragma unroll
  for (int k = 0; k < FI; k++) a += hn[(size_t)n * FI + k] * wn_s[k * 32 + j];
  out[(size_t)n * 32 + j] = fmaxf(a, 0.f);
}

// ===========================================================================
// Kernels
// ===========================================================================

// Startup mega-kernel: [0,6144) fc3 layer0; [6144,6151) repack;
// [6151,6279) fw1 (big path only — fallback launches grid 6151).
__global__ __launch_bounds__(256) void startup_kernel(
    const float* __restrict__ feat,
    const float* __restrict__ W0, const float* __restrict__ B0,
    const float* __restrict__ W1, const float* __restrict__ B1,
    const float* __restrict__ W2, const float* __restrict__ B2,
    float* __restrict__ O0, float* __restrict__ O1, float* __restrict__ O2,
    const float* __restrict__ g1ws, const float* __restrict__ g1wd,
    const float* __restrict__ l1w, const float* __restrict__ g2ws,
    const float* __restrict__ g2wd, const float* __restrict__ l2w,
    const float* __restrict__ s2wih, short* __restrict__ Wp,
    const float* __restrict__ s1wih, const float* __restrict__ s1b,
    float* __restrict__ fwout) {
  __shared__ float w_s[5 * 64];
  __shared__ float in_s[32 * 8];
  __shared__ float b_s[64];
  const int bid = blockIdx.x;
  const int t = threadIdx.x;
  if (bid < 6144) {
    const int bz = bid >> 11, rem = bid & 2047, by = rem >> 10, bx = rem & 1023;
    const float* W = (bz == 0) ? W0 : (bz == 1) ? W1 : W2;
    const float* bias = (bz == 0) ? B0 : (bz == 1) ? B1 : B2;
    float* out = (bz == 0) ? O0 : (bz == 1) ? O1 : O2;
    const int rowBase = bx * 32;
    const int colBase = by * 64;
    for (int idx = t; idx < 5 * 64; idx += 256) {
      int k = idx >> 6, jj = idx & 63;
      w_s[idx] = W[(size_t)k * 128 + colBase + jj];
    }
    if (t < 64) b_s[t] = bias[colBase + t];
    for (int idx = t; idx < 32 * 5; idx += 256) {
      int r = idx / 5, k = idx - r * 5;
      in_s[r * 8 + k] = feat[(size_t)(rowBase + r) * 5 + k];
    }
    __syncthreads();
    const int jj = t & 63;
    const int rslot = t >> 6;
    float acc[8];
#pragma unroll
    for (int r = 0; r < 8; r++) acc[r] = b_s[jj];
    {
      float wv0 = w_s[0 * 64 + jj], wv1 = w_s[1 * 64 + jj];
      float wv2 = w_s[2 * 64 + jj], wv3 = w_s[3 * 64 + jj];
#pragma unroll
      for (int r = 0; r < 8; r++) {
        float4 ip = *(const float4*)&in_s[(rslot * 8 + r) * 8];
        acc[r] += ip.x * wv0 + ip.y * wv1 + ip.z * wv2 + ip.w * wv3;
      }
      float wv4 = w_s[4 * 64 + jj];
#pragma unroll
      for (int r = 0; r < 8; r++) acc[r] += in_s[(rslot * 8 + r) * 8 + 4] * wv4;
    }
#pragma unroll
    for (int r = 0; r < 8; r++)
      out[(size_t)(rowBase + rslot * 8 + r) * 128 + colBase + jj] = acc[r];
  } else if (bid < 6151) {
    const int mid = bid - 6144;
    const float* W;
    int FI, FO, TRANS;
    size_t base;
    if (mid == 0)      { W = g1ws;  FI = 128; FO = 128; TRANS = 0; base = WP_G1; }
    else if (mid == 1) { W = g1wd;  FI = 128; FO = 128; TRANS = 0; base = WP_G1 + 32768; }
    else if (mid == 2) { W = l1w;   FI = 128; FO = 128; TRANS = 0; base = WP_G1 + 65536; }
    else if (mid == 3) { W = g2ws;  FI = 128; FO = 32;  TRANS = 0; base = WP_G2; }
    else if (mid == 4) { W = g2wd;  FI = 128; FO = 32;  TRANS = 0; base = WP_G2 + 8192; }
    else if (mid == 5) { W = l2w;   FI = 128; FO = 32;  TRANS = 0; base = WP_G2 + 16384; }
    else               { W = s2wih; FI = 32;  FO = 128; TRANS = 1; base = WP_S2WIH; }
    const int KS = FI / 32;
    const int total = FI * FO;
    for (int p = t; p < total; p += 256) {
      int j = p & 7, lane = (p >> 3) & 63, rest = p >> 9;
      int ks = rest % KS, f = rest / KS;
      int n = lane & 15, q = lane >> 4;
      int k = 32 * ks + 8 * q + j, fo = 16 * f + n;
      float v = TRANS ? W[(size_t)fo * FI + k] : W[(size_t)k * FO + fo];
      unsigned short hi = f2bf_(v);
      float resid = v - bf2f_(hi);
      Wp[base + p] = (short)hi;
      Wp[base + total + p] = (short)f2bf_(resid);
    }
  } else {
    fw1_body(bid - 6151, feat, s1wih, s1b, fwout, w_s, b_s);
  }
}

// Standalone kernels (fallback path — R0-exact configs).
__global__ __launch_bounds__(256) void gat4_kernel(const float* __restrict__ fs,
                                                   const float* __restrict__ fd,
                                                   const float* __restrict__ lin,
                                                   const int* __restrict__ src,
                                                   const float* __restrict__ attn,
                                                   const float* __restrict__ bias,
                                                   float* __restrict__ out) {
  gat4_body(blockIdx.x, fs, fd, lin, src, attn, bias, out);
}

template <int KS, int FOT, int NZ>
__global__ __launch_bounds__(256) __attribute__((amdgpu_waves_per_eu(1, 4)))
void mfma_fc_kernel(const float* __restrict__ in, const short* __restrict__ Wp,
                    const float* __restrict__ B0, const float* __restrict__ B1,
                    const float* __restrict__ B2, float* __restrict__ O0,
                    float* __restrict__ O1, float* __restrict__ O2) {
  __shared__ float lds_pad[9600];
  if ((const void*)in == nullptr) lds_pad[0] = 1.f;
  mfma_fc_body<KS, FOT, NZ>(blockIdx.x, in, Wp, B0, B1, B2, O0, O1, O2);
}

__global__ __launch_bounds__(256) void gat1_fw1_kernel(
    const float* __restrict__ fs, const float* __restrict__ fd,
    const float* __restrict__ lin, const int* __restrict__ src,
    const float* __restrict__ attn, const float* __restrict__ bias,
    float* __restrict__ out, const float* __restrict__ feat,
    const float* __restrict__ wih, const float* __restrict__ wb,
    float* __restrict__ fwout) {
  __shared__ float w_s[100];
  __shared__ float b_s[20];
  if (blockIdx.x < 2048) {
    gat1_body(blockIdx.x, fs, fd, lin, src, attn, bias, out);
  } else {
    fw1_body(blockIdx.x - 2048, feat, wih, wb, fwout, w_s, b_s);
  }
}

__global__ __launch_bounds__(256) void gat1_kernel(
    const float* __restrict__ fs, const float* __restrict__ fd,
    const float* __restrict__ lin, const int* __restrict__ src,
    const float* __restrict__ attn, const float* __restrict__ bias,
    float* __restrict__ out) {
  gat1_body(blockIdx.x, fs, fd, lin, src, attn, bias, out);
}

__global__ __attribute__((amdgpu_waves_per_eu(1, 4))) __launch_bounds__(256)
void lstm1s_kernel(const float* __restrict__ FW, const int* __restrict__ src,
                   const float* __restrict__ whh, const float* __restrict__ feat,
                   const float* __restrict__ wself, const float* __restrict__ wneigh,
                   const float* __restrict__ bias, float* __restrict__ x1out) {
  __shared__ float w_s[100];
  __shared__ float ws_s[160];
  __shared__ float wn_s[160];
  __shared__ float b_s[32];
  lstm1s_body(blockIdx.x, FW, src, whh, feat, wself, wneigh, bias, x1out,
              w_s, ws_s, wn_s, b_s);
}

__global__ __launch_bounds__(256) __attribute__((amdgpu_waves_per_eu(1, 2)))
void lstm2_mfma_kernel(const float* __restrict__ XW, const int* __restrict__ src,
                       const float* __restrict__ whh, float* __restrict__ hn_out) {
  __shared__ float h_lds_all[4 * 16 * 36];
  __shared__ int src_lds_all[4 * 256];
  __shared__ float lds_pad[15000];  // occupancy cap: ~73 KB total -> 2 blocks/CU
  if ((const void*)XW == nullptr) lds_pad[0] = 1.f;
  lstm2_body(blockIdx.x, XW, src, whh, hn_out, h_lds_all, src_lds_all);
}

__global__ __launch_bounds__(256) void sage_out_kernel(const float* __restrict__ in,
                                                       const float* __restrict__ hn,
                                                       const float* __restrict__ wself,
                                                       const float* __restrict__ wneigh,
                                                       const float* __restrict__ bias,
                                                       float* __restrict__ out) {
  __shared__ float ws_s[32 * 32];
  __shared__ float wn_s[32 * 32];
  __shared__ float b_s[32];
  sage_body(blockIdx.x, in, hn, wself, wneigh, bias, out, ws_s, wn_s, b_s);
}

// ---------------------------------------------------------------------------
// Fused kernels (big-workspace path). Block-role interleave keeps a mix of
// gather-heavy and compute blocks resident on every CU.
// ---------------------------------------------------------------------------

// K2: gat4-L0 (8192 blocks) || lstm1s (128 blocks). grid = 65*128 = 8320.
__global__ __launch_bounds__(256) void gat4_lstm1s_kernel(
    const float* __restrict__ fs, const float* __restrict__ fd,
    const float* __restrict__ lin, const int* __restrict__ src,
    const float* __restrict__ attn, const float* __restrict__ bias,
    float* __restrict__ out,
    const float* __restrict__ FW, const float* __restrict__ whh,
    const float* __restrict__ feat, const float* __restrict__ wself,
    const float* __restrict__ wneigh, const float* __restrict__ sbias,
    float* __restrict__ x1out) {
  __shared__ float w_s[100];
  __shared__ float ws_s[160];
  __shared__ float wn_s[160];
  __shared__ float b_s[32];
  const int bid = blockIdx.x;
  const int r = bid % 65, q = bid / 65;
  if (r < 64) {
    gat4_body(q * 64 + r, fs, fd, lin, src, attn, bias, out);
  } else {
    lstm1s_body(q, FW, src, whh, feat, wself, wneigh, sbias, x1out,
                w_s, ws_s, wn_s, b_s);
  }
}

// K3: mfma trio G1 (512) || XW-mfma (512). grid = 1024 (even=trio, odd=XW).
__global__ __launch_bounds__(256) void mfma_g1_xw_kernel(
    const float* __restrict__ in, const short* __restrict__ Wp,
    const float* __restrict__ B0, const float* __restrict__ B1,
    const float* __restrict__ B2, float* __restrict__ O0,
    float* __restrict__ O1, float* __restrict__ O2,
    const float* __restrict__ x1, const short* __restrict__ WpX,
    const float* __restrict__ s2b, float* __restrict__ XW) {
  __shared__ float lds_pad[9600];
  if ((const void*)in == nullptr) lds_pad[0] = 1.f;
  const int bid = blockIdx.x;
  if ((bid & 1) == 0) {
    mfma_fc_body<4, 8, 3>(bid >> 1, in, Wp, B0, B1, B2, O0, O1, O2);
  } else {
    mfma_fc_body<1, 8, 1>(bid >> 1, x1, WpX, s2b, nullptr, nullptr,
                          XW, nullptr, nullptr);
  }
}

// K4: gat4-L1 (8192) || lstm2 (512). grid = 17*512 = 8704.
__global__ __launch_bounds__(256) void gat4_lstm2_kernel(
    const float* __restrict__ fs, const float* __restrict__ fd,
    const float* __restrict__ lin, const int* __restrict__ src,
    const float* __restrict__ attn, const float* __restrict__ bias,
    float* __restrict__ out,
    const float* __restrict__ XW, const float* __restrict__ whh,
    float* __restrict__ hn_out) {
  __shared__ float h_lds_all[4 * 16 * 36];
  __shared__ int src_lds_all[4 * 256];
  const int bid = blockIdx.x;
  const int r = bid % 17, q = bid / 17;
  if (r < 16) {
    gat4_body(q * 16 + r, fs, fd, lin, src, attn, bias, out);
  } else {
    lstm2_body(q, XW, src, whh, hn_out, h_lds_all, src_lds_all);
  }
}

// K5: mfma trio G2 (512) || sage_out (4096). grid = 9*512 = 4608.
__global__ __launch_bounds__(256) void mfma_g2_sage_kernel(
    const float* __restrict__ in, const short* __restrict__ Wp,
    const float* __restrict__ B0, const float* __restrict__ B1,
    const float* __restrict__ B2, float* __restrict__ O0,
    float* __restrict__ O1, float* __restrict__ O2,
    const float* __restrict__ x1, const float* __restrict__ hn,
    const float* __restrict__ wself, const float* __restrict__ wneigh,
    const float* __restrict__ sbias, float* __restrict__ x2out) {
  __shared__ float lds_pad[9600];
  __shared__ float ws_s[32 * 32];
  __shared__ float wn_s[32 * 32];
  __shared__ float b_s[32];
  if ((const void*)in == nullptr) lds_pad[0] = 1.f;
  const int bid = blockIdx.x;
  const int r = bid % 9, q = bid / 9;
  if (r == 0) {
    mfma_fc_body<4, 2, 3>(q, in, Wp, B0, B1, B2, O0, O1, O2);
  } else {
    sage_body(q * 8 + (r - 1), x1, hn, wself, wneigh, sbias, x2out,
              ws_s, wn_s, b_s);
  }
}

// ---------------------------------------------------------------------------
// Final MLP (unchanged).
// ---------------------------------------------------------------------------
__global__ __attribute__((amdgpu_waves_per_eu(4, 4))) __launch_bounds__(256)
void final_kernel(const float* __restrict__ gat,
                  const float* __restrict__ x2,
                  const float* __restrict__ f1w,
                  const float* __restrict__ f1b,
                  const float* __restrict__ f2w,
                  const float* __restrict__ f2b,
                  float* __restrict__ out) {
  __shared__ float w1_s[64 * 16];
  __shared__ float b1_s[16];
  __shared__ float w2_s[16];
  for (int idx = threadIdx.x; idx < 1024; idx += 256) w1_s[idx] = f1w[idx];
  if (threadIdx.x < 16) {
    b1_s[threadIdx.x] = f1b[threadIdx.x];
    w2_s[threadIdx.x] = f2w[threadIdx.x];
  }
  __syncthreads();
  const int n = blockIdx.x * 256 + threadIdx.x;
  float z[64];
#pragma unroll
  for (int k = 0; k < 32; k += 4) {
    float4 a = *(const float4*)&gat[(size_t)n * 32 + k];
    z[k] = a.x; z[k + 1] = a.y; z[k + 2] = a.z; z[k + 3] = a.w;
    float4 b = *(const float4*)&x2[(size_t)n * 32 + k];
    z[32 + k] = b.x; z[32 + k + 1] = b.y; z[32 + k + 2] = b.z; z[32 + k + 3] = b.w;
  }
  float o = f2b[0];
#pragma unroll
  for (int j = 0; j < 16; j++) {
    float a = b1_s[j];
#pragma unroll
    for (int k = 0; k < 64; k++) a += z[k] * w1_s[k * 16 + j];
    o += fmaxf(a, 0.f) * w2_s[j];
  }
  out[n] = o;
}

extern "C" void kernel_launch(void* const* d_in, const int* in_sizes, int n_in,
                              void* d_out, int out_size, void* d_ws, size_t ws_size,
                              hipStream_t stream) {
  const int N = NNODES;
  const float* feat = (const float*)d_in[0];
  const int* src = (const int*)d_in[1];
  const float* g0_ws = (const float*)d_in[2];
  const float* g0_bs = (const float*)d_in[3];
  const float* g0_wd = (const float*)d_in[4];
  const float* g0_bd = (const float*)d_in[5];
  const float* g0_attn = (const float*)d_in[6];
  const float* g0_bias = (const float*)d_in[7];
  const float* l0_w = (const float*)d_in[8];
  const float* l0_b = (const float*)d_in[9];
  const float* g1_ws = (const float*)d_in[10];
  const float* g1_bs = (const float*)d_in[11];
  const float* g1_wd = (const float*)d_in[12];
  const float* g1_bd = (const float*)d_in[13];
  const float* g1_attn = (const float*)d_in[14];
  const float* g1_bias = (const float*)d_in[15];
  const float* l1_w = (const float*)d_in[16];
  const float* l1_b = (const float*)d_in[17];
  const float* g2_ws = (const float*)d_in[18];
  const float* g2_bs = (const float*)d_in[19];
  const float* g2_wd = (const float*)d_in[20];
  const float* g2_bd = (const float*)d_in[21];
  const float* g2_attn = (const float*)d_in[22];
  const float* g2_bias = (const float*)d_in[23];
  const float* l2_w = (const float*)d_in[24];
  const float* l2_b = (const float*)d_in[25];
  const float* s1_wih = (const float*)d_in[26];
  const float* s1_whh = (const float*)d_in[27];
  const float* s1_b = (const float*)d_in[28];
  const float* s1_wself = (const float*)d_in[29];
  const float* s1_wneigh = (const float*)d_in[30];
  const float* s1_bias = (const float*)d_in[31];
  const float* s2_wih = (const float*)d_in[32];
  const float* s2_whh = (const float*)d_in[33];
  const float* s2_b = (const float*)d_in[34];
  const float* s2_wself = (const float*)d_in[35];
  const float* s2_wneigh = (const float*)d_in[36];
  const float* s2_bias = (const float*)d_in[37];
  const float* f1_w = (const float*)d_in[38];
  const float* f1_b = (const float*)d_in[39];
  const float* f2_w = (const float*)d_in[40];
  const float* f2_b = (const float*)d_in[41];

  float* A = (float*)d_ws;                // N*128
  float* B = A + (size_t)N * 128;
  float* C = B + (size_t)N * 128;
  float* D = C + (size_t)N * 128;
  float* E = D + (size_t)N * 128;         // A..E = 84 MB
  short* Wp = (short*)(A + (size_t)5 * N * 128);  // packed bf16 weights, 262 KB
  // Workspace tail (big path only): SAGE-chain intermediates.
  float* X1 = (float*)(Wp + WP_TOTAL);    // x1  [N,32]  4 MB
  float* XW = X1 + (size_t)N * 32;        // XW  [N,128] 16 MB
  float* HN2 = XW + (size_t)N * 128;      // hn2 [N,32]  4 MB
  float* X2 = HN2 + (size_t)N * 32;       // x2  [N,32]  4 MB
  const size_t need = (size_t)((char*)(X2 + (size_t)N * 32) - (char*)d_ws);
  const bool big = ws_size >= need;

  if (big) {
    // K1: fc3-L0 + repack + fw1 -> A,B,C, Wp, E[0..N*20)=FW1
    startup_kernel<<<6151 + 128, 256, 0, stream>>>(
        feat, g0_ws, g0_bs, g0_wd, g0_bd, l0_w, l0_b, A, B, C,
        g1_ws, g1_wd, l1_w, g2_ws, g2_wd, l2_w, s2_wih, Wp, s1_wih, s1_b, E);
    // K2: gat4-L0 (A,B,C -> D=h1) || lstm1s (E-FW1 -> X1)
    gat4_lstm1s_kernel<<<8320, 256, 0, stream>>>(
        A, B, C, src, g0_attn, g0_bias, D,
        E, s1_whh, feat, s1_wself, s1_wneigh, s1_bias, X1);
    // K3: mfma trio G1 (D -> A,B,C) || XW = x1@wih.T+b (X1 -> XW)
    mfma_g1_xw_kernel<<<1024, 256, 0, stream>>>(
        D, Wp + WP_G1, g1_bs, g1_bd, l1_b, A, B, C,
        X1, Wp + WP_S2WIH, s2_b, XW);
    // K4: gat4-L1 (A,B,C -> E=h2) || lstm2 (XW -> HN2)
    gat4_lstm2_kernel<<<8704, 256, 0, stream>>>(
        A, B, C, src, g1_attn, g1_bias, E,
        XW, s2_whh, HN2);
    // K5: mfma trio G2 (E -> A,B,C [N,32]) || sage_out (X1,HN2 -> X2)
    mfma_g2_sage_kernel<<<4608, 256, 0, stream>>>(
        E, Wp + WP_G2, g2_bs, g2_bd, l2_b, A, B, C,
        X1, HN2, s2_wself, s2_wneigh, s2_bias, X2);
    // K6: gat1 -> D = gat [N,32]
    gat1_kernel<<<2048, 256, 0, stream>>>(A, B, C, src, g2_attn, g2_bias, D);
    // K7: final MLP
    final_kernel<<<N / 256, 256, 0, stream>>>(D, X2, f1_w, f1_b, f2_w, f2_b,
                                              (float*)d_out);
  } else {
    // Fallback: exact round-0 serial schedule and buffer roles.
    startup_kernel<<<6151, 256, 0, stream>>>(
        feat, g0_ws, g0_bs, g0_wd, g0_bd, l0_w, l0_b, A, B, C,
        g1_ws, g1_wd, l1_w, g2_ws, g2_wd, l2_w, s2_wih, Wp, s1_wih, s1_b, E);
    gat4_kernel<<<N / 4, 256, 0, stream>>>(A, B, C, src, g0_attn, g0_bias, D);
    mfma_fc_kernel<4, 8, 3><<<N / 64, 256, 0, stream>>>(
        D, Wp + WP_G1, g1_bs, g1_bd, l1_b, A, B, C);
    gat4_kernel<<<N / 4, 256, 0, stream>>>(A, B, C, src, g1_attn, g1_bias, E);
    mfma_fc_kernel<4, 2, 3><<<N / 64, 256, 0, stream>>>(
        E, Wp + WP_G2, g2_bs, g2_bd, l2_b, A, B, C);
    gat1_fw1_kernel<<<2048 + 128, 256, 0, stream>>>(
        A, B, C, src, g2_attn, g2_bias, D, feat, s1_wih, s1_b, E);
    lstm1s_kernel<<<N / 256, 256, 0, stream>>>(E, src, s1_whh, feat, s1_wself,
                                               s1_wneigh, s1_bias, C);
    mfma_fc_kernel<1, 8, 1><<<N / 64, 256, 0, stream>>>(
        C, Wp + WP_S2WIH, s2_b, nullptr, nullptr, A, nullptr, nullptr);
    lstm2_mfma_kernel<<<N / 64, 256, 0, stream>>>(A, src, s2_whh, E);
    sage_out_kernel<<<N / 8, 256, 0, stream>>>(C, E, s2_wself, s2_wneigh,
                                               s2_bias, B);
    final_kernel<<<N / 256, 256, 0, stream>>>(D, B, f1_w, f1_b, f2_w, f2_b,
                                              (float*)d_out);
  }
}

// Round 3
// 426.906 us; speedup vs baseline: 1.1906x; 1.1906x over previous
//
#include <hip/hip_runtime.h>
#include <hip/hip_bf16.h>

#define NNODES 32768
#define DEG 16

__device__ __forceinline__ float sigmoidf_(float x) { return 1.f / (1.f + __expf(-x)); }
__device__ __forceinline__ float tanhf_(float x) { return 1.f - 2.f / (__expf(2.f * x) + 1.f); }

typedef __attribute__((ext_vector_type(8))) short bf16x8;
typedef __attribute__((ext_vector_type(4))) float f32x4;

__device__ __forceinline__ unsigned short f2bf_(float x) {
  __hip_bfloat16 b = __float2bfloat16(x);
  union { __hip_bfloat16 b; unsigned short u; } cv;
  cv.b = b;
  return cv.u;
}
__device__ __forceinline__ float bf2f_(unsigned short u) {
  union { unsigned short u; __hip_bfloat16 b; } cv;
  cv.u = u;
  return __bfloat162float(cv.b);
}
__device__ __forceinline__ void pack_hilo_(const float* v, bf16x8& hi, bf16x8& lo) {
#pragma unroll
  for (int j = 0; j < 8; j++) {
    unsigned short h = f2bf_(v[j]);
    float resid = v[j] - bf2f_(h);
    hi[j] = (short)h;
    lo[j] = (short)f2bf_(resid);
  }
}

// Packed-weight offsets (shorts); hi block then lo block per matrix.
#define WP_G1    0        // 3 x (128x128): stride 32768
#define WP_G2    98304    // 3 x (128x32):  stride 8192
#define WP_S2WIH 122880   // 32x128 (transposed use)
#define WP_TOTAL 131072

// ---------------------------------------------------------------------------
// Startup mega-kernel: [0,6144) = fc3 layer0; [6144,6151) = weight repack.
// R0-exact.
// ---------------------------------------------------------------------------
__global__ __launch_bounds__(256) void startup_kernel(
    const float* __restrict__ feat,
    const float* __restrict__ W0, const float* __restrict__ B0,
    const float* __restrict__ W1, const float* __restrict__ B1,
    const float* __restrict__ W2, const float* __restrict__ B2,
    float* __restrict__ O0, float* __restrict__ O1, float* __restrict__ O2,
    const float* __restrict__ g1ws, const float* __restrict__ g1wd,
    const float* __restrict__ l1w, const float* __restrict__ g2ws,
    const float* __restrict__ g2wd, const float* __restrict__ l2w,
    const float* __restrict__ s2wih, short* __restrict__ Wp) {
  __shared__ float w_s[5 * 64];
  __shared__ float in_s[32 * 8];
  __shared__ float b_s[64];
  const int bid = blockIdx.x;
  const int t = threadIdx.x;
  if (bid < 6144) {
    const int bz = bid >> 11, rem = bid & 2047, by = rem >> 10, bx = rem & 1023;
    const float* W = (bz == 0) ? W0 : (bz == 1) ? W1 : W2;
    const float* bias = (bz == 0) ? B0 : (bz == 1) ? B1 : B2;
    float* out = (bz == 0) ? O0 : (bz == 1) ? O1 : O2;
    const int rowBase = bx * 32;
    const int colBase = by * 64;
    for (int idx = t; idx < 5 * 64; idx += 256) {
      int k = idx >> 6, jj = idx & 63;
      w_s[idx] = W[(size_t)k * 128 + colBase + jj];
    }
    if (t < 64) b_s[t] = bias[colBase + t];
    for (int idx = t; idx < 32 * 5; idx += 256) {
      int r = idx / 5, k = idx - r * 5;
      in_s[r * 8 + k] = feat[(size_t)(rowBase + r) * 5 + k];
    }
    __syncthreads();
    const int jj = t & 63;
    const int rslot = t >> 6;
    float acc[8];
#pragma unroll
    for (int r = 0; r < 8; r++) acc[r] = b_s[jj];
    {
      float wv0 = w_s[0 * 64 + jj], wv1 = w_s[1 * 64 + jj];
      float wv2 = w_s[2 * 64 + jj], wv3 = w_s[3 * 64 + jj];
#pragma unroll
      for (int r = 0; r < 8; r++) {
        float4 ip = *(const float4*)&in_s[(rslot * 8 + r) * 8];
        acc[r] += ip.x * wv0 + ip.y * wv1 + ip.z * wv2 + ip.w * wv3;
      }
      float wv4 = w_s[4 * 64 + jj];
#pragma unroll
      for (int r = 0; r < 8; r++) acc[r] += in_s[(rslot * 8 + r) * 8 + 4] * wv4;
    }
#pragma unroll
    for (int r = 0; r < 8; r++)
      out[(size_t)(rowBase + rslot * 8 + r) * 128 + colBase + jj] = acc[r];
  } else {
    const int mid = bid - 6144;
    const float* W;
    int FI, FO, TRANS;
    size_t base;
    if (mid == 0)      { W = g1ws;  FI = 128; FO = 128; TRANS = 0; base = WP_G1; }
    else if (mid == 1) { W = g1wd;  FI = 128; FO = 128; TRANS = 0; base = WP_G1 + 32768; }
    else if (mid == 2) { W = l1w;   FI = 128; FO = 128; TRANS = 0; base = WP_G1 + 65536; }
    else if (mid == 3) { W = g2ws;  FI = 128; FO = 32;  TRANS = 0; base = WP_G2; }
    else if (mid == 4) { W = g2wd;  FI = 128; FO = 32;  TRANS = 0; base = WP_G2 + 8192; }
    else if (mid == 5) { W = l2w;   FI = 128; FO = 32;  TRANS = 0; base = WP_G2 + 16384; }
    else               { W = s2wih; FI = 32;  FO = 128; TRANS = 1; base = WP_S2WIH; }
    const int KS = FI / 32;
    const int total = FI * FO;
    for (int p = t; p < total; p += 256) {
      int j = p & 7, lane = (p >> 3) & 63, rest = p >> 9;
      int ks = rest % KS, f = rest / KS;
      int n = lane & 15, q = lane >> 4;
      int k = 32 * ks + 8 * q + j, fo = 16 * f + n;
      float v = TRANS ? W[(size_t)fo * FI + k] : W[(size_t)k * FO + fo];
      unsigned short hi = f2bf_(v);
      float resid = v - bf2f_(hi);
      Wp[base + p] = (short)hi;
      Wp[base + total + p] = (short)f2bf_(resid);
    }
  }
}

// ---------------------------------------------------------------------------
// MFMA FC (R0-exact).
// ---------------------------------------------------------------------------
template <int KS, int FOT, int NZ>  // FI=32*KS, FO=16*FOT
__global__ __launch_bounds__(256) __attribute__((amdgpu_waves_per_eu(1, 4)))
void mfma_fc_kernel(const float* __restrict__ in, const short* __restrict__ Wp,
                    const float* __restrict__ B0, const float* __restrict__ B1,
                    const float* __restrict__ B2, float* __restrict__ O0,
                    float* __restrict__ O1, float* __restrict__ O2) {
  constexpr int FI = 32 * KS;
  constexpr int FO = 16 * FOT;
  __shared__ float lds_pad[9600];
  if ((const void*)in == nullptr) lds_pad[0] = 1.f;
  const int tid = threadIdx.x;
  const int wid = tid >> 6;
  const int lane = tid & 63;
  const int q = lane >> 4, n = lane & 15;
  const int n0 = blockIdx.x * 64 + wid * 16;
  bf16x8 Ahi[KS], Alo[KS];
#pragma unroll
  for (int ks = 0; ks < KS; ks++) {
    float av[8];
    *(float4*)&av[0] = *(const float4*)&in[(size_t)(n0 + n) * FI + 32 * ks + 8 * q];
    *(float4*)&av[4] = *(const float4*)&in[(size_t)(n0 + n) * FI + 32 * ks + 8 * q + 4];
    pack_hilo_(av, Ahi[ks], Alo[ks]);
  }
#pragma unroll
  for (int z = 0; z < NZ; z++) {
    const short* wz = Wp + (size_t)z * FI * FO * 2;
    const float* bz = (z == 0) ? B0 : (z == 1) ? B1 : B2;
    float* oz = (z == 0) ? O0 : (z == 1) ? O1 : O2;
#pragma unroll
    for (int f = 0; f < FOT; f++) {
      float bv = bz[16 * f + n];
      f32x4 acc = {bv, bv, bv, bv};
#pragma unroll
      for (int ks = 0; ks < KS; ks++) {
        bf16x8 Bhi = *(const bf16x8*)&wz[((size_t)(f * KS + ks) * 64 + lane) * 8];
        bf16x8 Blo = *(const bf16x8*)&wz[(size_t)FI * FO + ((size_t)(f * KS + ks) * 64 + lane) * 8];
        acc = __builtin_amdgcn_mfma_f32_16x16x32_bf16(Ahi[ks], Bhi, acc, 0, 0, 0);
        acc = __builtin_amdgcn_mfma_f32_16x16x32_bf16(Alo[ks], Bhi, acc, 0, 0, 0);
        acc = __builtin_amdgcn_mfma_f32_16x16x32_bf16(Ahi[ks], Blo, acc, 0, 0, 0);
      }
#pragma unroll
      for (int r = 0; r < 4; r++)
        oz[(size_t)(n0 + 4 * q + r) * FO + 16 * f + n] = acc[r];
    }
  }
}

// ---------------------------------------------------------------------------
// GATv2 H=4 (R0-exact).
// ---------------------------------------------------------------------------
__global__ __launch_bounds__(256) void gat4_kernel(const float* __restrict__ fs,
                                                   const float* __restrict__ fd,
                                                   const float* __restrict__ lin,
                                                   const int* __restrict__ src,
                                                   const float* __restrict__ attn,
                                                   const float* __restrict__ bias,
                                                   float* __restrict__ out) {
  constexpr int F = 128;
  const int lane = threadIdx.x & 63;
  const int wave = threadIdx.x >> 6;
  const int li = lane & 15;
  const int node = blockIdx.x * 4 + wave;
  const int f0 = 2 * lane;
  const int srcv = src[(size_t)node * DEG + li];
  const float2 fdv = *(const float2*)&fd[(size_t)node * F + f0];
  const float a0 = attn[f0];
  const float a1 = attn[f0 + 1];
  float m = -1e30f, s = 0.f, acc0 = 0.f, acc1 = 0.f;
  int sd = __shfl(srcv, (lane & 48), 64);
  float2 fsv = *(const float2*)&fs[(size_t)sd * F + f0];
#pragma unroll
  for (int d = 0; d < DEG; d++) {
    float2 cur = fsv;
    if (d < DEG - 1) {
      int sn = __shfl(srcv, (lane & 48) | (d + 1), 64);
      fsv = *(const float2*)&fs[(size_t)sn * F + f0];
    }
    float e0 = cur.x + fdv.x; e0 = (e0 > 0.f) ? e0 : 0.2f * e0;
    float e1 = cur.y + fdv.y; e1 = (e1 > 0.f) ? e1 : 0.2f * e1;
    float p = e0 * a0 + e1 * a1;
    p += __shfl_xor(p, 1, 64);
    p += __shfl_xor(p, 2, 64);
    p += __shfl_xor(p, 4, 64);
    p += __shfl_xor(p, 8, 64);
    float nm = fmaxf(m, p);
    float ex = __expf(p - nm);
    float sc = __expf(m - nm);
    s = s * sc + ex;
    acc0 = acc0 * sc + ex * cur.x;
    acc1 = acc1 * sc + ex * cur.y;
    m = nm;
  }
  float inv = 1.f / s;
  float2 lv = *(const float2*)&lin[(size_t)node * F + f0];
  float o0 = acc0 * inv + lv.x + bias[f0];
  float o1 = acc1 * inv + lv.y + bias[f0 + 1];
  o0 = (o0 > 0.f) ? o0 : __expf(o0) - 1.f;
  o1 = (o1 > 0.f) ? o1 : __expf(o1) - 1.f;
  *(float2*)&out[(size_t)node * F + f0] = make_float2(o0, o1);
}

// ---------------------------------------------------------------------------
// GATv2 H=1 (no ELU) + fused fw1 (R0-exact).
// ---------------------------------------------------------------------------
__global__ __launch_bounds__(256) void gat1_fw1_kernel(
    const float* __restrict__ fs, const float* __restrict__ fd,
    const float* __restrict__ lin, const int* __restrict__ src,
    const float* __restrict__ attn, const float* __restrict__ bias,
    float* __restrict__ out, const float* __restrict__ feat,
    const float* __restrict__ wih, const float* __restrict__ wb,
    float* __restrict__ fwout) {
  __shared__ float w_s[100];
  __shared__ float b_s[20];
  if (blockIdx.x < 2048) {
    constexpr int F = 32;
    const int lane = threadIdx.x & 63;
    const int wave = threadIdx.x >> 6;
    const int G = lane >> 4, li = lane & 15;
    const int node = blockIdx.x * 16 + wave * 4 + G;
    const int f0 = 2 * li;
    const int srcv = src[(size_t)node * DEG + li];
    const float2 fdv = *(const float2*)&fd[(size_t)node * F + f0];
    const float a0 = attn[f0];
    const float a1 = attn[f0 + 1];
    float m = -1e30f, s = 0.f, acc0 = 0.f, acc1 = 0.f;
    int sd = __shfl(srcv, (lane & 48), 64);
    float2 fsv = *(const float2*)&fs[(size_t)sd * F + f0];
#pragma unroll
    for (int d = 0; d < DEG; d++) {
      float2 cur = fsv;
      if (d < DEG - 1) {
        int sn = __shfl(srcv, (lane & 48) | (d + 1), 64);
        fsv = *(const float2*)&fs[(size_t)sn * F + f0];
      }
      float e0 = cur.x + fdv.x; e0 = (e0 > 0.f) ? e0 : 0.2f * e0;
      float e1 = cur.y + fdv.y; e1 = (e1 > 0.f) ? e1 : 0.2f * e1;
      float p = e0 * a0 + e1 * a1;
      p += __shfl_xor(p, 1, 64);
      p += __shfl_xor(p, 2, 64);
      p += __shfl_xor(p, 4, 64);
      p += __shfl_xor(p, 8, 64);
      float nm = fmaxf(m, p);
      float ex = __expf(p - nm);
      float sc = __expf(m - nm);
      s = s * sc + ex;
      acc0 = acc0 * sc + ex * cur.x;
      acc1 = acc1 * sc + ex * cur.y;
      m = nm;
    }
    float inv = 1.f / s;
    float2 lv = *(const float2*)&lin[(size_t)node * F + f0];
    float o0 = acc0 * inv + lv.x + bias[f0];
    float o1 = acc1 * inv + lv.y + bias[f0 + 1];
    *(float2*)&out[(size_t)node * F + f0] = make_float2(o0, o1);
  } else {
    if (threadIdx.x < 100) w_s[threadIdx.x] = wih[threadIdx.x];
    if (threadIdx.x < 20) b_s[threadIdx.x] = wb[threadIdx.x];
    __syncthreads();
    const int n = (blockIdx.x - 2048) * 256 + threadIdx.x;
    float f[5];
#pragma unroll
    for (int k = 0; k < 5; k++) f[k] = feat[(size_t)n * 5 + k];
#pragma unroll
    for (int j = 0; j < 20; j++) {
      float a = b_s[j];
#pragma unroll
      for (int k = 0; k < 5; k++) a += f[k] * w_s[j * 5 + k];
      fwout[(size_t)n * 20 + j] = a;
    }
  }
}

// ---------------------------------------------------------------------------
// SAGE-1: LSTM + fused projection (R0-exact).
// ---------------------------------------------------------------------------
__global__ __attribute__((amdgpu_waves_per_eu(1, 4))) __launch_bounds__(256)
void lstm1s_kernel(const float* __restrict__ FW, const int* __restrict__ src,
                   const float* __restrict__ whh, const float* __restrict__ feat,
                   const float* __restrict__ wself, const float* __restrict__ wneigh,
                   const float* __restrict__ bias, float* __restrict__ x1out) {
  __shared__ float w_s[100];   // whh [20][5]
  __shared__ float ws_s[160];  // wself [5][32]
  __shared__ float wn_s[160];  // wneigh [5][32]
  __shared__ float b_s[32];
  if (threadIdx.x < 100) w_s[threadIdx.x] = whh[threadIdx.x];
  if (threadIdx.x < 160) {
    ws_s[threadIdx.x] = wself[threadIdx.x];
    wn_s[threadIdx.x] = wneigh[threadIdx.x];
  }
  if (threadIdx.x < 32) b_s[threadIdx.x] = bias[threadIdx.x];
  __syncthreads();
  const int n = blockIdx.x * 256 + threadIdx.x;
  const int* sp = src + (size_t)n * DEG;
  float f[5];
#pragma unroll
  for (int k = 0; k < 5; k++) f[k] = feat[(size_t)n * 5 + k];
  float h[5] = {0, 0, 0, 0, 0}, c[5] = {0, 0, 0, 0, 0};
  int sd = sp[0];
  float4 p0 = *(const float4*)&FW[(size_t)sd * 20 + 0];
  float4 p1 = *(const float4*)&FW[(size_t)sd * 20 + 4];
  float4 p2 = *(const float4*)&FW[(size_t)sd * 20 + 8];
  float4 p3 = *(const float4*)&FW[(size_t)sd * 20 + 12];
  float4 p4 = *(const float4*)&FW[(size_t)sd * 20 + 16];
  for (int d = 0; d < DEG; d++) {
    float g[20];
    g[0] = p0.x; g[1] = p0.y; g[2] = p0.z; g[3] = p0.w;
    g[4] = p1.x; g[5] = p1.y; g[6] = p1.z; g[7] = p1.w;
    g[8] = p2.x; g[9] = p2.y; g[10] = p2.z; g[11] = p2.w;
    g[12] = p3.x; g[13] = p3.y; g[14] = p3.z; g[15] = p3.w;
    g[16] = p4.x; g[17] = p4.y; g[18] = p4.z; g[19] = p4.w;
    if (d < DEG - 1) {
      int sn = sp[d + 1];
      p0 = *(const float4*)&FW[(size_t)sn * 20 + 0];
      p1 = *(const float4*)&FW[(size_t)sn * 20 + 4];
      p2 = *(const float4*)&FW[(size_t)sn * 20 + 8];
      p3 = *(const float4*)&FW[(size_t)sn * 20 + 12];
      p4 = *(const float4*)&FW[(size_t)sn * 20 + 16];
    }
#pragma unroll
    for (int j = 0; j < 20; j++) {
#pragma unroll
      for (int k = 0; k < 5; k++) g[j] += h[k] * w_s[j * 5 + k];
    }
#pragma unroll
    for (int k = 0; k < 5; k++) {
      float iv = sigmoidf_(g[k]);
      float fv = sigmoidf_(g[5 + k]);
      float gv = tanhf_(g[10 + k]);
      float ov = sigmoidf_(g[15 + k]);
      c[k] = fv * c[k] + iv * gv;
      h[k] = ov * tanhf_(c[k]);
    }
  }
#pragma unroll
  for (int j = 0; j < 32; j++) {
    float a = b_s[j];
#pragma unroll
    for (int k = 0; k < 5; k++) a += f[k] * ws_s[k * 32 + j] + h[k] * wn_s[k * 32 + j];
    x1out[(size_t)n * 32 + j] = fmaxf(a, 0.f);
  }
}

// ---------------------------------------------------------------------------
// SAGE-2 LSTM (MFMA) — R0-exact arithmetic. ONLY change this round:
// occupancy cap relaxed 2 -> 4 blocks/CU (pad 60KB -> 27KB, waves_per_eu
// (1,2) -> (1,4)). Rationale: gat4 sustains ~2.5 TB/s on the same random
// row-gather fabric; lstm2 sat at 1.65 TB/s with VALUBusy 62% at 17%
// occupancy -> wave-starved, not fabric-bound. Bit-exact numerics.
// ---------------------------------------------------------------------------
__global__ __launch_bounds__(256) __attribute__((amdgpu_waves_per_eu(1, 4)))
void lstm2_mfma_kernel(const float* __restrict__ XW, const int* __restrict__ src,
                       const float* __restrict__ whh, float* __restrict__ hn_out) {
  __shared__ float h_lds_all[4 * 16 * 36];
  __shared__ int src_lds_all[4 * 256];
  __shared__ float lds_pad[6900];  // occupancy cap: ~40 KB total -> 4 blocks/CU
  if ((const void*)XW == nullptr) lds_pad[0] = 1.f;  // keep pad allocated
  const int tid = threadIdx.x;
  const int wid = tid >> 6;
  const int lane = tid & 63;
  const int q = lane >> 4;   // quad
  const int n = lane & 15;   // node within group / fragment col
  const int n0 = (blockIdx.x * 4 + wid) * 16;
  float* h_lds = &h_lds_all[wid * 16 * 36];
  int* src_lds = &src_lds_all[wid * 256];

  {
    int4 sv = *(const int4*)&src[(size_t)(n0 + (lane >> 2)) * DEG + 4 * (lane & 3)];
    src_lds[(4 * (lane & 3) + 0) * 16 + (lane >> 2)] = sv.x;
    src_lds[(4 * (lane & 3) + 1) * 16 + (lane >> 2)] = sv.y;
    src_lds[(4 * (lane & 3) + 2) * 16 + (lane >> 2)] = sv.z;
    src_lds[(4 * (lane & 3) + 3) * 16 + (lane >> 2)] = sv.w;
  }

  bf16x8 Whi[8], Wlo[8];
#pragma unroll
  for (int gt = 0; gt < 8; gt++) {
    float wv[8];
    *(float4*)&wv[0] = *(const float4*)&whh[(size_t)(16 * gt + n) * 32 + 8 * q];
    *(float4*)&wv[4] = *(const float4*)&whh[(size_t)(16 * gt + n) * 32 + 8 * q + 4];
    pack_hilo_(wv, Whi[gt], Wlo[gt]);
  }

  bf16x8 Bhi, Blo;
#pragma unroll
  for (int j = 0; j < 8; j++) { Bhi[j] = 0; Blo[j] = 0; }
  float cst[8];
#pragma unroll
  for (int i = 0; i < 8; i++) cst[i] = 0.f;

  float4 tc[8], tn[8];
  {
    int s0 = src_lds[0 * 16 + n];
    const float* gb = XW + (size_t)s0 * 128;
#pragma unroll
    for (int i = 0; i < 8; i++) tc[i] = *(const float4*)&gb[16 * i + 4 * q];
  }

  float hv[8];
#pragma unroll
  for (int d = 0; d < DEG; d++) {
    f32x4 D[4][2];
#pragma unroll
    for (int p = 0; p < 4; p++) {
#pragma unroll
      for (int hh = 0; hh < 2; hh++) {
        int gt = p * 2 + hh;
        f32x4 acc = {0.f, 0.f, 0.f, 0.f};
        acc = __builtin_amdgcn_mfma_f32_16x16x32_bf16(Whi[gt], Bhi, acc, 0, 0, 0);
        acc = __builtin_amdgcn_mfma_f32_16x16x32_bf16(Wlo[gt], Bhi, acc, 0, 0, 0);
        acc = __builtin_amdgcn_mfma_f32_16x16x32_bf16(Whi[gt], Blo, acc, 0, 0, 0);
        D[p][hh] = acc;
      }
    }
    if (d < DEG - 1) {
      int s = src_lds[(d + 1) * 16 + n];
      const float* gb = XW + (size_t)s * 128;
#pragma unroll
      for (int i = 0; i < 8; i++) tn[i] = *(const float4*)&gb[16 * i + 4 * q];
    }
#pragma unroll
    for (int hh = 0; hh < 2; hh++) {
      float4 xi = tc[0 + hh];
      float4 xf = tc[2 + hh];
      float4 xg = tc[4 + hh];
      float4 xo = tc[6 + hh];
#pragma unroll
      for (int r = 0; r < 4; r++) {
        float xiv = (r == 0) ? xi.x : (r == 1) ? xi.y : (r == 2) ? xi.z : xi.w;
        float xfv = (r == 0) ? xf.x : (r == 1) ? xf.y : (r == 2) ? xf.z : xf.w;
        float xgv = (r == 0) ? xg.x : (r == 1) ? xg.y : (r == 2) ? xg.z : xg.w;
        float xov = (r == 0) ? xo.x : (r == 1) ? xo.y : (r == 2) ? xo.z : xo.w;
        int ci = hh * 4 + r;
        float iv = sigmoidf_(D[0][hh][r] + xiv);
        float fv = sigmoidf_(D[1][hh][r] + xfv);
        float gv = tanhf_(D[2][hh][r] + xgv);
        float ov = sigmoidf_(D[3][hh][r] + xov);
        cst[ci] = fv * cst[ci] + iv * gv;
        hv[ci] = ov * tanhf_(cst[ci]);
      }
    }
    if (d < DEG - 1) {
      *(float4*)&h_lds[n * 36 + 0 + 4 * q] = make_float4(hv[0], hv[1], hv[2], hv[3]);
      *(float4*)&h_lds[n * 36 + 16 + 4 * q] = make_float4(hv[4], hv[5], hv[6], hv[7]);
      float hb[8];
      *(float4*)&hb[0] = *(const float4*)&h_lds[n * 36 + 8 * q];
      *(float4*)&hb[4] = *(const float4*)&h_lds[n * 36 + 8 * q + 4];
      pack_hilo_(hb, Bhi, Blo);
#pragma unroll
      for (int i = 0; i < 8; i++) tc[i] = tn[i];
    }
  }
  *(float4*)&hn_out[(size_t)(n0 + n) * 32 + 0 + 4 * q] = make_float4(hv[0], hv[1], hv[2], hv[3]);
  *(float4*)&hn_out[(size_t)(n0 + n) * 32 + 16 + 4 * q] = make_float4(hv[4], hv[5], hv[6], hv[7]);
}

// ---------------------------------------------------------------------------
// SAGE output (R0-exact): out = relu(in@wself + hn@wneigh + b)
// ---------------------------------------------------------------------------
template <int FI>
__global__ __launch_bounds__(256) void sage_out_kernel(const float* __restrict__ in,
                                                       const float* __restrict__ hn,
                                                       const float* __restrict__ wself,
                                                       const float* __restrict__ wneigh,
                                                       const float* __restrict__ bias,
                                                       float* __restrict__ out) {
  __shared__ float ws_s[FI * 32];
  __shared__ float wn_s[FI * 32];
  __shared__ float b_s[32];
  for (int idx = threadIdx.x; idx < FI * 32; idx += 256) {
    ws_s[idx] = wself[idx];
    wn_s[idx] = wneigh[idx];
  }
  if (threadIdx.x < 32) b_s[threadIdx.x] = bias[threadIdx.x];
  __syncthreads();
  const int n = blockIdx.x * 8 + (threadIdx.x >> 5);
  const int j = threadIdx.x & 31;
  float a = b_s[j];
#pragma unroll
  for (int k = 0; k < FI; k++) a += in[(size_t)n * FI + k] * ws_s[k * 32 + j];
#pragma unroll
  for (int k = 0; k < FI; k++) a += hn[(size_t)n * FI + k] * wn_s[k * 32 + j];
  out[(size_t)n * 32 + j] = fmaxf(a, 0.f);
}

// ---------------------------------------------------------------------------
// Final MLP (R0-exact).
// ---------------------------------------------------------------------------
__global__ __attribute__((amdgpu_waves_per_eu(4, 4))) __launch_bounds__(256)
void final_kernel(const float* __restrict__ gat,
                  const float* __restrict__ x2,
                  const float* __restrict__ f1w,
                  const float* __restrict__ f1b,
                  const float* __restrict__ f2w,
                  const float* __restrict__ f2b,
                  float* __restrict__ out) {
  __shared__ float w1_s[64 * 16];
  __shared__ float b1_s[16];
  __shared__ float w2_s[16];
  for (int idx = threadIdx.x; idx < 1024; idx += 256) w1_s[idx] = f1w[idx];
  if (threadIdx.x < 16) {
    b1_s[threadIdx.x] = f1b[threadIdx.x];
    w2_s[threadIdx.x] = f2w[threadIdx.x];
  }
  __syncthreads();
  const int n = blockIdx.x * 256 + threadIdx.x;
  float z[64];
#pragma unroll
  for (int k = 0; k < 32; k += 4) {
    float4 a = *(const float4*)&gat[(size_t)n * 32 + k];
    z[k] = a.x; z[k + 1] = a.y; z[k + 2] = a.z; z[k + 3] = a.w;
    float4 b = *(const float4*)&x2[(size_t)n * 32 + k];
    z[32 + k] = b.x; z[32 + k + 1] = b.y; z[32 + k + 2] = b.z; z[32 + k + 3] = b.w;
  }
  float o = f2b[0];
#pragma unroll
  for (int j = 0; j < 16; j++) {
    float a = b1_s[j];
#pragma unroll
    for (int k = 0; k < 64; k++) a += z[k] * w1_s[k * 16 + j];
    o += fmaxf(a, 0.f) * w2_s[j];
  }
  out[n] = o;
}

extern "C" void kernel_launch(void* const* d_in, const int* in_sizes, int n_in,
                              void* d_out, int out_size, void* d_ws, size_t ws_size,
                              hipStream_t stream) {
  const int N = NNODES;
  const float* feat = (const float*)d_in[0];
  const int* src = (const int*)d_in[1];
  const float* g0_ws = (const float*)d_in[2];
  const float* g0_bs = (const float*)d_in[3];
  const float* g0_wd = (const float*)d_in[4];
  const float* g0_bd = (const float*)d_in[5];
  const float* g0_attn = (const float*)d_in[6];
  const float* g0_bias = (const float*)d_in[7];
  const float* l0_w = (const float*)d_in[8];
  const float* l0_b = (const float*)d_in[9];
  const float* g1_ws = (const float*)d_in[10];
  const float* g1_bs = (const float*)d_in[11];
  const float* g1_wd = (const float*)d_in[12];
  const float* g1_bd = (const float*)d_in[13];
  const float* g1_attn = (const float*)d_in[14];
  const float* g1_bias = (const float*)d_in[15];
  const float* l1_w = (const float*)d_in[16];
  const float* l1_b = (const float*)d_in[17];
  const float* g2_ws = (const float*)d_in[18];
  const float* g2_bs = (const float*)d_in[19];
  const float* g2_wd = (const float*)d_in[20];
  const float* g2_bd = (const float*)d_in[21];
  const float* g2_attn = (const float*)d_in[22];
  const float* g2_bias = (const float*)d_in[23];
  const float* l2_w = (const float*)d_in[24];
  const float* l2_b = (const float*)d_in[25];
  const float* s1_wih = (const float*)d_in[26];
  const float* s1_whh = (const float*)d_in[27];
  const float* s1_b = (const float*)d_in[28];
  const float* s1_wself = (const float*)d_in[29];
  const float* s1_wneigh = (const float*)d_in[30];
  const float* s1_bias = (const float*)d_in[31];
  const float* s2_wih = (const float*)d_in[32];
  const float* s2_whh = (const float*)d_in[33];
  const float* s2_b = (const float*)d_in[34];
  const float* s2_wself = (const float*)d_in[35];
  const float* s2_wneigh = (const float*)d_in[36];
  const float* s2_bias = (const float*)d_in[37];
  const float* f1_w = (const float*)d_in[38];
  const float* f1_b = (const float*)d_in[39];
  const float* f2_w = (const float*)d_in[40];
  const float* f2_b = (const float*)d_in[41];

  float* A = (float*)d_ws;                // N*128
  float* B = A + (size_t)N * 128;
  float* C = B + (size_t)N * 128;
  float* D = C + (size_t)N * 128;
  float* E = D + (size_t)N * 128;         // A..E = 84 MB
  short* Wp = (short*)(A + (size_t)5 * N * 128);  // packed bf16 weights, 262 KB

  // 1. startup: fc3 layer0 (A=fs, B=fd, C=lin) + repack 7 weight matrices
  startup_kernel<<<6151, 256, 0, stream>>>(
      feat, g0_ws, g0_bs, g0_wd, g0_bd, l0_w, l0_b, A, B, C,
      g1_ws, g1_wd, l1_w, g2_ws, g2_wd, l2_w, s2_wih, Wp);
  // 2. GAT layer 0 -> D = h1
  gat4_kernel<<<N / 4, 256, 0, stream>>>(A, B, C, src, g0_attn, g0_bias, D);
  // 3. layer-1 FC trio (MFMA) -> A,B,C
  mfma_fc_kernel<4, 8, 3><<<N / 64, 256, 0, stream>>>(
      D, Wp + WP_G1, g1_bs, g1_bd, l1_b, A, B, C);
  // 4. GAT layer 1 -> E = h2
  gat4_kernel<<<N / 4, 256, 0, stream>>>(A, B, C, src, g1_attn, g1_bias, E);
  // 5. layer-2 FC trio (MFMA) -> A,B,C  (N x 32 each)
  mfma_fc_kernel<4, 2, 3><<<N / 64, 256, 0, stream>>>(
      E, Wp + WP_G2, g2_bs, g2_bd, l2_b, A, B, C);
  // 6. GAT layer 2 -> D = gat [N,32]; + fused fw1 -> E = FW1 [N,20]
  gat1_fw1_kernel<<<2048 + 128, 256, 0, stream>>>(
      A, B, C, src, g2_attn, g2_bias, D, feat, s1_wih, s1_b, E);
  // 7. SAGE-1 LSTM + projection -> C = x1 [N,32]
  lstm1s_kernel<<<N / 256, 256, 0, stream>>>(E, src, s1_whh, feat, s1_wself,
                                             s1_wneigh, s1_bias, C);
  // 8. XW2 = x1 @ wih.T + b -> A [N,128]
  mfma_fc_kernel<1, 8, 1><<<N / 64, 256, 0, stream>>>(
      C, Wp + WP_S2WIH, s2_b, nullptr, nullptr, A, nullptr, nullptr);
  // 9. SAGE-2 LSTM -> E = hn2 [N,32]
  lstm2_mfma_kernel<<<N / 64, 256, 0, stream>>>(A, src, s2_whh, E);
  // 10. sage_out (fp32, exact) -> B = x2 [N,32]
  sage_out_kernel<32><<<N / 8, 256, 0, stream>>>(C, E, s2_wself, s2_wneigh,
                                                 s2_bias, B);
  // 11. final MLP -> out
  final_kernel<<<N / 256, 256, 0, stream>>>(D, B, f1_w, f1_b, f2_w, f2_b, (float*)d_out);
}

// Round 4
// 415.816 us; speedup vs baseline: 1.2224x; 1.0267x over previous
//
#include <hip/hip_runtime.h>
#include <hip/hip_bf16.h>

#define NNODES 32768
#define DEG 16

__device__ __forceinline__ float sigmoidf_(float x) { return 1.f / (1.f + __expf(-x)); }
__device__ __forceinline__ float tanhf_(float x) { return 1.f - 2.f / (__expf(2.f * x) + 1.f); }

typedef __attribute__((ext_vector_type(8))) short bf16x8;
typedef __attribute__((ext_vector_type(4))) float f32x4;
typedef __attribute__((ext_vector_type(8))) _Float16 f16x8;

__device__ __forceinline__ unsigned short f2bf_(float x) {
  __hip_bfloat16 b = __float2bfloat16(x);
  union { __hip_bfloat16 b; unsigned short u; } cv;
  cv.b = b;
  return cv.u;
}
__device__ __forceinline__ float bf2f_(unsigned short u) {
  union { unsigned short u; __hip_bfloat16 b; } cv;
  cv.u = u;
  return __bfloat162float(cv.b);
}
__device__ __forceinline__ void pack_hilo_(const float* v, bf16x8& hi, bf16x8& lo) {
#pragma unroll
  for (int j = 0; j < 8; j++) {
    unsigned short h = f2bf_(v[j]);
    float resid = v[j] - bf2f_(h);
    hi[j] = (short)h;
    lo[j] = (short)f2bf_(resid);
  }
}

// Packed-weight offsets (shorts); hi block then lo block per matrix.
#define WP_G1    0        // 3 x (128x128): stride 32768
#define WP_G2    98304    // 3 x (128x32):  stride 8192
#define WP_S2WIH 122880   // 32x128 (transposed use)
#define WP_TOTAL 131072

// ---------------------------------------------------------------------------
// Startup mega-kernel: [0,6144) = fc3 layer0; [6144,6151) = weight repack.
// R0-exact.
// ---------------------------------------------------------------------------
__global__ __launch_bounds__(256) void startup_kernel(
    const float* __restrict__ feat,
    const float* __restrict__ W0, const float* __restrict__ B0,
    const float* __restrict__ W1, const float* __restrict__ B1,
    const float* __restrict__ W2, const float* __restrict__ B2,
    float* __restrict__ O0, float* __restrict__ O1, float* __restrict__ O2,
    const float* __restrict__ g1ws, const float* __restrict__ g1wd,
    const float* __restrict__ l1w, const float* __restrict__ g2ws,
    const float* __restrict__ g2wd, const float* __restrict__ l2w,
    const float* __restrict__ s2wih, short* __restrict__ Wp) {
  __shared__ float w_s[5 * 64];
  __shared__ float in_s[32 * 8];
  __shared__ float b_s[64];
  const int bid = blockIdx.x;
  const int t = threadIdx.x;
  if (bid < 6144) {
    const int bz = bid >> 11, rem = bid & 2047, by = rem >> 10, bx = rem & 1023;
    const float* W = (bz == 0) ? W0 : (bz == 1) ? W1 : W2;
    const float* bias = (bz == 0) ? B0 : (bz == 1) ? B1 : B2;
    float* out = (bz == 0) ? O0 : (bz == 1) ? O1 : O2;
    const int rowBase = bx * 32;
    const int colBase = by * 64;
    for (int idx = t; idx < 5 * 64; idx += 256) {
      int k = idx >> 6, jj = idx & 63;
      w_s[idx] = W[(size_t)k * 128 + colBase + jj];
    }
    if (t < 64) b_s[t] = bias[colBase + t];
    for (int idx = t; idx < 32 * 5; idx += 256) {
      int r = idx / 5, k = idx - r * 5;
      in_s[r * 8 + k] = feat[(size_t)(rowBase + r) * 5 + k];
    }
    __syncthreads();
    const int jj = t & 63;
    const int rslot = t >> 6;
    float acc[8];
#pragma unroll
    for (int r = 0; r < 8; r++) acc[r] = b_s[jj];
    {
      float wv0 = w_s[0 * 64 + jj], wv1 = w_s[1 * 64 + jj];
      float wv2 = w_s[2 * 64 + jj], wv3 = w_s[3 * 64 + jj];
#pragma unroll
      for (int r = 0; r < 8; r++) {
        float4 ip = *(const float4*)&in_s[(rslot * 8 + r) * 8];
        acc[r] += ip.x * wv0 + ip.y * wv1 + ip.z * wv2 + ip.w * wv3;
      }
      float wv4 = w_s[4 * 64 + jj];
#pragma unroll
      for (int r = 0; r < 8; r++) acc[r] += in_s[(rslot * 8 + r) * 8 + 4] * wv4;
    }
#pragma unroll
    for (int r = 0; r < 8; r++)
      out[(size_t)(rowBase + rslot * 8 + r) * 128 + colBase + jj] = acc[r];
  } else {
    const int mid = bid - 6144;
    const float* W;
    int FI, FO, TRANS;
    size_t base;
    if (mid == 0)      { W = g1ws;  FI = 128; FO = 128; TRANS = 0; base = WP_G1; }
    else if (mid == 1) { W = g1wd;  FI = 128; FO = 128; TRANS = 0; base = WP_G1 + 32768; }
    else if (mid == 2) { W = l1w;   FI = 128; FO = 128; TRANS = 0; base = WP_G1 + 65536; }
    else if (mid == 3) { W = g2ws;  FI = 128; FO = 32;  TRANS = 0; base = WP_G2; }
    else if (mid == 4) { W = g2wd;  FI = 128; FO = 32;  TRANS = 0; base = WP_G2 + 8192; }
    else if (mid == 5) { W = l2w;   FI = 128; FO = 32;  TRANS = 0; base = WP_G2 + 16384; }
    else               { W = s2wih; FI = 32;  FO = 128; TRANS = 1; base = WP_S2WIH; }
    const int KS = FI / 32;
    const int total = FI * FO;
    for (int p = t; p < total; p += 256) {
      int j = p & 7, lane = (p >> 3) & 63, rest = p >> 9;
      int ks = rest % KS, f = rest / KS;
      int n = lane & 15, q = lane >> 4;
      int k = 32 * ks + 8 * q + j, fo = 16 * f + n;
      float v = TRANS ? W[(size_t)fo * FI + k] : W[(size_t)k * FO + fo];
      unsigned short hi = f2bf_(v);
      float resid = v - bf2f_(hi);
      Wp[base + p] = (short)hi;
      Wp[base + total + p] = (short)f2bf_(resid);
    }
  }
}

// ---------------------------------------------------------------------------
// MFMA FC (R0-exact).
// ---------------------------------------------------------------------------
template <int KS, int FOT, int NZ>  // FI=32*KS, FO=16*FOT
__global__ __launch_bounds__(256) __attribute__((amdgpu_waves_per_eu(1, 4)))
void mfma_fc_kernel(const float* __restrict__ in, const short* __restrict__ Wp,
                    const float* __restrict__ B0, const float* __restrict__ B1,
                    const float* __restrict__ B2, float* __restrict__ O0,
                    float* __restrict__ O1, float* __restrict__ O2) {
  constexpr int FI = 32 * KS;
  constexpr int FO = 16 * FOT;
  const int tid = threadIdx.x;
  const int wid = tid >> 6;
  const int lane = tid & 63;
  const int q = lane >> 4, n = lane & 15;
  const int n0 = blockIdx.x * 64 + wid * 16;
  bf16x8 Ahi[KS], Alo[KS];
#pragma unroll
  for (int ks = 0; ks < KS; ks++) {
    float av[8];
    *(float4*)&av[0] = *(const float4*)&in[(size_t)(n0 + n) * FI + 32 * ks + 8 * q];
    *(float4*)&av[4] = *(const float4*)&in[(size_t)(n0 + n) * FI + 32 * ks + 8 * q + 4];
    pack_hilo_(av, Ahi[ks], Alo[ks]);
  }
#pragma unroll
  for (int z = 0; z < NZ; z++) {
    const short* wz = Wp + (size_t)z * FI * FO * 2;
    const float* bz = (z == 0) ? B0 : (z == 1) ? B1 : B2;
    float* oz = (z == 0) ? O0 : (z == 1) ? O1 : O2;
#pragma unroll
    for (int f = 0; f < FOT; f++) {
      float bv = bz[16 * f + n];
      f32x4 acc = {bv, bv, bv, bv};
#pragma unroll
      for (int ks = 0; ks < KS; ks++) {
        bf16x8 Bhi = *(const bf16x8*)&wz[((size_t)(f * KS + ks) * 64 + lane) * 8];
        bf16x8 Blo = *(const bf16x8*)&wz[(size_t)FI * FO + ((size_t)(f * KS + ks) * 64 + lane) * 8];
        acc = __builtin_amdgcn_mfma_f32_16x16x32_bf16(Ahi[ks], Bhi, acc, 0, 0, 0);
        acc = __builtin_amdgcn_mfma_f32_16x16x32_bf16(Alo[ks], Bhi, acc, 0, 0, 0);
        acc = __builtin_amdgcn_mfma_f32_16x16x32_bf16(Ahi[ks], Blo, acc, 0, 0, 0);
      }
#pragma unroll
      for (int r = 0; r < 4; r++)
        oz[(size_t)(n0 + 4 * q + r) * FO + 16 * f + n] = acc[r];
    }
  }
}

// ---------------------------------------------------------------------------
// XW writer (R4): same arithmetic as mfma_fc_body<1,8,1> (bias init + 3-MFMA
// hi/lo), but output stored as fp16 in a per-thread-contiguous PERMUTED
// layout: XWh[node*128 + (g>>2 & 3)*32 + (g>>4)*4 + (g&3)] for gate dim g.
// lstm2's thread (n,q) then reads halves [q*32, q*32+32) = 64 B contiguous.
// Only intended numeric change: fp16 RNE rounding of XW (|XW| ~ 0.1-0.5,
// abs err <= ~2.5e-4, enters gates via fp32 add).
// ---------------------------------------------------------------------------
__global__ __launch_bounds__(256) __attribute__((amdgpu_waves_per_eu(1, 4)))
void xw_half_kernel(const float* __restrict__ in, const short* __restrict__ Wp,
                    const float* __restrict__ bz, _Float16* __restrict__ XWh) {
  const int tid = threadIdx.x;
  const int wid = tid >> 6;
  const int lane = tid & 63;
  const int q = lane >> 4, n = lane & 15;
  const int n0 = blockIdx.x * 64 + wid * 16;
  bf16x8 Ahi, Alo;
  {
    float av[8];
    *(float4*)&av[0] = *(const float4*)&in[(size_t)(n0 + n) * 32 + 8 * q];
    *(float4*)&av[4] = *(const float4*)&in[(size_t)(n0 + n) * 32 + 8 * q + 4];
    pack_hilo_(av, Ahi, Alo);
  }
#pragma unroll
  for (int f = 0; f < 8; f++) {
    float bv = bz[16 * f + n];
    f32x4 acc = {bv, bv, bv, bv};
    bf16x8 Bhi = *(const bf16x8*)&Wp[((size_t)f * 64 + lane) * 8];
    bf16x8 Blo = *(const bf16x8*)&Wp[4096 + ((size_t)f * 64 + lane) * 8];
    acc = __builtin_amdgcn_mfma_f32_16x16x32_bf16(Ahi, Bhi, acc, 0, 0, 0);
    acc = __builtin_amdgcn_mfma_f32_16x16x32_bf16(Alo, Bhi, acc, 0, 0, 0);
    acc = __builtin_amdgcn_mfma_f32_16x16x32_bf16(Ahi, Blo, acc, 0, 0, 0);
    // gate dim g = 16*f + n; perm(g) = (n>>2)*32 + f*4 + (n&3)
#pragma unroll
    for (int r = 0; r < 4; r++)
      XWh[(size_t)(n0 + 4 * q + r) * 128 + ((n >> 2) * 32 + f * 4 + (n & 3))] =
          (_Float16)acc[r];
  }
}

// ---------------------------------------------------------------------------
// GATv2 H=4 (R0-exact).
// ---------------------------------------------------------------------------
__global__ __launch_bounds__(256) void gat4_kernel(const float* __restrict__ fs,
                                                   const float* __restrict__ fd,
                                                   const float* __restrict__ lin,
                                                   const int* __restrict__ src,
                                                   const float* __restrict__ attn,
                                                   const float* __restrict__ bias,
                                                   float* __restrict__ out) {
  constexpr int F = 128;
  const int lane = threadIdx.x & 63;
  const int wave = threadIdx.x >> 6;
  const int li = lane & 15;
  const int node = blockIdx.x * 4 + wave;
  const int f0 = 2 * lane;
  const int srcv = src[(size_t)node * DEG + li];
  const float2 fdv = *(const float2*)&fd[(size_t)node * F + f0];
  const float a0 = attn[f0];
  const float a1 = attn[f0 + 1];
  float m = -1e30f, s = 0.f, acc0 = 0.f, acc1 = 0.f;
  int sd = __shfl(srcv, (lane & 48), 64);
  float2 fsv = *(const float2*)&fs[(size_t)sd * F + f0];
#pragma unroll
  for (int d = 0; d < DEG; d++) {
    float2 cur = fsv;
    if (d < DEG - 1) {
      int sn = __shfl(srcv, (lane & 48) | (d + 1), 64);
      fsv = *(const float2*)&fs[(size_t)sn * F + f0];
    }
    float e0 = cur.x + fdv.x; e0 = (e0 > 0.f) ? e0 : 0.2f * e0;
    float e1 = cur.y + fdv.y; e1 = (e1 > 0.f) ? e1 : 0.2f * e1;
    float p = e0 * a0 + e1 * a1;
    p += __shfl_xor(p, 1, 64);
    p += __shfl_xor(p, 2, 64);
    p += __shfl_xor(p, 4, 64);
    p += __shfl_xor(p, 8, 64);
    float nm = fmaxf(m, p);
    float ex = __expf(p - nm);
    float sc = __expf(m - nm);
    s = s * sc + ex;
    acc0 = acc0 * sc + ex * cur.x;
    acc1 = acc1 * sc + ex * cur.y;
    m = nm;
  }
  float inv = 1.f / s;
  float2 lv = *(const float2*)&lin[(size_t)node * F + f0];
  float o0 = acc0 * inv + lv.x + bias[f0];
  float o1 = acc1 * inv + lv.y + bias[f0 + 1];
  o0 = (o0 > 0.f) ? o0 : __expf(o0) - 1.f;
  o1 = (o1 > 0.f) ? o1 : __expf(o1) - 1.f;
  *(float2*)&out[(size_t)node * F + f0] = make_float2(o0, o1);
}

// ---------------------------------------------------------------------------
// GATv2 H=1 (no ELU) + fused fw1 (R0-exact).
// ---------------------------------------------------------------------------
__global__ __launch_bounds__(256) void gat1_fw1_kernel(
    const float* __restrict__ fs, const float* __restrict__ fd,
    const float* __restrict__ lin, const int* __restrict__ src,
    const float* __restrict__ attn, const float* __restrict__ bias,
    float* __restrict__ out, const float* __restrict__ feat,
    const float* __restrict__ wih, const float* __restrict__ wb,
    float* __restrict__ fwout) {
  __shared__ float w_s[100];
  __shared__ float b_s[20];
  if (blockIdx.x < 2048) {
    constexpr int F = 32;
    const int lane = threadIdx.x & 63;
    const int wave = threadIdx.x >> 6;
    const int G = lane >> 4, li = lane & 15;
    const int node = blockIdx.x * 16 + wave * 4 + G;
    const int f0 = 2 * li;
    const int srcv = src[(size_t)node * DEG + li];
    const float2 fdv = *(const float2*)&fd[(size_t)node * F + f0];
    const float a0 = attn[f0];
    const float a1 = attn[f0 + 1];
    float m = -1e30f, s = 0.f, acc0 = 0.f, acc1 = 0.f;
    int sd = __shfl(srcv, (lane & 48), 64);
    float2 fsv = *(const float2*)&fs[(size_t)sd * F + f0];
#pragma unroll
    for (int d = 0; d < DEG; d++) {
      float2 cur = fsv;
      if (d < DEG - 1) {
        int sn = __shfl(srcv, (lane & 48) | (d + 1), 64);
        fsv = *(const float2*)&fs[(size_t)sn * F + f0];
      }
      float e0 = cur.x + fdv.x; e0 = (e0 > 0.f) ? e0 : 0.2f * e0;
      float e1 = cur.y + fdv.y; e1 = (e1 > 0.f) ? e1 : 0.2f * e1;
      float p = e0 * a0 + e1 * a1;
      p += __shfl_xor(p, 1, 64);
      p += __shfl_xor(p, 2, 64);
      p += __shfl_xor(p, 4, 64);
      p += __shfl_xor(p, 8, 64);
      float nm = fmaxf(m, p);
      float ex = __expf(p - nm);
      float sc = __expf(m - nm);
      s = s * sc + ex;
      acc0 = acc0 * sc + ex * cur.x;
      acc1 = acc1 * sc + ex * cur.y;
      m = nm;
    }
    float inv = 1.f / s;
    float2 lv = *(const float2*)&lin[(size_t)node * F + f0];
    float o0 = acc0 * inv + lv.x + bias[f0];
    float o1 = acc1 * inv + lv.y + bias[f0 + 1];
    *(float2*)&out[(size_t)node * F + f0] = make_float2(o0, o1);
  } else {
    if (threadIdx.x < 100) w_s[threadIdx.x] = wih[threadIdx.x];
    if (threadIdx.x < 20) b_s[threadIdx.x] = wb[threadIdx.x];
    __syncthreads();
    const int n = (blockIdx.x - 2048) * 256 + threadIdx.x;
    float f[5];
#pragma unroll
    for (int k = 0; k < 5; k++) f[k] = feat[(size_t)n * 5 + k];
#pragma unroll
    for (int j = 0; j < 20; j++) {
      float a = b_s[j];
#pragma unroll
      for (int k = 0; k < 5; k++) a += f[k] * w_s[j * 5 + k];
      fwout[(size_t)n * 20 + j] = a;
    }
  }
}

// ---------------------------------------------------------------------------
// SAGE-1: LSTM + fused projection (R0-exact).
// ---------------------------------------------------------------------------
__global__ __attribute__((amdgpu_waves_per_eu(1, 4))) __launch_bounds__(256)
void lstm1s_kernel(const float* __restrict__ FW, const int* __restrict__ src,
                   const float* __restrict__ whh, const float* __restrict__ feat,
                   const float* __restrict__ wself, const float* __restrict__ wneigh,
                   const float* __restrict__ bias, float* __restrict__ x1out) {
  __shared__ float w_s[100];   // whh [20][5]
  __shared__ float ws_s[160];  // wself [5][32]
  __shared__ float wn_s[160];  // wneigh [5][32]
  __shared__ float b_s[32];
  if (threadIdx.x < 100) w_s[threadIdx.x] = whh[threadIdx.x];
  if (threadIdx.x < 160) {
    ws_s[threadIdx.x] = wself[threadIdx.x];
    wn_s[threadIdx.x] = wneigh[threadIdx.x];
  }
  if (threadIdx.x < 32) b_s[threadIdx.x] = bias[threadIdx.x];
  __syncthreads();
  const int n = blockIdx.x * 256 + threadIdx.x;
  const int* sp = src + (size_t)n * DEG;
  float f[5];
#pragma unroll
  for (int k = 0; k < 5; k++) f[k] = feat[(size_t)n * 5 + k];
  float h[5] = {0, 0, 0, 0, 0}, c[5] = {0, 0, 0, 0, 0};
  int sd = sp[0];
  float4 p0 = *(const float4*)&FW[(size_t)sd * 20 + 0];
  float4 p1 = *(const float4*)&FW[(size_t)sd * 20 + 4];
  float4 p2 = *(const float4*)&FW[(size_t)sd * 20 + 8];
  float4 p3 = *(const float4*)&FW[(size_t)sd * 20 + 12];
  float4 p4 = *(const float4*)&FW[(size_t)sd * 20 + 16];
  for (int d = 0; d < DEG; d++) {
    float g[20];
    g[0] = p0.x; g[1] = p0.y; g[2] = p0.z; g[3] = p0.w;
    g[4] = p1.x; g[5] = p1.y; g[6] = p1.z; g[7] = p1.w;
    g[8] = p2.x; g[9] = p2.y; g[10] = p2.z; g[11] = p2.w;
    g[12] = p3.x; g[13] = p3.y; g[14] = p3.z; g[15] = p3.w;
    g[16] = p4.x; g[17] = p4.y; g[18] = p4.z; g[19] = p4.w;
    if (d < DEG - 1) {
      int sn = sp[d + 1];
      p0 = *(const float4*)&FW[(size_t)sn * 20 + 0];
      p1 = *(const float4*)&FW[(size_t)sn * 20 + 4];
      p2 = *(const float4*)&FW[(size_t)sn * 20 + 8];
      p3 = *(const float4*)&FW[(size_t)sn * 20 + 12];
      p4 = *(const float4*)&FW[(size_t)sn * 20 + 16];
    }
#pragma unroll
    for (int j = 0; j < 20; j++) {
#pragma unroll
      for (int k = 0; k < 5; k++) g[j] += h[k] * w_s[j * 5 + k];
    }
#pragma unroll
    for (int k = 0; k < 5; k++) {
      float iv = sigmoidf_(g[k]);
      float fv = sigmoidf_(g[5 + k]);
      float gv = tanhf_(g[10 + k]);
      float ov = sigmoidf_(g[15 + k]);
      c[k] = fv * c[k] + iv * gv;
      h[k] = ov * tanhf_(c[k]);
    }
  }
#pragma unroll
  for (int j = 0; j < 32; j++) {
    float a = b_s[j];
#pragma unroll
    for (int k = 0; k < 5; k++) a += f[k] * ws_s[k * 32 + j] + h[k] * wn_s[k * 32 + j];
    x1out[(size_t)n * 32 + j] = fmaxf(a, 0.f);
  }
}

// ---------------------------------------------------------------------------
// SAGE-2 LSTM (MFMA) — R4: gathers fp16 PERMUTED XW rows (256 B/row, 64 B
// contiguous per thread, 4x16B loads vs 8x16B fp32). All other arithmetic
// (MFMA hi/lo h-part, gate adds, transcendentals, h LDS roundtrip) is
// R0-byte-exact. Gate xiv now rounds through fp16 (intended, bounded).
// ---------------------------------------------------------------------------
__global__ __launch_bounds__(256) __attribute__((amdgpu_waves_per_eu(1, 4)))
void lstm2_mfma_kernel(const _Float16* __restrict__ XW, const int* __restrict__ src,
                       const float* __restrict__ whh, float* __restrict__ hn_out) {
  __shared__ float h_lds_all[4 * 16 * 36];
  __shared__ int src_lds_all[4 * 256];
  const int tid = threadIdx.x;
  const int wid = tid >> 6;
  const int lane = tid & 63;
  const int q = lane >> 4;   // quad
  const int n = lane & 15;   // node within group / fragment col
  const int n0 = (blockIdx.x * 4 + wid) * 16;
  float* h_lds = &h_lds_all[wid * 16 * 36];
  int* src_lds = &src_lds_all[wid * 256];

  {
    int4 sv = *(const int4*)&src[(size_t)(n0 + (lane >> 2)) * DEG + 4 * (lane & 3)];
    src_lds[(4 * (lane & 3) + 0) * 16 + (lane >> 2)] = sv.x;
    src_lds[(4 * (lane & 3) + 1) * 16 + (lane >> 2)] = sv.y;
    src_lds[(4 * (lane & 3) + 2) * 16 + (lane >> 2)] = sv.z;
    src_lds[(4 * (lane & 3) + 3) * 16 + (lane >> 2)] = sv.w;
  }

  bf16x8 Whi[8], Wlo[8];
#pragma unroll
  for (int gt = 0; gt < 8; gt++) {
    float wv[8];
    *(float4*)&wv[0] = *(const float4*)&whh[(size_t)(16 * gt + n) * 32 + 8 * q];
    *(float4*)&wv[4] = *(const float4*)&whh[(size_t)(16 * gt + n) * 32 + 8 * q + 4];
    pack_hilo_(wv, Whi[gt], Wlo[gt]);
  }

  bf16x8 Bhi, Blo;
#pragma unroll
  for (int j = 0; j < 8; j++) { Bhi[j] = 0; Blo[j] = 0; }
  float cst[8];
#pragma unroll
  for (int i = 0; i < 8; i++) cst[i] = 0.f;

  // Thread (n,q) reads its node's permuted halves [q*32, q*32+32):
  // tch[t] half j: tc[2t + (j>>2)][j&3] in the old fp32 tc[] indexing.
  f16x8 tch[4], tnh[4];
  {
    int s0 = src_lds[0 * 16 + n];
    const _Float16* gb = XW + (size_t)s0 * 128 + q * 32;
#pragma unroll
    for (int t = 0; t < 4; t++) tch[t] = *(const f16x8*)&gb[8 * t];
  }

  float hv[8];
#pragma unroll
  for (int d = 0; d < DEG; d++) {
    f32x4 D[4][2];
#pragma unroll
    for (int p = 0; p < 4; p++) {
#pragma unroll
      for (int hh = 0; hh < 2; hh++) {
        int gt = p * 2 + hh;
        f32x4 acc = {0.f, 0.f, 0.f, 0.f};
        acc = __builtin_amdgcn_mfma_f32_16x16x32_bf16(Whi[gt], Bhi, acc, 0, 0, 0);
        acc = __builtin_amdgcn_mfma_f32_16x16x32_bf16(Wlo[gt], Bhi, acc, 0, 0, 0);
        acc = __builtin_amdgcn_mfma_f32_16x16x32_bf16(Whi[gt], Blo, acc, 0, 0, 0);
        D[p][hh] = acc;
      }
    }
    if (d < DEG - 1) {
      int s = src_lds[(d + 1) * 16 + n];
      const _Float16* gb = XW + (size_t)s * 128 + q * 32;
#pragma unroll
      for (int t = 0; t < 4; t++) tnh[t] = *(const f16x8*)&gb[8 * t];
    }
#pragma unroll
    for (int hh = 0; hh < 2; hh++) {
#pragma unroll
      for (int r = 0; r < 4; r++) {
        int ci = hh * 4 + r;
        // old tc[0+hh]/tc[2+hh]/tc[4+hh]/tc[6+hh] -> tch[0..3][hh*4+r]
        float xiv = (float)tch[0][hh * 4 + r];
        float xfv = (float)tch[1][hh * 4 + r];
        float xgv = (float)tch[2][hh * 4 + r];
        float xov = (float)tch[3][hh * 4 + r];
        float iv = sigmoidf_(D[0][hh][r] + xiv);
        float fv = sigmoidf_(D[1][hh][r] + xfv);
        float gv = tanhf_(D[2][hh][r] + xgv);
        float ov = sigmoidf_(D[3][hh][r] + xov);
        cst[ci] = fv * cst[ci] + iv * gv;
        hv[ci] = ov * tanhf_(cst[ci]);
      }
    }
    if (d < DEG - 1) {
      *(float4*)&h_lds[n * 36 + 0 + 4 * q] = make_float4(hv[0], hv[1], hv[2], hv[3]);
      *(float4*)&h_lds[n * 36 + 16 + 4 * q] = make_float4(hv[4], hv[5], hv[6], hv[7]);
      float hb[8];
      *(float4*)&hb[0] = *(const float4*)&h_lds[n * 36 + 8 * q];
      *(float4*)&hb[4] = *(const float4*)&h_lds[n * 36 + 8 * q + 4];
      pack_hilo_(hb, Bhi, Blo);
#pragma unroll
      for (int t = 0; t < 4; t++) tch[t] = tnh[t];
    }
  }
  *(float4*)&hn_out[(size_t)(n0 + n) * 32 + 0 + 4 * q] = make_float4(hv[0], hv[1], hv[2], hv[3]);
  *(float4*)&hn_out[(size_t)(n0 + n) * 32 + 16 + 4 * q] = make_float4(hv[4], hv[5], hv[6], hv[7]);
}

// ---------------------------------------------------------------------------
// R4: fused sage_out + final MLP. x2 was consumed only by final; each node's
// x2 row is computed in registers with the EXACT sage_out FMA order, then the
// EXACT final_kernel math runs on it (fp32 roundtrip through memory removed —
// values bitwise identical). 128 threads/block, 1 node/thread.
// ---------------------------------------------------------------------------
__global__ __launch_bounds__(128) void sage_final_kernel(
    const float* __restrict__ x1, const float* __restrict__ hn,
    const float* __restrict__ wself, const float* __restrict__ wneigh,
    const float* __restrict__ sbias, const float* __restrict__ gat,
    const float* __restrict__ f1w, const float* __restrict__ f1b,
    const float* __restrict__ f2w, const float* __restrict__ f2b,
    float* __restrict__ out) {
  __shared__ float ws_s[32 * 32];
  __shared__ float wn_s[32 * 32];
  __shared__ float b_s[32];
  __shared__ float w1_s[64 * 16];
  __shared__ float b1_s[16];
  __shared__ float w2_s[16];
  for (int idx = threadIdx.x; idx < 1024; idx += 128) {
    ws_s[idx] = wself[idx];
    wn_s[idx] = wneigh[idx];
    w1_s[idx] = f1w[idx];
  }
  if (threadIdx.x < 32) b_s[threadIdx.x] = sbias[threadIdx.x];
  if (threadIdx.x < 16) {
    b1_s[threadIdx.x] = f1b[threadIdx.x];
    w2_s[threadIdx.x] = f2w[threadIdx.x];
  }
  __syncthreads();
  const int n = blockIdx.x * 128 + threadIdx.x;
  float xr[32], hr[32], z[64];
#pragma unroll
  for (int k = 0; k < 32; k += 4) {
    *(float4*)&xr[k] = *(const float4*)&x1[(size_t)n * 32 + k];
    *(float4*)&hr[k] = *(const float4*)&hn[(size_t)n * 32 + k];
    float4 a = *(const float4*)&gat[(size_t)n * 32 + k];
    z[k] = a.x; z[k + 1] = a.y; z[k + 2] = a.z; z[k + 3] = a.w;
  }
  // sage_out (exact order): a = b + sum_k x1*ws + sum_k hn*wn; relu
#pragma unroll
  for (int j = 0; j < 32; j++) {
    float a = b_s[j];
#pragma unroll
    for (int k = 0; k < 32; k++) a += xr[k] * ws_s[k * 32 + j];
#pragma unroll
    for (int k = 0; k < 32; k++) a += hr[k] * wn_s[k * 32 + j];
    z[32 + j] = fmaxf(a, 0.f);
  }
  // final (exact)
  float o = f2b[0];
#pragma unroll
  for (int j = 0; j < 16; j++) {
    float a = b1_s[j];
#pragma unroll
    for (int k = 0; k < 64; k++) a += z[k] * w1_s[k * 16 + j];
    o += fmaxf(a, 0.f) * w2_s[j];
  }
  out[n] = o;
}

extern "C" void kernel_launch(void* const* d_in, const int* in_sizes, int n_in,
                              void* d_out, int out_size, void* d_ws, size_t ws_size,
                              hipStream_t stream) {
  const int N = NNODES;
  const float* feat = (const float*)d_in[0];
  const int* src = (const int*)d_in[1];
  const float* g0_ws = (const float*)d_in[2];
  const float* g0_bs = (const float*)d_in[3];
  const float* g0_wd = (const float*)d_in[4];
  const float* g0_bd = (const float*)d_in[5];
  const float* g0_attn = (const float*)d_in[6];
  const float* g0_bias = (const float*)d_in[7];
  const float* l0_w = (const float*)d_in[8];
  const float* l0_b = (const float*)d_in[9];
  const float* g1_ws = (const float*)d_in[10];
  const float* g1_bs = (const float*)d_in[11];
  const float* g1_wd = (const float*)d_in[12];
  const float* g1_bd = (const float*)d_in[13];
  const float* g1_attn = (const float*)d_in[14];
  const float* g1_bias = (const float*)d_in[15];
  const float* l1_w = (const float*)d_in[16];
  const float* l1_b = (const float*)d_in[17];
  const float* g2_ws = (const float*)d_in[18];
  const float* g2_bs = (const float*)d_in[19];
  const float* g2_wd = (const float*)d_in[20];
  const float* g2_bd = (const float*)d_in[21];
  const float* g2_attn = (const float*)d_in[22];
  const float* g2_bias = (const float*)d_in[23];
  const float* l2_w = (const float*)d_in[24];
  const float* l2_b = (const float*)d_in[25];
  const float* s1_wih = (const float*)d_in[26];
  const float* s1_whh = (const float*)d_in[27];
  const float* s1_b = (const float*)d_in[28];
  const float* s1_wself = (const float*)d_in[29];
  const float* s1_wneigh = (const float*)d_in[30];
  const float* s1_bias = (const float*)d_in[31];
  const float* s2_wih = (const float*)d_in[32];
  const float* s2_whh = (const float*)d_in[33];
  const float* s2_b = (const float*)d_in[34];
  const float* s2_wself = (const float*)d_in[35];
  const float* s2_wneigh = (const float*)d_in[36];
  const float* s2_bias = (const float*)d_in[37];
  const float* f1_w = (const float*)d_in[38];
  const float* f1_b = (const float*)d_in[39];
  const float* f2_w = (const float*)d_in[40];
  const float* f2_b = (const float*)d_in[41];

  float* A = (float*)d_ws;                // N*128
  float* B = A + (size_t)N * 128;
  float* C = B + (size_t)N * 128;
  float* D = C + (size_t)N * 128;
  float* E = D + (size_t)N * 128;         // A..E = 84 MB
  short* Wp = (short*)(A + (size_t)5 * N * 128);  // packed bf16 weights, 262 KB

  // 1. startup: fc3 layer0 (A=fs, B=fd, C=lin) + repack 7 weight matrices
  startup_kernel<<<6151, 256, 0, stream>>>(
      feat, g0_ws, g0_bs, g0_wd, g0_bd, l0_w, l0_b, A, B, C,
      g1_ws, g1_wd, l1_w, g2_ws, g2_wd, l2_w, s2_wih, Wp);
  // 2. GAT layer 0 -> D = h1
  gat4_kernel<<<N / 4, 256, 0, stream>>>(A, B, C, src, g0_attn, g0_bias, D);
  // 3. layer-1 FC trio (MFMA) -> A,B,C
  mfma_fc_kernel<4, 8, 3><<<N / 64, 256, 0, stream>>>(
      D, Wp + WP_G1, g1_bs, g1_bd, l1_b, A, B, C);
  // 4. GAT layer 1 -> E = h2
  gat4_kernel<<<N / 4, 256, 0, stream>>>(A, B, C, src, g1_attn, g1_bias, E);
  // 5. layer-2 FC trio (MFMA) -> A,B,C  (N x 32 each)
  mfma_fc_kernel<4, 2, 3><<<N / 64, 256, 0, stream>>>(
      E, Wp + WP_G2, g2_bs, g2_bd, l2_b, A, B, C);
  // 6. GAT layer 2 -> D = gat [N,32]; + fused fw1 -> E = FW1 [N,20]
  gat1_fw1_kernel<<<2048 + 128, 256, 0, stream>>>(
      A, B, C, src, g2_attn, g2_bias, D, feat, s1_wih, s1_b, E);
  // 7. SAGE-1 LSTM + projection -> C = x1 [N,32]
  lstm1s_kernel<<<N / 256, 256, 0, stream>>>(E, src, s1_whh, feat, s1_wself,
                                             s1_wneigh, s1_bias, C);
  // 8. XW2 = x1 @ wih.T + b -> A as fp16 permuted [N,128]
  xw_half_kernel<<<N / 64, 256, 0, stream>>>(
      C, Wp + WP_S2WIH, s2_b, (_Float16*)A);
  // 9. SAGE-2 LSTM -> E = hn2 [N,32]
  lstm2_mfma_kernel<<<N / 64, 256, 0, stream>>>((const _Float16*)A, src, s2_whh, E);
  // 10. fused sage_out + final MLP -> out
  sage_final_kernel<<<N / 128, 128, 0, stream>>>(
      C, E, s2_wself, s2_wneigh, s2_bias, D, f1_w, f1_b, f2_w, f2_b,
      (float*)d_out);
}

// Round 5
// 381.930 us; speedup vs baseline: 1.3309x; 1.0887x over previous
//
#include <hip/hip_runtime.h>
#include <hip/hip_bf16.h>

#define NNODES 32768
#define DEG 16

// R5: fast sigmoid/tanh — replace IEEE div (~8-14 inst chain without
// -ffast-math) with v_rcp_f32 (1 inst, ~1 ulp). Gate-output error ~1e-7.
__device__ __forceinline__ float sigmoidf_(float x) {
  return __builtin_amdgcn_rcpf(1.f + __expf(-x));
}
__device__ __forceinline__ float tanhf_(float x) {
  return 1.f - 2.f * __builtin_amdgcn_rcpf(__expf(2.f * x) + 1.f);
}

typedef __attribute__((ext_vector_type(8))) short bf16x8;
typedef __attribute__((ext_vector_type(4))) float f32x4;
typedef __attribute__((ext_vector_type(8))) _Float16 f16x8;
typedef __attribute__((ext_vector_type(2))) _Float16 f16x2;

__device__ __forceinline__ unsigned short f2bf_(float x) {
  __hip_bfloat16 b = __float2bfloat16(x);
  union { __hip_bfloat16 b; unsigned short u; } cv;
  cv.b = b;
  return cv.u;
}
__device__ __forceinline__ float bf2f_(unsigned short u) {
  union { unsigned short u; __hip_bfloat16 b; } cv;
  cv.u = u;
  return __bfloat162float(cv.b);
}
__device__ __forceinline__ void pack_hilo_(const float* v, bf16x8& hi, bf16x8& lo) {
#pragma unroll
  for (int j = 0; j < 8; j++) {
    unsigned short h = f2bf_(v[j]);
    float resid = v[j] - bf2f_(h);
    hi[j] = (short)h;
    lo[j] = (short)f2bf_(resid);
  }
}

// Packed-weight offsets (shorts); hi block then lo block per matrix.
#define WP_G1    0        // 3 x (128x128): stride 32768
#define WP_G2    98304    // 3 x (128x32):  stride 8192
#define WP_S2WIH 122880   // 32x128 (transposed use)
#define WP_TOTAL 131072

// ---------------------------------------------------------------------------
// Startup mega-kernel: [0,6144) = fc3 layer0; [6144,6151) = weight repack.
// R5: fs (bz==0 output) now stored fp16 — gat4 gathers half the bytes.
// ---------------------------------------------------------------------------
__global__ __launch_bounds__(256) void startup_kernel(
    const float* __restrict__ feat,
    const float* __restrict__ W0, const float* __restrict__ B0,
    const float* __restrict__ W1, const float* __restrict__ B1,
    const float* __restrict__ W2, const float* __restrict__ B2,
    _Float16* __restrict__ O0h, float* __restrict__ O1, float* __restrict__ O2,
    const float* __restrict__ g1ws, const float* __restrict__ g1wd,
    const float* __restrict__ l1w, const float* __restrict__ g2ws,
    const float* __restrict__ g2wd, const float* __restrict__ l2w,
    const float* __restrict__ s2wih, short* __restrict__ Wp) {
  __shared__ float w_s[5 * 64];
  __shared__ float in_s[32 * 8];
  __shared__ float b_s[64];
  const int bid = blockIdx.x;
  const int t = threadIdx.x;
  if (bid < 6144) {
    const int bz = bid >> 11, rem = bid & 2047, by = rem >> 10, bx = rem & 1023;
    const float* W = (bz == 0) ? W0 : (bz == 1) ? W1 : W2;
    const float* bias = (bz == 0) ? B0 : (bz == 1) ? B1 : B2;
    const int rowBase = bx * 32;
    const int colBase = by * 64;
    for (int idx = t; idx < 5 * 64; idx += 256) {
      int k = idx >> 6, jj = idx & 63;
      w_s[idx] = W[(size_t)k * 128 + colBase + jj];
    }
    if (t < 64) b_s[t] = bias[colBase + t];
    for (int idx = t; idx < 32 * 5; idx += 256) {
      int r = idx / 5, k = idx - r * 5;
      in_s[r * 8 + k] = feat[(size_t)(rowBase + r) * 5 + k];
    }
    __syncthreads();
    const int jj = t & 63;
    const int rslot = t >> 6;
    float acc[8];
#pragma unroll
    for (int r = 0; r < 8; r++) acc[r] = b_s[jj];
    {
      float wv0 = w_s[0 * 64 + jj], wv1 = w_s[1 * 64 + jj];
      float wv2 = w_s[2 * 64 + jj], wv3 = w_s[3 * 64 + jj];
#pragma unroll
      for (int r = 0; r < 8; r++) {
        float4 ip = *(const float4*)&in_s[(rslot * 8 + r) * 8];
        acc[r] += ip.x * wv0 + ip.y * wv1 + ip.z * wv2 + ip.w * wv3;
      }
      float wv4 = w_s[4 * 64 + jj];
#pragma unroll
      for (int r = 0; r < 8; r++) acc[r] += in_s[(rslot * 8 + r) * 8 + 4] * wv4;
    }
    if (bz == 0) {
#pragma unroll
      for (int r = 0; r < 8; r++)
        O0h[(size_t)(rowBase + rslot * 8 + r) * 128 + colBase + jj] =
            (_Float16)acc[r];
    } else {
      float* out = (bz == 1) ? O1 : O2;
#pragma unroll
      for (int r = 0; r < 8; r++)
        out[(size_t)(rowBase + rslot * 8 + r) * 128 + colBase + jj] = acc[r];
    }
  } else {
    const int mid = bid - 6144;
    const float* W;
    int FI, FO, TRANS;
    size_t base;
    if (mid == 0)      { W = g1ws;  FI = 128; FO = 128; TRANS = 0; base = WP_G1; }
    else if (mid == 1) { W = g1wd;  FI = 128; FO = 128; TRANS = 0; base = WP_G1 + 32768; }
    else if (mid == 2) { W = l1w;   FI = 128; FO = 128; TRANS = 0; base = WP_G1 + 65536; }
    else if (mid == 3) { W = g2ws;  FI = 128; FO = 32;  TRANS = 0; base = WP_G2; }
    else if (mid == 4) { W = g2wd;  FI = 128; FO = 32;  TRANS = 0; base = WP_G2 + 8192; }
    else if (mid == 5) { W = l2w;   FI = 128; FO = 32;  TRANS = 0; base = WP_G2 + 16384; }
    else               { W = s2wih; FI = 32;  FO = 128; TRANS = 1; base = WP_S2WIH; }
    const int KS = FI / 32;
    const int total = FI * FO;
    for (int p = t; p < total; p += 256) {
      int j = p & 7, lane = (p >> 3) & 63, rest = p >> 9;
      int ks = rest % KS, f = rest / KS;
      int n = lane & 15, q = lane >> 4;
      int k = 32 * ks + 8 * q + j, fo = 16 * f + n;
      float v = TRANS ? W[(size_t)fo * FI + k] : W[(size_t)k * FO + fo];
      unsigned short hi = f2bf_(v);
      float resid = v - bf2f_(hi);
      Wp[base + p] = (short)hi;
      Wp[base + total + p] = (short)f2bf_(resid);
    }
  }
}

// ---------------------------------------------------------------------------
// MFMA FC. R5: HALF0 template flag — when set, the z==0 output (fs) is
// stored fp16 for gat4's gather. Other outputs unchanged fp32.
// ---------------------------------------------------------------------------
template <int KS, int FOT, int NZ, int HALF0>  // FI=32*KS, FO=16*FOT
__global__ __launch_bounds__(256) __attribute__((amdgpu_waves_per_eu(1, 4)))
void mfma_fc_kernel(const float* __restrict__ in, const short* __restrict__ Wp,
                    const float* __restrict__ B0, const float* __restrict__ B1,
                    const float* __restrict__ B2, float* __restrict__ O0,
                    float* __restrict__ O1, float* __restrict__ O2) {
  constexpr int FI = 32 * KS;
  constexpr int FO = 16 * FOT;
  const int tid = threadIdx.x;
  const int wid = tid >> 6;
  const int lane = tid & 63;
  const int q = lane >> 4, n = lane & 15;
  const int n0 = blockIdx.x * 64 + wid * 16;
  bf16x8 Ahi[KS], Alo[KS];
#pragma unroll
  for (int ks = 0; ks < KS; ks++) {
    float av[8];
    *(float4*)&av[0] = *(const float4*)&in[(size_t)(n0 + n) * FI + 32 * ks + 8 * q];
    *(float4*)&av[4] = *(const float4*)&in[(size_t)(n0 + n) * FI + 32 * ks + 8 * q + 4];
    pack_hilo_(av, Ahi[ks], Alo[ks]);
  }
#pragma unroll
  for (int z = 0; z < NZ; z++) {
    const short* wz = Wp + (size_t)z * FI * FO * 2;
    const float* bz = (z == 0) ? B0 : (z == 1) ? B1 : B2;
    float* oz = (z == 0) ? O0 : (z == 1) ? O1 : O2;
#pragma unroll
    for (int f = 0; f < FOT; f++) {
      float bv = bz[16 * f + n];
      f32x4 acc = {bv, bv, bv, bv};
#pragma unroll
      for (int ks = 0; ks < KS; ks++) {
        bf16x8 Bhi = *(const bf16x8*)&wz[((size_t)(f * KS + ks) * 64 + lane) * 8];
        bf16x8 Blo = *(const bf16x8*)&wz[(size_t)FI * FO + ((size_t)(f * KS + ks) * 64 + lane) * 8];
        acc = __builtin_amdgcn_mfma_f32_16x16x32_bf16(Ahi[ks], Bhi, acc, 0, 0, 0);
        acc = __builtin_amdgcn_mfma_f32_16x16x32_bf16(Alo[ks], Bhi, acc, 0, 0, 0);
        acc = __builtin_amdgcn_mfma_f32_16x16x32_bf16(Ahi[ks], Blo, acc, 0, 0, 0);
      }
      if (HALF0 && z == 0) {
#pragma unroll
        for (int r = 0; r < 4; r++)
          ((_Float16*)O0)[(size_t)(n0 + 4 * q + r) * FO + 16 * f + n] =
              (_Float16)acc[r];
      } else {
#pragma unroll
        for (int r = 0; r < 4; r++)
          oz[(size_t)(n0 + 4 * q + r) * FO + 16 * f + n] = acc[r];
      }
    }
  }
}

// ---------------------------------------------------------------------------
// XW writer (R4, unchanged): fp16 permuted XW.
// ---------------------------------------------------------------------------
__global__ __launch_bounds__(256) __attribute__((amdgpu_waves_per_eu(1, 4)))
void xw_half_kernel(const float* __restrict__ in, const short* __restrict__ Wp,
                    const float* __restrict__ bz, _Float16* __restrict__ XWh) {
  const int tid = threadIdx.x;
  const int wid = tid >> 6;
  const int lane = tid & 63;
  const int q = lane >> 4, n = lane & 15;
  const int n0 = blockIdx.x * 64 + wid * 16;
  bf16x8 Ahi, Alo;
  {
    float av[8];
    *(float4*)&av[0] = *(const float4*)&in[(size_t)(n0 + n) * 32 + 8 * q];
    *(float4*)&av[4] = *(const float4*)&in[(size_t)(n0 + n) * 32 + 8 * q + 4];
    pack_hilo_(av, Ahi, Alo);
  }
#pragma unroll
  for (int f = 0; f < 8; f++) {
    float bv = bz[16 * f + n];
    f32x4 acc = {bv, bv, bv, bv};
    bf16x8 Bhi = *(const bf16x8*)&Wp[((size_t)f * 64 + lane) * 8];
    bf16x8 Blo = *(const bf16x8*)&Wp[4096 + ((size_t)f * 64 + lane) * 8];
    acc = __builtin_amdgcn_mfma_f32_16x16x32_bf16(Ahi, Bhi, acc, 0, 0, 0);
    acc = __builtin_amdgcn_mfma_f32_16x16x32_bf16(Alo, Bhi, acc, 0, 0, 0);
    acc = __builtin_amdgcn_mfma_f32_16x16x32_bf16(Ahi, Blo, acc, 0, 0, 0);
    // gate dim g = 16*f + n; perm(g) = (n>>2)*32 + f*4 + (n&3)
#pragma unroll
    for (int r = 0; r < 4; r++)
      XWh[(size_t)(n0 + 4 * q + r) * 128 + ((n >> 2) * 32 + f * 4 + (n & 3))] =
          (_Float16)acc[r];
  }
}

// ---------------------------------------------------------------------------
// GATv2 H=4 — R5: fs gathered as fp16 (4 B/lane vs 8). fd/lin fp32.
// ---------------------------------------------------------------------------
__global__ __launch_bounds__(256) void gat4_kernel(const _Float16* __restrict__ fs,
                                                   const float* __restrict__ fd,
                                                   const float* __restrict__ lin,
                                                   const int* __restrict__ src,
                                                   const float* __restrict__ attn,
                                                   const float* __restrict__ bias,
                                                   float* __restrict__ out) {
  constexpr int F = 128;
  const int lane = threadIdx.x & 63;
  const int wave = threadIdx.x >> 6;
  const int li = lane & 15;
  const int node = blockIdx.x * 4 + wave;
  const int f0 = 2 * lane;
  const int srcv = src[(size_t)node * DEG + li];
  const float2 fdv = *(const float2*)&fd[(size_t)node * F + f0];
  const float a0 = attn[f0];
  const float a1 = attn[f0 + 1];
  float m = -1e30f, s = 0.f, acc0 = 0.f, acc1 = 0.f;
  int sd = __shfl(srcv, (lane & 48), 64);
  f16x2 fsv = *(const f16x2*)&fs[(size_t)sd * F + f0];
#pragma unroll
  for (int d = 0; d < DEG; d++) {
    float2 cur = make_float2((float)fsv[0], (float)fsv[1]);
    if (d < DEG - 1) {
      int sn = __shfl(srcv, (lane & 48) | (d + 1), 64);
      fsv = *(const f16x2*)&fs[(size_t)sn * F + f0];
    }
    float e0 = cur.x + fdv.x; e0 = (e0 > 0.f) ? e0 : 0.2f * e0;
    float e1 = cur.y + fdv.y; e1 = (e1 > 0.f) ? e1 : 0.2f * e1;
    float p = e0 * a0 + e1 * a1;
    p += __shfl_xor(p, 1, 64);
    p += __shfl_xor(p, 2, 64);
    p += __shfl_xor(p, 4, 64);
    p += __shfl_xor(p, 8, 64);
    float nm = fmaxf(m, p);
    float ex = __expf(p - nm);
    float sc = __expf(m - nm);
    s = s * sc + ex;
    acc0 = acc0 * sc + ex * cur.x;
    acc1 = acc1 * sc + ex * cur.y;
    m = nm;
  }
  float inv = 1.f / s;
  float2 lv = *(const float2*)&lin[(size_t)node * F + f0];
  float o0 = acc0 * inv + lv.x + bias[f0];
  float o1 = acc1 * inv + lv.y + bias[f0 + 1];
  o0 = (o0 > 0.f) ? o0 : __expf(o0) - 1.f;
  o1 = (o1 > 0.f) ? o1 : __expf(o1) - 1.f;
  *(float2*)&out[(size_t)node * F + f0] = make_float2(o0, o1);
}

// ---------------------------------------------------------------------------
// GATv2 H=1 (no ELU) + fused fw1 (fp32 fs — [N,32] table is L2-small).
// ---------------------------------------------------------------------------
__global__ __launch_bounds__(256) void gat1_fw1_kernel(
    const float* __restrict__ fs, const float* __restrict__ fd,
    const float* __restrict__ lin, const int* __restrict__ src,
    const float* __restrict__ attn, const float* __restrict__ bias,
    float* __restrict__ out, const float* __restrict__ feat,
    const float* __restrict__ wih, const float* __restrict__ wb,
    float* __restrict__ fwout) {
  __shared__ float w_s[100];
  __shared__ float b_s[20];
  if (blockIdx.x < 2048) {
    constexpr int F = 32;
    const int lane = threadIdx.x & 63;
    const int wave = threadIdx.x >> 6;
    const int G = lane >> 4, li = lane & 15;
    const int node = blockIdx.x * 16 + wave * 4 + G;
    const int f0 = 2 * li;
    const int srcv = src[(size_t)node * DEG + li];
    const float2 fdv = *(const float2*)&fd[(size_t)node * F + f0];
    const float a0 = attn[f0];
    const float a1 = attn[f0 + 1];
    float m = -1e30f, s = 0.f, acc0 = 0.f, acc1 = 0.f;
    int sd = __shfl(srcv, (lane & 48), 64);
    float2 fsv = *(const float2*)&fs[(size_t)sd * F + f0];
#pragma unroll
    for (int d = 0; d < DEG; d++) {
      float2 cur = fsv;
      if (d < DEG - 1) {
        int sn = __shfl(srcv, (lane & 48) | (d + 1), 64);
        fsv = *(const float2*)&fs[(size_t)sn * F + f0];
      }
      float e0 = cur.x + fdv.x; e0 = (e0 > 0.f) ? e0 : 0.2f * e0;
      float e1 = cur.y + fdv.y; e1 = (e1 > 0.f) ? e1 : 0.2f * e1;
      float p = e0 * a0 + e1 * a1;
      p += __shfl_xor(p, 1, 64);
      p += __shfl_xor(p, 2, 64);
      p += __shfl_xor(p, 4, 64);
      p += __shfl_xor(p, 8, 64);
      float nm = fmaxf(m, p);
      float ex = __expf(p - nm);
      float sc = __expf(m - nm);
      s = s * sc + ex;
      acc0 = acc0 * sc + ex * cur.x;
      acc1 = acc1 * sc + ex * cur.y;
      m = nm;
    }
    float inv = 1.f / s;
    float2 lv = *(const float2*)&lin[(size_t)node * F + f0];
    float o0 = acc0 * inv + lv.x + bias[f0];
    float o1 = acc1 * inv + lv.y + bias[f0 + 1];
    *(float2*)&out[(size_t)node * F + f0] = make_float2(o0, o1);
  } else {
    if (threadIdx.x < 100) w_s[threadIdx.x] = wih[threadIdx.x];
    if (threadIdx.x < 20) b_s[threadIdx.x] = wb[threadIdx.x];
    __syncthreads();
    const int n = (blockIdx.x - 2048) * 256 + threadIdx.x;
    float f[5];
#pragma unroll
    for (int k = 0; k < 5; k++) f[k] = feat[(size_t)n * 5 + k];
#pragma unroll
    for (int j = 0; j < 20; j++) {
      float a = b_s[j];
#pragma unroll
      for (int k = 0; k < 5; k++) a += f[k] * w_s[j * 5 + k];
      fwout[(size_t)n * 20 + j] = a;
    }
  }
}

// ---------------------------------------------------------------------------
// SAGE-1: LSTM + fused projection (R5: rcp-based gates, else unchanged).
// ---------------------------------------------------------------------------
__global__ __attribute__((amdgpu_waves_per_eu(1, 4))) __launch_bounds__(256)
void lstm1s_kernel(const float* __restrict__ FW, const int* __restrict__ src,
                   const float* __restrict__ whh, const float* __restrict__ feat,
                   const float* __restrict__ wself, const float* __restrict__ wneigh,
                   const float* __restrict__ bias, float* __restrict__ x1out) {
  __shared__ float w_s[100];   // whh [20][5]
  __shared__ float ws_s[160];  // wself [5][32]
  __shared__ float wn_s[160];  // wneigh [5][32]
  __shared__ float b_s[32];
  if (threadIdx.x < 100) w_s[threadIdx.x] = whh[threadIdx.x];
  if (threadIdx.x < 160) {
    ws_s[threadIdx.x] = wself[threadIdx.x];
    wn_s[threadIdx.x] = wneigh[threadIdx.x];
  }
  if (threadIdx.x < 32) b_s[threadIdx.x] = bias[threadIdx.x];
  __syncthreads();
  const int n = blockIdx.x * 256 + threadIdx.x;
  const int* sp = src + (size_t)n * DEG;
  float f[5];
#pragma unroll
  for (int k = 0; k < 5; k++) f[k] = feat[(size_t)n * 5 + k];
  float h[5] = {0, 0, 0, 0, 0}, c[5] = {0, 0, 0, 0, 0};
  int sd = sp[0];
  float4 p0 = *(const float4*)&FW[(size_t)sd * 20 + 0];
  float4 p1 = *(const float4*)&FW[(size_t)sd * 20 + 4];
  float4 p2 = *(const float4*)&FW[(size_t)sd * 20 + 8];
  float4 p3 = *(const float4*)&FW[(size_t)sd * 20 + 12];
  float4 p4 = *(const float4*)&FW[(size_t)sd * 20 + 16];
  for (int d = 0; d < DEG; d++) {
    float g[20];
    g[0] = p0.x; g[1] = p0.y; g[2] = p0.z; g[3] = p0.w;
    g[4] = p1.x; g[5] = p1.y; g[6] = p1.z; g[7] = p1.w;
    g[8] = p2.x; g[9] = p2.y; g[10] = p2.z; g[11] = p2.w;
    g[12] = p3.x; g[13] = p3.y; g[14] = p3.z; g[15] = p3.w;
    g[16] = p4.x; g[17] = p4.y; g[18] = p4.z; g[19] = p4.w;
    if (d < DEG - 1) {
      int sn = sp[d + 1];
      p0 = *(const float4*)&FW[(size_t)sn * 20 + 0];
      p1 = *(const float4*)&FW[(size_t)sn * 20 + 4];
      p2 = *(const float4*)&FW[(size_t)sn * 20 + 8];
      p3 = *(const float4*)&FW[(size_t)sn * 20 + 12];
      p4 = *(const float4*)&FW[(size_t)sn * 20 + 16];
    }
#pragma unroll
    for (int j = 0; j < 20; j++) {
#pragma unroll
      for (int k = 0; k < 5; k++) g[j] += h[k] * w_s[j * 5 + k];
    }
#pragma unroll
    for (int k = 0; k < 5; k++) {
      float iv = sigmoidf_(g[k]);
      float fv = sigmoidf_(g[5 + k]);
      float gv = tanhf_(g[10 + k]);
      float ov = sigmoidf_(g[15 + k]);
      c[k] = fv * c[k] + iv * gv;
      h[k] = ov * tanhf_(c[k]);
    }
  }
#pragma unroll
  for (int j = 0; j < 32; j++) {
    float a = b_s[j];
#pragma unroll
    for (int k = 0; k < 5; k++) a += f[k] * ws_s[k * 32 + j] + h[k] * wn_s[k * 32 + j];
    x1out[(size_t)n * 32 + j] = fmaxf(a, 0.f);
  }
}

// ---------------------------------------------------------------------------
// SAGE-2 LSTM (MFMA) — R5: rcp-based gates (VALU was the binding resource:
// R4 proved byte count is irrelevant — FETCH 102->40 MB, dur unchanged).
// Everything else R4-identical.
// ---------------------------------------------------------------------------
__global__ __launch_bounds__(256) __attribute__((amdgpu_waves_per_eu(1, 4)))
void lstm2_mfma_kernel(const _Float16* __restrict__ XW, const int* __restrict__ src,
                       const float* __restrict__ whh, float* __restrict__ hn_out) {
  __shared__ float h_lds_all[4 * 16 * 36];
  __shared__ int src_lds_all[4 * 256];
  const int tid = threadIdx.x;
  const int wid = tid >> 6;
  const int lane = tid & 63;
  const int q = lane >> 4;   // quad
  const int n = lane & 15;   // node within group / fragment col
  const int n0 = (blockIdx.x * 4 + wid) * 16;
  float* h_lds = &h_lds_all[wid * 16 * 36];
  int* src_lds = &src_lds_all[wid * 256];

  {
    int4 sv = *(const int4*)&src[(size_t)(n0 + (lane >> 2)) * DEG + 4 * (lane & 3)];
    src_lds[(4 * (lane & 3) + 0) * 16 + (lane >> 2)] = sv.x;
    src_lds[(4 * (lane & 3) + 1) * 16 + (lane >> 2)] = sv.y;
    src_lds[(4 * (lane & 3) + 2) * 16 + (lane >> 2)] = sv.z;
    src_lds[(4 * (lane & 3) + 3) * 16 + (lane >> 2)] = sv.w;
  }

  bf16x8 Whi[8], Wlo[8];
#pragma unroll
  for (int gt = 0; gt < 8; gt++) {
    float wv[8];
    *(float4*)&wv[0] = *(const float4*)&whh[(size_t)(16 * gt + n) * 32 + 8 * q];
    *(float4*)&wv[4] = *(const float4*)&whh[(size_t)(16 * gt + n) * 32 + 8 * q + 4];
    pack_hilo_(wv, Whi[gt], Wlo[gt]);
  }

  bf16x8 Bhi, Blo;
#pragma unroll
  for (int j = 0; j < 8; j++) { Bhi[j] = 0; Blo[j] = 0; }
  float cst[8];
#pragma unroll
  for (int i = 0; i < 8; i++) cst[i] = 0.f;

  f16x8 tch[4], tnh[4];
  {
    int s0 = src_lds[0 * 16 + n];
    const _Float16* gb = XW + (size_t)s0 * 128 + q * 32;
#pragma unroll
    for (int t = 0; t < 4; t++) tch[t] = *(const f16x8*)&gb[8 * t];
  }

  float hv[8];
#pragma unroll
  for (int d = 0; d < DEG; d++) {
    f32x4 D[4][2];
#pragma unroll
    for (int p = 0; p < 4; p++) {
#pragma unroll
      for (int hh = 0; hh < 2; hh++) {
        int gt = p * 2 + hh;
        f32x4 acc = {0.f, 0.f, 0.f, 0.f};
        acc = __builtin_amdgcn_mfma_f32_16x16x32_bf16(Whi[gt], Bhi, acc, 0, 0, 0);
        acc = __builtin_amdgcn_mfma_f32_16x16x32_bf16(Wlo[gt], Bhi, acc, 0, 0, 0);
        acc = __builtin_amdgcn_mfma_f32_16x16x32_bf16(Whi[gt], Blo, acc, 0, 0, 0);
        D[p][hh] = acc;
      }
    }
    if (d < DEG - 1) {
      int s = src_lds[(d + 1) * 16 + n];
      const _Float16* gb = XW + (size_t)s * 128 + q * 32;
#pragma unroll
      for (int t = 0; t < 4; t++) tnh[t] = *(const f16x8*)&gb[8 * t];
    }
#pragma unroll
    for (int hh = 0; hh < 2; hh++) {
#pragma unroll
      for (int r = 0; r < 4; r++) {
        int ci = hh * 4 + r;
        float xiv = (float)tch[0][hh * 4 + r];
        float xfv = (float)tch[1][hh * 4 + r];
        float xgv = (float)tch[2][hh * 4 + r];
        float xov = (float)tch[3][hh * 4 + r];
        float iv = sigmoidf_(D[0][hh][r] + xiv);
        float fv = sigmoidf_(D[1][hh][r] + xfv);
        float gv = tanhf_(D[2][hh][r] + xgv);
        float ov = sigmoidf_(D[3][hh][r] + xov);
        cst[ci] = fv * cst[ci] + iv * gv;
        hv[ci] = ov * tanhf_(cst[ci]);
      }
    }
    if (d < DEG - 1) {
      *(float4*)&h_lds[n * 36 + 0 + 4 * q] = make_float4(hv[0], hv[1], hv[2], hv[3]);
      *(float4*)&h_lds[n * 36 + 16 + 4 * q] = make_float4(hv[4], hv[5], hv[6], hv[7]);
      float hb[8];
      *(float4*)&hb[0] = *(const float4*)&h_lds[n * 36 + 8 * q];
      *(float4*)&hb[4] = *(const float4*)&h_lds[n * 36 + 8 * q + 4];
      pack_hilo_(hb, Bhi, Blo);
#pragma unroll
      for (int t = 0; t < 4; t++) tch[t] = tnh[t];
    }
  }
  *(float4*)&hn_out[(size_t)(n0 + n) * 32 + 0 + 4 * q] = make_float4(hv[0], hv[1], hv[2], hv[3]);
  *(float4*)&hn_out[(size_t)(n0 + n) * 32 + 16 + 4 * q] = make_float4(hv[4], hv[5], hv[6], hv[7]);
}

// ---------------------------------------------------------------------------
// Fused sage_out + final MLP (R4, unchanged).
// ---------------------------------------------------------------------------
__global__ __launch_bounds__(128) void sage_final_kernel(
    const float* __restrict__ x1, const float* __restrict__ hn,
    const float* __restrict__ wself, const float* __restrict__ wneigh,
    const float* __restrict__ sbias, const float* __restrict__ gat,
    const float* __restrict__ f1w, const float* __restrict__ f1b,
    const float* __restrict__ f2w, const float* __restrict__ f2b,
    float* __restrict__ out) {
  __shared__ float ws_s[32 * 32];
  __shared__ float wn_s[32 * 32];
  __shared__ float b_s[32];
  __shared__ float w1_s[64 * 16];
  __shared__ float b1_s[16];
  __shared__ float w2_s[16];
  for (int idx = threadIdx.x; idx < 1024; idx += 128) {
    ws_s[idx] = wself[idx];
    wn_s[idx] = wneigh[idx];
    w1_s[idx] = f1w[idx];
  }
  if (threadIdx.x < 32) b_s[threadIdx.x] = sbias[threadIdx.x];
  if (threadIdx.x < 16) {
    b1_s[threadIdx.x] = f1b[threadIdx.x];
    w2_s[threadIdx.x] = f2w[threadIdx.x];
  }
  __syncthreads();
  const int n = blockIdx.x * 128 + threadIdx.x;
  float xr[32], hr[32], z[64];
#pragma unroll
  for (int k = 0; k < 32; k += 4) {
    *(float4*)&xr[k] = *(const float4*)&x1[(size_t)n * 32 + k];
    *(float4*)&hr[k] = *(const float4*)&hn[(size_t)n * 32 + k];
    float4 a = *(const float4*)&gat[(size_t)n * 32 + k];
    z[k] = a.x; z[k + 1] = a.y; z[k + 2] = a.z; z[k + 3] = a.w;
  }
#pragma unroll
  for (int j = 0; j < 32; j++) {
    float a = b_s[j];
#pragma unroll
    for (int k = 0; k < 32; k++) a += xr[k] * ws_s[k * 32 + j];
#pragma unroll
    for (int k = 0; k < 32; k++) a += hr[k] * wn_s[k * 32 + j];
    z[32 + j] = fmaxf(a, 0.f);
  }
  float o = f2b[0];
#pragma unroll
  for (int j = 0; j < 16; j++) {
    float a = b1_s[j];
#pragma unroll
    for (int k = 0; k < 64; k++) a += z[k] * w1_s[k * 16 + j];
    o += fmaxf(a, 0.f) * w2_s[j];
  }
  out[n] = o;
}

extern "C" void kernel_launch(void* const* d_in, const int* in_sizes, int n_in,
                              void* d_out, int out_size, void* d_ws, size_t ws_size,
                              hipStream_t stream) {
  const int N = NNODES;
  const float* feat = (const float*)d_in[0];
  const int* src = (const int*)d_in[1];
  const float* g0_ws = (const float*)d_in[2];
  const float* g0_bs = (const float*)d_in[3];
  const float* g0_wd = (const float*)d_in[4];
  const float* g0_bd = (const float*)d_in[5];
  const float* g0_attn = (const float*)d_in[6];
  const float* g0_bias = (const float*)d_in[7];
  const float* l0_w = (const float*)d_in[8];
  const float* l0_b = (const float*)d_in[9];
  const float* g1_ws = (const float*)d_in[10];
  const float* g1_bs = (const float*)d_in[11];
  const float* g1_wd = (const float*)d_in[12];
  const float* g1_bd = (const float*)d_in[13];
  const float* g1_attn = (const float*)d_in[14];
  const float* g1_bias = (const float*)d_in[15];
  const float* l1_w = (const float*)d_in[16];
  const float* l1_b = (const float*)d_in[17];
  const float* g2_ws = (const float*)d_in[18];
  const float* g2_bs = (const float*)d_in[19];
  const float* g2_wd = (const float*)d_in[20];
  const float* g2_bd = (const float*)d_in[21];
  const float* g2_attn = (const float*)d_in[22];
  const float* g2_bias = (const float*)d_in[23];
  const float* l2_w = (const float*)d_in[24];
  const float* l2_b = (const float*)d_in[25];
  const float* s1_wih = (const float*)d_in[26];
  const float* s1_whh = (const float*)d_in[27];
  const float* s1_b = (const float*)d_in[28];
  const float* s1_wself = (const float*)d_in[29];
  const float* s1_wneigh = (const float*)d_in[30];
  const float* s1_bias = (const float*)d_in[31];
  const float* s2_wih = (const float*)d_in[32];
  const float* s2_whh = (const float*)d_in[33];
  const float* s2_b = (const float*)d_in[34];
  const float* s2_wself = (const float*)d_in[35];
  const float* s2_wneigh = (const float*)d_in[36];
  const float* s2_bias = (const float*)d_in[37];
  const float* f1_w = (const float*)d_in[38];
  const float* f1_b = (const float*)d_in[39];
  const float* f2_w = (const float*)d_in[40];
  const float* f2_b = (const float*)d_in[41];

  float* A = (float*)d_ws;                // N*128
  float* B = A + (size_t)N * 128;
  float* C = B + (size_t)N * 128;
  float* D = C + (size_t)N * 128;
  float* E = D + (size_t)N * 128;         // A..E = 84 MB
  short* Wp = (short*)(A + (size_t)5 * N * 128);  // packed bf16 weights, 262 KB

  // 1. startup: fc3 layer0 (A=fs[fp16], B=fd, C=lin) + repack 7 weights
  startup_kernel<<<6151, 256, 0, stream>>>(
      feat, g0_ws, g0_bs, g0_wd, g0_bd, l0_w, l0_b,
      (_Float16*)A, B, C,
      g1_ws, g1_wd, l1_w, g2_ws, g2_wd, l2_w, s2_wih, Wp);
  // 2. GAT layer 0 -> D = h1
  gat4_kernel<<<N / 4, 256, 0, stream>>>((const _Float16*)A, B, C, src,
                                         g0_attn, g0_bias, D);
  // 3. layer-1 FC trio (MFMA) -> A=fs[fp16], B, C
  mfma_fc_kernel<4, 8, 3, 1><<<N / 64, 256, 0, stream>>>(
      D, Wp + WP_G1, g1_bs, g1_bd, l1_b, A, B, C);
  // 4. GAT layer 1 -> E = h2
  gat4_kernel<<<N / 4, 256, 0, stream>>>((const _Float16*)A, B, C, src,
                                         g1_attn, g1_bias, E);
  // 5. layer-2 FC trio (MFMA) -> A,B,C  (N x 32 each, fp32)
  mfma_fc_kernel<4, 2, 3, 0><<<N / 64, 256, 0, stream>>>(
      E, Wp + WP_G2, g2_bs, g2_bd, l2_b, A, B, C);
  // 6. GAT layer 2 -> D = gat [N,32]; + fused fw1 -> E = FW1 [N,20]
  gat1_fw1_kernel<<<2048 + 128, 256, 0, stream>>>(
      A, B, C, src, g2_attn, g2_bias, D, feat, s1_wih, s1_b, E);
  // 7. SAGE-1 LSTM + projection -> C = x1 [N,32]
  lstm1s_kernel<<<N / 256, 256, 0, stream>>>(E, src, s1_whh, feat, s1_wself,
                                             s1_wneigh, s1_bias, C);
  // 8. XW2 = x1 @ wih.T + b -> A as fp16 permuted [N,128]
  xw_half_kernel<<<N / 64, 256, 0, stream>>>(
      C, Wp + WP_S2WIH, s2_b, (_Float16*)A);
  // 9. SAGE-2 LSTM -> E = hn2 [N,32]
  lstm2_mfma_kernel<<<N / 64, 256, 0, stream>>>((const _Float16*)A, src, s2_whh, E);
  // 10. fused sage_out + final MLP -> out
  sage_final_kernel<<<N / 128, 128, 0, stream>>>(
      C, E, s2_wself, s2_wneigh, s2_bias, D, f1_w, f1_b, f2_w, f2_b,
      (float*)d_out);
}

// Round 6
// 371.101 us; speedup vs baseline: 1.3697x; 1.0292x over previous
//
#include <hip/hip_runtime.h>
#include <hip/hip_bf16.h>

#define NNODES 32768
#define DEG 16

// R5: fast sigmoid/tanh — v_rcp_f32 instead of IEEE div chain. ~1 ulp.
__device__ __forceinline__ float sigmoidf_(float x) {
  return __builtin_amdgcn_rcpf(1.f + __expf(-x));
}
__device__ __forceinline__ float tanhf_(float x) {
  return 1.f - 2.f * __builtin_amdgcn_rcpf(__expf(2.f * x) + 1.f);
}

typedef __attribute__((ext_vector_type(8))) short bf16x8;
typedef __attribute__((ext_vector_type(4))) float f32x4;
typedef __attribute__((ext_vector_type(8))) _Float16 f16x8;
typedef __attribute__((ext_vector_type(2))) _Float16 f16x2;

__device__ __forceinline__ unsigned short f2bf_(float x) {
  __hip_bfloat16 b = __float2bfloat16(x);
  union { __hip_bfloat16 b; unsigned short u; } cv;
  cv.b = b;
  return cv.u;
}
__device__ __forceinline__ float bf2f_(unsigned short u) {
  union { unsigned short u; __hip_bfloat16 b; } cv;
  cv.u = u;
  return __bfloat162float(cv.b);
}
__device__ __forceinline__ void pack_hilo_(const float* v, bf16x8& hi, bf16x8& lo) {
#pragma unroll
  for (int j = 0; j < 8; j++) {
    unsigned short h = f2bf_(v[j]);
    float resid = v[j] - bf2f_(h);
    hi[j] = (short)h;
    lo[j] = (short)f2bf_(resid);
  }
}

// Packed-weight offsets (shorts); hi block then lo block per matrix.
#define WP_G1    0        // 3 x (128x128): stride 32768
#define WP_G2    98304    // 3 x (128x32):  stride 8192
#define WP_S2WIH 122880   // 32x128 (transposed use)
#define WP_TOTAL 131072

// ---------------------------------------------------------------------------
// Startup mega-kernel (R5-exact): fc3 layer0 (fs fp16) + weight repack.
// ---------------------------------------------------------------------------
__global__ __launch_bounds__(256) void startup_kernel(
    const float* __restrict__ feat,
    const float* __restrict__ W0, const float* __restrict__ B0,
    const float* __restrict__ W1, const float* __restrict__ B1,
    const float* __restrict__ W2, const float* __restrict__ B2,
    _Float16* __restrict__ O0h, float* __restrict__ O1, float* __restrict__ O2,
    const float* __restrict__ g1ws, const float* __restrict__ g1wd,
    const float* __restrict__ l1w, const float* __restrict__ g2ws,
    const float* __restrict__ g2wd, const float* __restrict__ l2w,
    const float* __restrict__ s2wih, short* __restrict__ Wp) {
  __shared__ float w_s[5 * 64];
  __shared__ float in_s[32 * 8];
  __shared__ float b_s[64];
  const int bid = blockIdx.x;
  const int t = threadIdx.x;
  if (bid < 6144) {
    const int bz = bid >> 11, rem = bid & 2047, by = rem >> 10, bx = rem & 1023;
    const float* W = (bz == 0) ? W0 : (bz == 1) ? W1 : W2;
    const float* bias = (bz == 0) ? B0 : (bz == 1) ? B1 : B2;
    const int rowBase = bx * 32;
    const int colBase = by * 64;
    for (int idx = t; idx < 5 * 64; idx += 256) {
      int k = idx >> 6, jj = idx & 63;
      w_s[idx] = W[(size_t)k * 128 + colBase + jj];
    }
    if (t < 64) b_s[t] = bias[colBase + t];
    for (int idx = t; idx < 32 * 5; idx += 256) {
      int r = idx / 5, k = idx - r * 5;
      in_s[r * 8 + k] = feat[(size_t)(rowBase + r) * 5 + k];
    }
    __syncthreads();
    const int jj = t & 63;
    const int rslot = t >> 6;
    float acc[8];
#pragma unroll
    for (int r = 0; r < 8; r++) acc[r] = b_s[jj];
    {
      float wv0 = w_s[0 * 64 + jj], wv1 = w_s[1 * 64 + jj];
      float wv2 = w_s[2 * 64 + jj], wv3 = w_s[3 * 64 + jj];
#pragma unroll
      for (int r = 0; r < 8; r++) {
        float4 ip = *(const float4*)&in_s[(rslot * 8 + r) * 8];
        acc[r] += ip.x * wv0 + ip.y * wv1 + ip.z * wv2 + ip.w * wv3;
      }
      float wv4 = w_s[4 * 64 + jj];
#pragma unroll
      for (int r = 0; r < 8; r++) acc[r] += in_s[(rslot * 8 + r) * 8 + 4] * wv4;
    }
    if (bz == 0) {
#pragma unroll
      for (int r = 0; r < 8; r++)
        O0h[(size_t)(rowBase + rslot * 8 + r) * 128 + colBase + jj] =
            (_Float16)acc[r];
    } else {
      float* out = (bz == 1) ? O1 : O2;
#pragma unroll
      for (int r = 0; r < 8; r++)
        out[(size_t)(rowBase + rslot * 8 + r) * 128 + colBase + jj] = acc[r];
    }
  } else {
    const int mid = bid - 6144;
    const float* W;
    int FI, FO, TRANS;
    size_t base;
    if (mid == 0)      { W = g1ws;  FI = 128; FO = 128; TRANS = 0; base = WP_G1; }
    else if (mid == 1) { W = g1wd;  FI = 128; FO = 128; TRANS = 0; base = WP_G1 + 32768; }
    else if (mid == 2) { W = l1w;   FI = 128; FO = 128; TRANS = 0; base = WP_G1 + 65536; }
    else if (mid == 3) { W = g2ws;  FI = 128; FO = 32;  TRANS = 0; base = WP_G2; }
    else if (mid == 4) { W = g2wd;  FI = 128; FO = 32;  TRANS = 0; base = WP_G2 + 8192; }
    else if (mid == 5) { W = l2w;   FI = 128; FO = 32;  TRANS = 0; base = WP_G2 + 16384; }
    else               { W = s2wih; FI = 32;  FO = 128; TRANS = 1; base = WP_S2WIH; }
    const int KS = FI / 32;
    const int total = FI * FO;
    for (int p = t; p < total; p += 256) {
      int j = p & 7, lane = (p >> 3) & 63, rest = p >> 9;
      int ks = rest % KS, f = rest / KS;
      int n = lane & 15, q = lane >> 4;
      int k = 32 * ks + 8 * q + j, fo = 16 * f + n;
      float v = TRANS ? W[(size_t)fo * FI + k] : W[(size_t)k * FO + fo];
      unsigned short hi = f2bf_(v);
      float resid = v - bf2f_(hi);
      Wp[base + p] = (short)hi;
      Wp[base + total + p] = (short)f2bf_(resid);
    }
  }
}

// ---------------------------------------------------------------------------
// MFMA FC (R5-exact, HALF0 flag for fp16 fs output).
// ---------------------------------------------------------------------------
template <int KS, int FOT, int NZ, int HALF0>  // FI=32*KS, FO=16*FOT
__global__ __launch_bounds__(256) __attribute__((amdgpu_waves_per_eu(1, 4)))
void mfma_fc_kernel(const float* __restrict__ in, const short* __restrict__ Wp,
                    const float* __restrict__ B0, const float* __restrict__ B1,
                    const float* __restrict__ B2, float* __restrict__ O0,
                    float* __restrict__ O1, float* __restrict__ O2) {
  constexpr int FI = 32 * KS;
  constexpr int FO = 16 * FOT;
  const int tid = threadIdx.x;
  const int wid = tid >> 6;
  const int lane = tid & 63;
  const int q = lane >> 4, n = lane & 15;
  const int n0 = blockIdx.x * 64 + wid * 16;
  bf16x8 Ahi[KS], Alo[KS];
#pragma unroll
  for (int ks = 0; ks < KS; ks++) {
    float av[8];
    *(float4*)&av[0] = *(const float4*)&in[(size_t)(n0 + n) * FI + 32 * ks + 8 * q];
    *(float4*)&av[4] = *(const float4*)&in[(size_t)(n0 + n) * FI + 32 * ks + 8 * q + 4];
    pack_hilo_(av, Ahi[ks], Alo[ks]);
  }
#pragma unroll
  for (int z = 0; z < NZ; z++) {
    const short* wz = Wp + (size_t)z * FI * FO * 2;
    const float* bz = (z == 0) ? B0 : (z == 1) ? B1 : B2;
    float* oz = (z == 0) ? O0 : (z == 1) ? O1 : O2;
#pragma unroll
    for (int f = 0; f < FOT; f++) {
      float bv = bz[16 * f + n];
      f32x4 acc = {bv, bv, bv, bv};
#pragma unroll
      for (int ks = 0; ks < KS; ks++) {
        bf16x8 Bhi = *(const bf16x8*)&wz[((size_t)(f * KS + ks) * 64 + lane) * 8];
        bf16x8 Blo = *(const bf16x8*)&wz[(size_t)FI * FO + ((size_t)(f * KS + ks) * 64 + lane) * 8];
        acc = __builtin_amdgcn_mfma_f32_16x16x32_bf16(Ahi[ks], Bhi, acc, 0, 0, 0);
        acc = __builtin_amdgcn_mfma_f32_16x16x32_bf16(Alo[ks], Bhi, acc, 0, 0, 0);
        acc = __builtin_amdgcn_mfma_f32_16x16x32_bf16(Ahi[ks], Blo, acc, 0, 0, 0);
      }
      if (HALF0 && z == 0) {
#pragma unroll
        for (int r = 0; r < 4; r++)
          ((_Float16*)O0)[(size_t)(n0 + 4 * q + r) * FO + 16 * f + n] =
              (_Float16)acc[r];
      } else {
#pragma unroll
        for (int r = 0; r < 4; r++)
          oz[(size_t)(n0 + 4 * q + r) * FO + 16 * f + n] = acc[r];
      }
    }
  }
}

// ---------------------------------------------------------------------------
// XW writer (R4, unchanged): fp16 permuted XW.
// ---------------------------------------------------------------------------
__global__ __launch_bounds__(256) __attribute__((amdgpu_waves_per_eu(1, 4)))
void xw_half_kernel(const float* __restrict__ in, const short* __restrict__ Wp,
                    const float* __restrict__ bz, _Float16* __restrict__ XWh) {
  const int tid = threadIdx.x;
  const int wid = tid >> 6;
  const int lane = tid & 63;
  const int q = lane >> 4, n = lane & 15;
  const int n0 = blockIdx.x * 64 + wid * 16;
  bf16x8 Ahi, Alo;
  {
    float av[8];
    *(float4*)&av[0] = *(const float4*)&in[(size_t)(n0 + n) * 32 + 8 * q];
    *(float4*)&av[4] = *(const float4*)&in[(size_t)(n0 + n) * 32 + 8 * q + 4];
    pack_hilo_(av, Ahi, Alo);
  }
#pragma unroll
  for (int f = 0; f < 8; f++) {
    float bv = bz[16 * f + n];
    f32x4 acc = {bv, bv, bv, bv};
    bf16x8 Bhi = *(const bf16x8*)&Wp[((size_t)f * 64 + lane) * 8];
    bf16x8 Blo = *(const bf16x8*)&Wp[4096 + ((size_t)f * 64 + lane) * 8];
    acc = __builtin_amdgcn_mfma_f32_16x16x32_bf16(Ahi, Bhi, acc, 0, 0, 0);
    acc = __builtin_amdgcn_mfma_f32_16x16x32_bf16(Alo, Bhi, acc, 0, 0, 0);
    acc = __builtin_amdgcn_mfma_f32_16x16x32_bf16(Ahi, Blo, acc, 0, 0, 0);
    // gate dim g = 16*f + n; perm(g) = (n>>2)*32 + f*4 + (n&3)
#pragma unroll
    for (int r = 0; r < 4; r++)
      XWh[(size_t)(n0 + 4 * q + r) * 128 + ((n >> 2) * 32 + f * 4 + (n & 3))] =
          (_Float16)acc[r];
  }
}

// ---------------------------------------------------------------------------
// GATv2 H=4 — R6: all 16 gathers issued UP-FRONT (addresses are register-only
// shfls of srcv; 16 independent 256B-coalesced row reads in flight), then
// TWO-PASS softmax over registers (= the reference's exact exp(p-max)/sum
// form; deletes the per-iter online rescale: 2 exps + 3 muls -> amortized).
// R5's counters showed the 1-deep prefetch chain was latency-bound
// (VALUBusy 57%, BW 1.77 TB/s < fabric's 2.5).
// ---------------------------------------------------------------------------
__global__ __launch_bounds__(256) void gat4_kernel(const _Float16* __restrict__ fs,
                                                   const float* __restrict__ fd,
                                                   const float* __restrict__ lin,
                                                   const int* __restrict__ src,
                                                   const float* __restrict__ attn,
                                                   const float* __restrict__ bias,
                                                   float* __restrict__ out) {
  constexpr int F = 128;
  const int lane = threadIdx.x & 63;
  const int wave = threadIdx.x >> 6;
  const int li = lane & 15;
  const int node = blockIdx.x * 4 + wave;
  const int f0 = 2 * lane;
  const int srcv = src[(size_t)node * DEG + li];
  const float2 fdv = *(const float2*)&fd[(size_t)node * F + f0];
  const float a0 = attn[f0];
  const float a1 = attn[f0 + 1];
  // issue all DEG gathers (independent; addresses from register shfls)
  f16x2 curh[DEG];
#pragma unroll
  for (int d = 0; d < DEG; d++) {
    int sn = __shfl(srcv, (lane & 48) | d, 64);
    curh[d] = *(const f16x2*)&fs[(size_t)sn * F + f0];
  }
  // pass 1: logits + max (per-head dot via 16-lane xor-reduce)
  float p[DEG];
  float m = -1e30f;
#pragma unroll
  for (int d = 0; d < DEG; d++) {
    float c0 = (float)curh[d][0], c1 = (float)curh[d][1];
    float e0 = c0 + fdv.x; e0 = (e0 > 0.f) ? e0 : 0.2f * e0;
    float e1 = c1 + fdv.y; e1 = (e1 > 0.f) ? e1 : 0.2f * e1;
    float pp = e0 * a0 + e1 * a1;
    pp += __shfl_xor(pp, 1, 64);
    pp += __shfl_xor(pp, 2, 64);
    pp += __shfl_xor(pp, 4, 64);
    pp += __shfl_xor(pp, 8, 64);
    p[d] = pp;
    m = fmaxf(m, pp);
  }
  // pass 2: exp + accumulate (reference-form softmax)
  float s = 0.f, acc0 = 0.f, acc1 = 0.f;
#pragma unroll
  for (int d = 0; d < DEG; d++) {
    float ex = __expf(p[d] - m);
    s += ex;
    acc0 += ex * (float)curh[d][0];
    acc1 += ex * (float)curh[d][1];
  }
  float inv = 1.f / s;
  float2 lv = *(const float2*)&lin[(size_t)node * F + f0];
  float o0 = acc0 * inv + lv.x + bias[f0];
  float o1 = acc1 * inv + lv.y + bias[f0 + 1];
  o0 = (o0 > 0.f) ? o0 : __expf(o0) - 1.f;
  o1 = (o1 > 0.f) ? o1 : __expf(o1) - 1.f;
  *(float2*)&out[(size_t)node * F + f0] = make_float2(o0, o1);
}

// ---------------------------------------------------------------------------
// GATv2 H=1 (no ELU) + fused fw1 — R6: same up-front gather + two-pass
// softmax restructure (fp32 fs, [N,32]).
// ---------------------------------------------------------------------------
__global__ __launch_bounds__(256) void gat1_fw1_kernel(
    const float* __restrict__ fs, const float* __restrict__ fd,
    const float* __restrict__ lin, const int* __restrict__ src,
    const float* __restrict__ attn, const float* __restrict__ bias,
    float* __restrict__ out, const float* __restrict__ feat,
    const float* __restrict__ wih, const float* __restrict__ wb,
    float* __restrict__ fwout) {
  __shared__ float w_s[100];
  __shared__ float b_s[20];
  if (blockIdx.x < 2048) {
    constexpr int F = 32;
    const int lane = threadIdx.x & 63;
    const int wave = threadIdx.x >> 6;
    const int G = lane >> 4, li = lane & 15;
    const int node = blockIdx.x * 16 + wave * 4 + G;
    const int f0 = 2 * li;
    const int srcv = src[(size_t)node * DEG + li];
    const float2 fdv = *(const float2*)&fd[(size_t)node * F + f0];
    const float a0 = attn[f0];
    const float a1 = attn[f0 + 1];
    float2 cur[DEG];
#pragma unroll
    for (int d = 0; d < DEG; d++) {
      int sn = __shfl(srcv, (lane & 48) | d, 64);
      cur[d] = *(const float2*)&fs[(size_t)sn * F + f0];
    }
    float p[DEG];
    float m = -1e30f;
#pragma unroll
    for (int d = 0; d < DEG; d++) {
      float e0 = cur[d].x + fdv.x; e0 = (e0 > 0.f) ? e0 : 0.2f * e0;
      float e1 = cur[d].y + fdv.y; e1 = (e1 > 0.f) ? e1 : 0.2f * e1;
      float pp = e0 * a0 + e1 * a1;
      pp += __shfl_xor(pp, 1, 64);
      pp += __shfl_xor(pp, 2, 64);
      pp += __shfl_xor(pp, 4, 64);
      pp += __shfl_xor(pp, 8, 64);
      p[d] = pp;
      m = fmaxf(m, pp);
    }
    float s = 0.f, acc0 = 0.f, acc1 = 0.f;
#pragma unroll
    for (int d = 0; d < DEG; d++) {
      float ex = __expf(p[d] - m);
      s += ex;
      acc0 += ex * cur[d].x;
      acc1 += ex * cur[d].y;
    }
    float inv = 1.f / s;
    float2 lv = *(const float2*)&lin[(size_t)node * F + f0];
    float o0 = acc0 * inv + lv.x + bias[f0];
    float o1 = acc1 * inv + lv.y + bias[f0 + 1];
    *(float2*)&out[(size_t)node * F + f0] = make_float2(o0, o1);
  } else {
    if (threadIdx.x < 100) w_s[threadIdx.x] = wih[threadIdx.x];
    if (threadIdx.x < 20) b_s[threadIdx.x] = wb[threadIdx.x];
    __syncthreads();
    const int n = (blockIdx.x - 2048) * 256 + threadIdx.x;
    float f[5];
#pragma unroll
    for (int k = 0; k < 5; k++) f[k] = feat[(size_t)n * 5 + k];
#pragma unroll
    for (int j = 0; j < 20; j++) {
      float a = b_s[j];
#pragma unroll
      for (int k = 0; k < 5; k++) a += f[k] * w_s[j * 5 + k];
      fwout[(size_t)n * 20 + j] = a;
    }
  }
}

// ---------------------------------------------------------------------------
// SAGE-1: LSTM + fused projection (R5-exact).
// ---------------------------------------------------------------------------
__global__ __attribute__((amdgpu_waves_per_eu(1, 4))) __launch_bounds__(256)
void lstm1s_kernel(const float* __restrict__ FW, const int* __restrict__ src,
                   const float* __restrict__ whh, const float* __restrict__ feat,
                   const float* __restrict__ wself, const float* __restrict__ wneigh,
                   const float* __restrict__ bias, float* __restrict__ x1out) {
  __shared__ float w_s[100];   // whh [20][5]
  __shared__ float ws_s[160];  // wself [5][32]
  __shared__ float wn_s[160];  // wneigh [5][32]
  __shared__ float b_s[32];
  if (threadIdx.x < 100) w_s[threadIdx.x] = whh[threadIdx.x];
  if (threadIdx.x < 160) {
    ws_s[threadIdx.x] = wself[threadIdx.x];
    wn_s[threadIdx.x] = wneigh[threadIdx.x];
  }
  if (threadIdx.x < 32) b_s[threadIdx.x] = bias[threadIdx.x];
  __syncthreads();
  const int n = blockIdx.x * 256 + threadIdx.x;
  const int* sp = src + (size_t)n * DEG;
  float f[5];
#pragma unroll
  for (int k = 0; k < 5; k++) f[k] = feat[(size_t)n * 5 + k];
  float h[5] = {0, 0, 0, 0, 0}, c[5] = {0, 0, 0, 0, 0};
  int sd = sp[0];
  float4 p0 = *(const float4*)&FW[(size_t)sd * 20 + 0];
  float4 p1 = *(const float4*)&FW[(size_t)sd * 20 + 4];
  float4 p2 = *(const float4*)&FW[(size_t)sd * 20 + 8];
  float4 p3 = *(const float4*)&FW[(size_t)sd * 20 + 12];
  float4 p4 = *(const float4*)&FW[(size_t)sd * 20 + 16];
  for (int d = 0; d < DEG; d++) {
    float g[20];
    g[0] = p0.x; g[1] = p0.y; g[2] = p0.z; g[3] = p0.w;
    g[4] = p1.x; g[5] = p1.y; g[6] = p1.z; g[7] = p1.w;
    g[8] = p2.x; g[9] = p2.y; g[10] = p2.z; g[11] = p2.w;
    g[12] = p3.x; g[13] = p3.y; g[14] = p3.z; g[15] = p3.w;
    g[16] = p4.x; g[17] = p4.y; g[18] = p4.z; g[19] = p4.w;
    if (d < DEG - 1) {
      int sn = sp[d + 1];
      p0 = *(const float4*)&FW[(size_t)sn * 20 + 0];
      p1 = *(const float4*)&FW[(size_t)sn * 20 + 4];
      p2 = *(const float4*)&FW[(size_t)sn * 20 + 8];
      p3 = *(const float4*)&FW[(size_t)sn * 20 + 12];
      p4 = *(const float4*)&FW[(size_t)sn * 20 + 16];
    }
#pragma unroll
    for (int j = 0; j < 20; j++) {
#pragma unroll
      for (int k = 0; k < 5; k++) g[j] += h[k] * w_s[j * 5 + k];
    }
#pragma unroll
    for (int k = 0; k < 5; k++) {
      float iv = sigmoidf_(g[k]);
      float fv = sigmoidf_(g[5 + k]);
      float gv = tanhf_(g[10 + k]);
      float ov = sigmoidf_(g[15 + k]);
      c[k] = fv * c[k] + iv * gv;
      h[k] = ov * tanhf_(c[k]);
    }
  }
#pragma unroll
  for (int j = 0; j < 32; j++) {
    float a = b_s[j];
#pragma unroll
    for (int k = 0; k < 5; k++) a += f[k] * ws_s[k * 32 + j] + h[k] * wn_s[k * 32 + j];
    x1out[(size_t)n * 32 + j] = fmaxf(a, 0.f);
  }
}

// ---------------------------------------------------------------------------
// SAGE-2 LSTM (MFMA) — R5-exact (fp16 permuted XW gather, rcp gates).
// ---------------------------------------------------------------------------
__global__ __launch_bounds__(256) __attribute__((amdgpu_waves_per_eu(1, 4)))
void lstm2_mfma_kernel(const _Float16* __restrict__ XW, const int* __restrict__ src,
                       const float* __restrict__ whh, float* __restrict__ hn_out) {
  __shared__ float h_lds_all[4 * 16 * 36];
  __shared__ int src_lds_all[4 * 256];
  const int tid = threadIdx.x;
  const int wid = tid >> 6;
  const int lane = tid & 63;
  const int q = lane >> 4;   // quad
  const int n = lane & 15;   // node within group / fragment col
  const int n0 = (blockIdx.x * 4 + wid) * 16;
  float* h_lds = &h_lds_all[wid * 16 * 36];
  int* src_lds = &src_lds_all[wid * 256];

  {
    int4 sv = *(const int4*)&src[(size_t)(n0 + (lane >> 2)) * DEG + 4 * (lane & 3)];
    src_lds[(4 * (lane & 3) + 0) * 16 + (lane >> 2)] = sv.x;
    src_lds[(4 * (lane & 3) + 1) * 16 + (lane >> 2)] = sv.y;
    src_lds[(4 * (lane & 3) + 2) * 16 + (lane >> 2)] = sv.z;
    src_lds[(4 * (lane & 3) + 3) * 16 + (lane >> 2)] = sv.w;
  }

  bf16x8 Whi[8], Wlo[8];
#pragma unroll
  for (int gt = 0; gt < 8; gt++) {
    float wv[8];
    *(float4*)&wv[0] = *(const float4*)&whh[(size_t)(16 * gt + n) * 32 + 8 * q];
    *(float4*)&wv[4] = *(const float4*)&whh[(size_t)(16 * gt + n) * 32 + 8 * q + 4];
    pack_hilo_(wv, Whi[gt], Wlo[gt]);
  }

  bf16x8 Bhi, Blo;
#pragma unroll
  for (int j = 0; j < 8; j++) { Bhi[j] = 0; Blo[j] = 0; }
  float cst[8];
#pragma unroll
  for (int i = 0; i < 8; i++) cst[i] = 0.f;

  f16x8 tch[4], tnh[4];
  {
    int s0 = src_lds[0 * 16 + n];
    const _Float16* gb = XW + (size_t)s0 * 128 + q * 32;
#pragma unroll
    for (int t = 0; t < 4; t++) tch[t] = *(const f16x8*)&gb[8 * t];
  }

  float hv[8];
#pragma unroll
  for (int d = 0; d < DEG; d++) {
    f32x4 D[4][2];
#pragma unroll
    for (int p = 0; p < 4; p++) {
#pragma unroll
      for (int hh = 0; hh < 2; hh++) {
        int gt = p * 2 + hh;
        f32x4 acc = {0.f, 0.f, 0.f, 0.f};
        acc = __builtin_amdgcn_mfma_f32_16x16x32_bf16(Whi[gt], Bhi, acc, 0, 0, 0);
        acc = __builtin_amdgcn_mfma_f32_16x16x32_bf16(Wlo[gt], Bhi, acc, 0, 0, 0);
        acc = __builtin_amdgcn_mfma_f32_16x16x32_bf16(Whi[gt], Blo, acc, 0, 0, 0);
        D[p][hh] = acc;
      }
    }
    if (d < DEG - 1) {
      int s = src_lds[(d + 1) * 16 + n];
      const _Float16* gb = XW + (size_t)s * 128 + q * 32;
#pragma unroll
      for (int t = 0; t < 4; t++) tnh[t] = *(const f16x8*)&gb[8 * t];
    }
#pragma unroll
    for (int hh = 0; hh < 2; hh++) {
#pragma unroll
      for (int r = 0; r < 4; r++) {
        int ci = hh * 4 + r;
        float xiv = (float)tch[0][hh * 4 + r];
        float xfv = (float)tch[1][hh * 4 + r];
        float xgv = (float)tch[2][hh * 4 + r];
        float xov = (float)tch[3][hh * 4 + r];
        float iv = sigmoidf_(D[0][hh][r] + xiv);
        float fv = sigmoidf_(D[1][hh][r] + xfv);
        float gv = tanhf_(D[2][hh][r] + xgv);
        float ov = sigmoidf_(D[3][hh][r] + xov);
        cst[ci] = fv * cst[ci] + iv * gv;
        hv[ci] = ov * tanhf_(cst[ci]);
      }
    }
    if (d < DEG - 1) {
      *(float4*)&h_lds[n * 36 + 0 + 4 * q] = make_float4(hv[0], hv[1], hv[2], hv[3]);
      *(float4*)&h_lds[n * 36 + 16 + 4 * q] = make_float4(hv[4], hv[5], hv[6], hv[7]);
      float hb[8];
      *(float4*)&hb[0] = *(const float4*)&h_lds[n * 36 + 8 * q];
      *(float4*)&hb[4] = *(const float4*)&h_lds[n * 36 + 8 * q + 4];
      pack_hilo_(hb, Bhi, Blo);
#pragma unroll
      for (int t = 0; t < 4; t++) tch[t] = tnh[t];
    }
  }
  *(float4*)&hn_out[(size_t)(n0 + n) * 32 + 0 + 4 * q] = make_float4(hv[0], hv[1], hv[2], hv[3]);
  *(float4*)&hn_out[(size_t)(n0 + n) * 32 + 16 + 4 * q] = make_float4(hv[4], hv[5], hv[6], hv[7]);
}

// ---------------------------------------------------------------------------
// Fused sage_out + final MLP (R4, unchanged).
// ---------------------------------------------------------------------------
__global__ __launch_bounds__(128) void sage_final_kernel(
    const float* __restrict__ x1, const float* __restrict__ hn,
    const float* __restrict__ wself, const float* __restrict__ wneigh,
    const float* __restrict__ sbias, const float* __restrict__ gat,
    const float* __restrict__ f1w, const float* __restrict__ f1b,
    const float* __restrict__ f2w, const float* __restrict__ f2b,
    float* __restrict__ out) {
  __shared__ float ws_s[32 * 32];
  __shared__ float wn_s[32 * 32];
  __shared__ float b_s[32];
  __shared__ float w1_s[64 * 16];
  __shared__ float b1_s[16];
  __shared__ float w2_s[16];
  for (int idx = threadIdx.x; idx < 1024; idx += 128) {
    ws_s[idx] = wself[idx];
    wn_s[idx] = wneigh[idx];
    w1_s[idx] = f1w[idx];
  }
  if (threadIdx.x < 32) b_s[threadIdx.x] = sbias[threadIdx.x];
  if (threadIdx.x < 16) {
    b1_s[threadIdx.x] = f1b[threadIdx.x];
    w2_s[threadIdx.x] = f2w[threadIdx.x];
  }
  __syncthreads();
  const int n = blockIdx.x * 128 + threadIdx.x;
  float xr[32], hr[32], z[64];
#pragma unroll
  for (int k = 0; k < 32; k += 4) {
    *(float4*)&xr[k] = *(const float4*)&x1[(size_t)n * 32 + k];
    *(float4*)&hr[k] = *(const float4*)&hn[(size_t)n * 32 + k];
    float4 a = *(const float4*)&gat[(size_t)n * 32 + k];
    z[k] = a.x; z[k + 1] = a.y; z[k + 2] = a.z; z[k + 3] = a.w;
  }
#pragma unroll
  for (int j = 0; j < 32; j++) {
    float a = b_s[j];
#pragma unroll
    for (int k = 0; k < 32; k++) a += xr[k] * ws_s[k * 32 + j];
#pragma unroll
    for (int k = 0; k < 32; k++) a += hr[k] * wn_s[k * 32 + j];
    z[32 + j] = fmaxf(a, 0.f);
  }
  float o = f2b[0];
#pragma unroll
  for (int j = 0; j < 16; j++) {
    float a = b1_s[j];
#pragma unroll
    for (int k = 0; k < 64; k++) a += z[k] * w1_s[k * 16 + j];
    o += fmaxf(a, 0.f) * w2_s[j];
  }
  out[n] = o;
}

extern "C" void kernel_launch(void* const* d_in, const int* in_sizes, int n_in,
                              void* d_out, int out_size, void* d_ws, size_t ws_size,
                              hipStream_t stream) {
  const int N = NNODES;
  const float* feat = (const float*)d_in[0];
  const int* src = (const int*)d_in[1];
  const float* g0_ws = (const float*)d_in[2];
  const float* g0_bs = (const float*)d_in[3];
  const float* g0_wd = (const float*)d_in[4];
  const float* g0_bd = (const float*)d_in[5];
  const float* g0_attn = (const float*)d_in[6];
  const float* g0_bias = (const float*)d_in[7];
  const float* l0_w = (const float*)d_in[8];
  const float* l0_b = (const float*)d_in[9];
  const float* g1_ws = (const float*)d_in[10];
  const float* g1_bs = (const float*)d_in[11];
  const float* g1_wd = (const float*)d_in[12];
  const float* g1_bd = (const float*)d_in[13];
  const float* g1_attn = (const float*)d_in[14];
  const float* g1_bias = (const float*)d_in[15];
  const float* l1_w = (const float*)d_in[16];
  const float* l1_b = (const float*)d_in[17];
  const float* g2_ws = (const float*)d_in[18];
  const float* g2_bs = (const float*)d_in[19];
  const float* g2_wd = (const float*)d_in[20];
  const float* g2_bd = (const float*)d_in[21];
  const float* g2_attn = (const float*)d_in[22];
  const float* g2_bias = (const float*)d_in[23];
  const float* l2_w = (const float*)d_in[24];
  const float* l2_b = (const float*)d_in[25];
  const float* s1_wih = (const float*)d_in[26];
  const float* s1_whh = (const float*)d_in[27];
  const float* s1_b = (const float*)d_in[28];
  const float* s1_wself = (const float*)d_in[29];
  const float* s1_wneigh = (const float*)d_in[30];
  const float* s1_bias = (const float*)d_in[31];
  const float* s2_wih = (const float*)d_in[32];
  const float* s2_whh = (const float*)d_in[33];
  const float* s2_b = (const float*)d_in[34];
  const float* s2_wself = (const float*)d_in[35];
  const float* s2_wneigh = (const float*)d_in[36];
  const float* s2_bias = (const float*)d_in[37];
  const float* f1_w = (const float*)d_in[38];
  const float* f1_b = (const float*)d_in[39];
  const float* f2_w = (const float*)d_in[40];
  const float* f2_b = (const float*)d_in[41];

  float* A = (float*)d_ws;                // N*128
  float* B = A + (size_t)N * 128;
  float* C = B + (size_t)N * 128;
  float* D = C + (size_t)N * 128;
  float* E = D + (size_t)N * 128;         // A..E = 84 MB
  short* Wp = (short*)(A + (size_t)5 * N * 128);  // packed bf16 weights, 262 KB

  // 1. startup: fc3 layer0 (A=fs[fp16], B=fd, C=lin) + repack 7 weights
  startup_kernel<<<6151, 256, 0, stream>>>(
      feat, g0_ws, g0_bs, g0_wd, g0_bd, l0_w, l0_b,
      (_Float16*)A, B, C,
      g1_ws, g1_wd, l1_w, g2_ws, g2_wd, l2_w, s2_wih, Wp);
  // 2. GAT layer 0 -> D = h1
  gat4_kernel<<<N / 4, 256, 0, stream>>>((const _Float16*)A, B, C, src,
                                         g0_attn, g0_bias, D);
  // 3. layer-1 FC trio (MFMA) -> A=fs[fp16], B, C
  mfma_fc_kernel<4, 8, 3, 1><<<N / 64, 256, 0, stream>>>(
      D, Wp + WP_G1, g1_bs, g1_bd, l1_b, A, B, C);
  // 4. GAT layer 1 -> E = h2
  gat4_kernel<<<N / 4, 256, 0, stream>>>((const _Float16*)A, B, C, src,
                                         g1_attn, g1_bias, E);
  // 5. layer-2 FC trio (MFMA) -> A,B,C  (N x 32 each, fp32)
  mfma_fc_kernel<4, 2, 3, 0><<<N / 64, 256, 0, stream>>>(
      E, Wp + WP_G2, g2_bs, g2_bd, l2_b, A, B, C);
  // 6. GAT layer 2 -> D = gat [N,32]; + fused fw1 -> E = FW1 [N,20]
  gat1_fw1_kernel<<<2048 + 128, 256, 0, stream>>>(
      A, B, C, src, g2_attn, g2_bias, D, feat, s1_wih, s1_b, E);
  // 7. SAGE-1 LSTM + projection -> C = x1 [N,32]
  lstm1s_kernel<<<N / 256, 256, 0, stream>>>(E, src, s1_whh, feat, s1_wself,
                                             s1_wneigh, s1_bias, C);
  // 8. XW2 = x1 @ wih.T + b -> A as fp16 permuted [N,128]
  xw_half_kernel<<<N / 64, 256, 0, stream>>>(
      C, Wp + WP_S2WIH, s2_b, (_Float16*)A);
  // 9. SAGE-2 LSTM -> E = hn2 [N,32]
  lstm2_mfma_kernel<<<N / 64, 256, 0, stream>>>((const _Float16*)A, src, s2_whh, E);
  // 10. fused sage_out + final MLP -> out
  sage_final_kernel<<<N / 128, 128, 0, stream>>>(
      C, E, s2_wself, s2_wneigh, s2_bias, D, f1_w, f1_b, f2_w, f2_b,
      (float*)d_out);
}

// Round 7
// 370.711 us; speedup vs baseline: 1.3711x; 1.0010x over previous
//
#include <hip/hip_runtime.h>
#include <hip/hip_bf16.h>

#define NNODES 32768
#define DEG 16

// R5: fast sigmoid/tanh — v_rcp_f32 instead of IEEE div chain. ~1 ulp.
__device__ __forceinline__ float sigmoidf_(float x) {
  return __builtin_amdgcn_rcpf(1.f + __expf(-x));
}
__device__ __forceinline__ float tanhf_(float x) {
  return 1.f - 2.f * __builtin_amdgcn_rcpf(__expf(2.f * x) + 1.f);
}

typedef __attribute__((ext_vector_type(8))) short bf16x8;
typedef __attribute__((ext_vector_type(4))) float f32x4;
typedef __attribute__((ext_vector_type(8))) _Float16 f16x8;
typedef __attribute__((ext_vector_type(2))) _Float16 f16x2;

__device__ __forceinline__ unsigned short f2bf_(float x) {
  __hip_bfloat16 b = __float2bfloat16(x);
  union { __hip_bfloat16 b; unsigned short u; } cv;
  cv.b = b;
  return cv.u;
}
__device__ __forceinline__ float bf2f_(unsigned short u) {
  union { unsigned short u; __hip_bfloat16 b; } cv;
  cv.u = u;
  return __bfloat162float(cv.b);
}

// R7: pack_hilo_ via gfx950 v_cvt_pk_bf16_f32 (2 f32 -> packed 2x bf16, RNE,
// D.lo16<-S0 / D.hi16<-S1). Replaces the ~100-inst software-RNE sequence
// (__float2bfloat16 x16) with ~24 insts. lo is computed from the EXACT
// residual v - unpack(hi), so even if HW rounding differed from SW RNE the
// hi+lo sum is preserved; 3-product MFMA result unchanged to ~2^-18 rel.
__device__ __forceinline__ void pack_hilo_(const float* v, bf16x8& hi, bf16x8& lo) {
  union { unsigned w[4]; bf16x8 h; } uh, ul;
#pragma unroll
  for (int j = 0; j < 4; j++) {
    unsigned rh;
    asm("v_cvt_pk_bf16_f32 %0, %1, %2" : "=v"(rh) : "v"(v[2 * j]), "v"(v[2 * j + 1]));
    float h0 = __uint_as_float(rh << 16);
    float h1 = __uint_as_float(rh & 0xffff0000u);
    float r0 = v[2 * j] - h0;
    float r1 = v[2 * j + 1] - h1;
    unsigned rl;
    asm("v_cvt_pk_bf16_f32 %0, %1, %2" : "=v"(rl) : "v"(r0), "v"(r1));
    uh.w[j] = rh;
    ul.w[j] = rl;
  }
  hi = uh.h;
  lo = ul.h;
}

// Packed-weight offsets (shorts); hi block then lo block per matrix.
#define WP_G1    0        // 3 x (128x128): stride 32768
#define WP_G2    98304    // 3 x (128x32):  stride 8192
#define WP_S2WIH 122880   // 32x128 (transposed use)
#define WP_TOTAL 131072

// ---------------------------------------------------------------------------
// Startup mega-kernel (R5-exact): fc3 layer0 (fs fp16) + weight repack.
// ---------------------------------------------------------------------------
__global__ __launch_bounds__(256) void startup_kernel(
    const float* __restrict__ feat,
    const float* __restrict__ W0, const float* __restrict__ B0,
    const float* __restrict__ W1, const float* __restrict__ B1,
    const float* __restrict__ W2, const float* __restrict__ B2,
    _Float16* __restrict__ O0h, float* __restrict__ O1, float* __restrict__ O2,
    const float* __restrict__ g1ws, const float* __restrict__ g1wd,
    const float* __restrict__ l1w, const float* __restrict__ g2ws,
    const float* __restrict__ g2wd, const float* __restrict__ l2w,
    const float* __restrict__ s2wih, short* __restrict__ Wp) {
  __shared__ float w_s[5 * 64];
  __shared__ float in_s[32 * 8];
  __shared__ float b_s[64];
  const int bid = blockIdx.x;
  const int t = threadIdx.x;
  if (bid < 6144) {
    const int bz = bid >> 11, rem = bid & 2047, by = rem >> 10, bx = rem & 1023;
    const float* W = (bz == 0) ? W0 : (bz == 1) ? W1 : W2;
    const float* bias = (bz == 0) ? B0 : (bz == 1) ? B1 : B2;
    const int rowBase = bx * 32;
    const int colBase = by * 64;
    for (int idx = t; idx < 5 * 64; idx += 256) {
      int k = idx >> 6, jj = idx & 63;
      w_s[idx] = W[(size_t)k * 128 + colBase + jj];
    }
    if (t < 64) b_s[t] = bias[colBase + t];
    for (int idx = t; idx < 32 * 5; idx += 256) {
      int r = idx / 5, k = idx - r * 5;
      in_s[r * 8 + k] = feat[(size_t)(rowBase + r) * 5 + k];
    }
    __syncthreads();
    const int jj = t & 63;
    const int rslot = t >> 6;
    float acc[8];
#pragma unroll
    for (int r = 0; r < 8; r++) acc[r] = b_s[jj];
    {
      float wv0 = w_s[0 * 64 + jj], wv1 = w_s[1 * 64 + jj];
      float wv2 = w_s[2 * 64 + jj], wv3 = w_s[3 * 64 + jj];
#pragma unroll
      for (int r = 0; r < 8; r++) {
        float4 ip = *(const float4*)&in_s[(rslot * 8 + r) * 8];
        acc[r] += ip.x * wv0 + ip.y * wv1 + ip.z * wv2 + ip.w * wv3;
      }
      float wv4 = w_s[4 * 64 + jj];
#pragma unroll
      for (int r = 0; r < 8; r++) acc[r] += in_s[(rslot * 8 + r) * 8 + 4] * wv4;
    }
    if (bz == 0) {
#pragma unroll
      for (int r = 0; r < 8; r++)
        O0h[(size_t)(rowBase + rslot * 8 + r) * 128 + colBase + jj] =
            (_Float16)acc[r];
    } else {
      float* out = (bz == 1) ? O1 : O2;
#pragma unroll
      for (int r = 0; r < 8; r++)
        out[(size_t)(rowBase + rslot * 8 + r) * 128 + colBase + jj] = acc[r];
    }
  } else {
    const int mid = bid - 6144;
    const float* W;
    int FI, FO, TRANS;
    size_t base;
    if (mid == 0)      { W = g1ws;  FI = 128; FO = 128; TRANS = 0; base = WP_G1; }
    else if (mid == 1) { W = g1wd;  FI = 128; FO = 128; TRANS = 0; base = WP_G1 + 32768; }
    else if (mid == 2) { W = l1w;   FI = 128; FO = 128; TRANS = 0; base = WP_G1 + 65536; }
    else if (mid == 3) { W = g2ws;  FI = 128; FO = 32;  TRANS = 0; base = WP_G2; }
    else if (mid == 4) { W = g2wd;  FI = 128; FO = 32;  TRANS = 0; base = WP_G2 + 8192; }
    else if (mid == 5) { W = l2w;   FI = 128; FO = 32;  TRANS = 0; base = WP_G2 + 16384; }
    else               { W = s2wih; FI = 32;  FO = 128; TRANS = 1; base = WP_S2WIH; }
    const int KS = FI / 32;
    const int total = FI * FO;
    for (int p = t; p < total; p += 256) {
      int j = p & 7, lane = (p >> 3) & 63, rest = p >> 9;
      int ks = rest % KS, f = rest / KS;
      int n = lane & 15, q = lane >> 4;
      int k = 32 * ks + 8 * q + j, fo = 16 * f + n;
      float v = TRANS ? W[(size_t)fo * FI + k] : W[(size_t)k * FO + fo];
      unsigned short hi = f2bf_(v);
      float resid = v - bf2f_(hi);
      Wp[base + p] = (short)hi;
      Wp[base + total + p] = (short)f2bf_(resid);
    }
  }
}

// ---------------------------------------------------------------------------
// MFMA FC (R5-exact structure, HALF0 flag for fp16 fs output).
// ---------------------------------------------------------------------------
template <int KS, int FOT, int NZ, int HALF0>  // FI=32*KS, FO=16*FOT
__global__ __launch_bounds__(256) __attribute__((amdgpu_waves_per_eu(1, 4)))
void mfma_fc_kernel(const float* __restrict__ in, const short* __restrict__ Wp,
                    const float* __restrict__ B0, const float* __restrict__ B1,
                    const float* __restrict__ B2, float* __restrict__ O0,
                    float* __restrict__ O1, float* __restrict__ O2) {
  constexpr int FI = 32 * KS;
  constexpr int FO = 16 * FOT;
  const int tid = threadIdx.x;
  const int wid = tid >> 6;
  const int lane = tid & 63;
  const int q = lane >> 4, n = lane & 15;
  const int n0 = blockIdx.x * 64 + wid * 16;
  bf16x8 Ahi[KS], Alo[KS];
#pragma unroll
  for (int ks = 0; ks < KS; ks++) {
    float av[8];
    *(float4*)&av[0] = *(const float4*)&in[(size_t)(n0 + n) * FI + 32 * ks + 8 * q];
    *(float4*)&av[4] = *(const float4*)&in[(size_t)(n0 + n) * FI + 32 * ks + 8 * q + 4];
    pack_hilo_(av, Ahi[ks], Alo[ks]);
  }
#pragma unroll
  for (int z = 0; z < NZ; z++) {
    const short* wz = Wp + (size_t)z * FI * FO * 2;
    const float* bz = (z == 0) ? B0 : (z == 1) ? B1 : B2;
    float* oz = (z == 0) ? O0 : (z == 1) ? O1 : O2;
#pragma unroll
    for (int f = 0; f < FOT; f++) {
      float bv = bz[16 * f + n];
      f32x4 acc = {bv, bv, bv, bv};
#pragma unroll
      for (int ks = 0; ks < KS; ks++) {
        bf16x8 Bhi = *(const bf16x8*)&wz[((size_t)(f * KS + ks) * 64 + lane) * 8];
        bf16x8 Blo = *(const bf16x8*)&wz[(size_t)FI * FO + ((size_t)(f * KS + ks) * 64 + lane) * 8];
        acc = __builtin_amdgcn_mfma_f32_16x16x32_bf16(Ahi[ks], Bhi, acc, 0, 0, 0);
        acc = __builtin_amdgcn_mfma_f32_16x16x32_bf16(Alo[ks], Bhi, acc, 0, 0, 0);
        acc = __builtin_amdgcn_mfma_f32_16x16x32_bf16(Ahi[ks], Blo, acc, 0, 0, 0);
      }
      if (HALF0 && z == 0) {
#pragma unroll
        for (int r = 0; r < 4; r++)
          ((_Float16*)O0)[(size_t)(n0 + 4 * q + r) * FO + 16 * f + n] =
              (_Float16)acc[r];
      } else {
#pragma unroll
        for (int r = 0; r < 4; r++)
          oz[(size_t)(n0 + 4 * q + r) * FO + 16 * f + n] = acc[r];
      }
    }
  }
}

// ---------------------------------------------------------------------------
// XW writer (R4-exact structure): fp16 permuted XW.
// ---------------------------------------------------------------------------
__global__ __launch_bounds__(256) __attribute__((amdgpu_waves_per_eu(1, 4)))
void xw_half_kernel(const float* __restrict__ in, const short* __restrict__ Wp,
                    const float* __restrict__ bz, _Float16* __restrict__ XWh) {
  const int tid = threadIdx.x;
  const int wid = tid >> 6;
  const int lane = tid & 63;
  const int q = lane >> 4, n = lane & 15;
  const int n0 = blockIdx.x * 64 + wid * 16;
  bf16x8 Ahi, Alo;
  {
    float av[8];
    *(float4*)&av[0] = *(const float4*)&in[(size_t)(n0 + n) * 32 + 8 * q];
    *(float4*)&av[4] = *(const float4*)&in[(size_t)(n0 + n) * 32 + 8 * q + 4];
    pack_hilo_(av, Ahi, Alo);
  }
#pragma unroll
  for (int f = 0; f < 8; f++) {
    float bv = bz[16 * f + n];
    f32x4 acc = {bv, bv, bv, bv};
    bf16x8 Bhi = *(const bf16x8*)&Wp[((size_t)f * 64 + lane) * 8];
    bf16x8 Blo = *(const bf16x8*)&Wp[4096 + ((size_t)f * 64 + lane) * 8];
    acc = __builtin_amdgcn_mfma_f32_16x16x32_bf16(Ahi, Bhi, acc, 0, 0, 0);
    acc = __builtin_amdgcn_mfma_f32_16x16x32_bf16(Alo, Bhi, acc, 0, 0, 0);
    acc = __builtin_amdgcn_mfma_f32_16x16x32_bf16(Ahi, Blo, acc, 0, 0, 0);
    // gate dim g = 16*f + n; perm(g) = (n>>2)*32 + f*4 + (n&3)
#pragma unroll
    for (int r = 0; r < 4; r++)
      XWh[(size_t)(n0 + 4 * q + r) * 128 + ((n >> 2) * 32 + f * 4 + (n & 3))] =
          (_Float16)acc[r];
  }
}

// ---------------------------------------------------------------------------
// GATv2 H=4 (R6-exact: up-front 16-deep gather + two-pass softmax).
// ---------------------------------------------------------------------------
__global__ __launch_bounds__(256) void gat4_kernel(const _Float16* __restrict__ fs,
                                                   const float* __restrict__ fd,
                                                   const float* __restrict__ lin,
                                                   const int* __restrict__ src,
                                                   const float* __restrict__ attn,
                                                   const float* __restrict__ bias,
                                                   float* __restrict__ out) {
  constexpr int F = 128;
  const int lane = threadIdx.x & 63;
  const int wave = threadIdx.x >> 6;
  const int li = lane & 15;
  const int node = blockIdx.x * 4 + wave;
  const int f0 = 2 * lane;
  const int srcv = src[(size_t)node * DEG + li];
  const float2 fdv = *(const float2*)&fd[(size_t)node * F + f0];
  const float a0 = attn[f0];
  const float a1 = attn[f0 + 1];
  f16x2 curh[DEG];
#pragma unroll
  for (int d = 0; d < DEG; d++) {
    int sn = __shfl(srcv, (lane & 48) | d, 64);
    curh[d] = *(const f16x2*)&fs[(size_t)sn * F + f0];
  }
  float p[DEG];
  float m = -1e30f;
#pragma unroll
  for (int d = 0; d < DEG; d++) {
    float c0 = (float)curh[d][0], c1 = (float)curh[d][1];
    float e0 = c0 + fdv.x; e0 = (e0 > 0.f) ? e0 : 0.2f * e0;
    float e1 = c1 + fdv.y; e1 = (e1 > 0.f) ? e1 : 0.2f * e1;
    float pp = e0 * a0 + e1 * a1;
    pp += __shfl_xor(pp, 1, 64);
    pp += __shfl_xor(pp, 2, 64);
    pp += __shfl_xor(pp, 4, 64);
    pp += __shfl_xor(pp, 8, 64);
    p[d] = pp;
    m = fmaxf(m, pp);
  }
  float s = 0.f, acc0 = 0.f, acc1 = 0.f;
#pragma unroll
  for (int d = 0; d < DEG; d++) {
    float ex = __expf(p[d] - m);
    s += ex;
    acc0 += ex * (float)curh[d][0];
    acc1 += ex * (float)curh[d][1];
  }
  float inv = 1.f / s;
  float2 lv = *(const float2*)&lin[(size_t)node * F + f0];
  float o0 = acc0 * inv + lv.x + bias[f0];
  float o1 = acc1 * inv + lv.y + bias[f0 + 1];
  o0 = (o0 > 0.f) ? o0 : __expf(o0) - 1.f;
  o1 = (o1 > 0.f) ? o1 : __expf(o1) - 1.f;
  *(float2*)&out[(size_t)node * F + f0] = make_float2(o0, o1);
}

// ---------------------------------------------------------------------------
// GATv2 H=1 (no ELU) + fused fw1 (R6-exact).
// ---------------------------------------------------------------------------
__global__ __launch_bounds__(256) void gat1_fw1_kernel(
    const float* __restrict__ fs, const float* __restrict__ fd,
    const float* __restrict__ lin, const int* __restrict__ src,
    const float* __restrict__ attn, const float* __restrict__ bias,
    float* __restrict__ out, const float* __restrict__ feat,
    const float* __restrict__ wih, const float* __restrict__ wb,
    float* __restrict__ fwout) {
  __shared__ float w_s[100];
  __shared__ float b_s[20];
  if (blockIdx.x < 2048) {
    constexpr int F = 32;
    const int lane = threadIdx.x & 63;
    const int wave = threadIdx.x >> 6;
    const int G = lane >> 4, li = lane & 15;
    const int node = blockIdx.x * 16 + wave * 4 + G;
    const int f0 = 2 * li;
    const int srcv = src[(size_t)node * DEG + li];
    const float2 fdv = *(const float2*)&fd[(size_t)node * F + f0];
    const float a0 = attn[f0];
    const float a1 = attn[f0 + 1];
    float2 cur[DEG];
#pragma unroll
    for (int d = 0; d < DEG; d++) {
      int sn = __shfl(srcv, (lane & 48) | d, 64);
      cur[d] = *(const float2*)&fs[(size_t)sn * F + f0];
    }
    float p[DEG];
    float m = -1e30f;
#pragma unroll
    for (int d = 0; d < DEG; d++) {
      float e0 = cur[d].x + fdv.x; e0 = (e0 > 0.f) ? e0 : 0.2f * e0;
      float e1 = cur[d].y + fdv.y; e1 = (e1 > 0.f) ? e1 : 0.2f * e1;
      float pp = e0 * a0 + e1 * a1;
      pp += __shfl_xor(pp, 1, 64);
      pp += __shfl_xor(pp, 2, 64);
      pp += __shfl_xor(pp, 4, 64);
      pp += __shfl_xor(pp, 8, 64);
      p[d] = pp;
      m = fmaxf(m, pp);
    }
    float s = 0.f, acc0 = 0.f, acc1 = 0.f;
#pragma unroll
    for (int d = 0; d < DEG; d++) {
      float ex = __expf(p[d] - m);
      s += ex;
      acc0 += ex * cur[d].x;
      acc1 += ex * cur[d].y;
    }
    float inv = 1.f / s;
    float2 lv = *(const float2*)&lin[(size_t)node * F + f0];
    float o0 = acc0 * inv + lv.x + bias[f0];
    float o1 = acc1 * inv + lv.y + bias[f0 + 1];
    *(float2*)&out[(size_t)node * F + f0] = make_float2(o0, o1);
  } else {
    if (threadIdx.x < 100) w_s[threadIdx.x] = wih[threadIdx.x];
    if (threadIdx.x < 20) b_s[threadIdx.x] = wb[threadIdx.x];
    __syncthreads();
    const int n = (blockIdx.x - 2048) * 256 + threadIdx.x;
    float f[5];
#pragma unroll
    for (int k = 0; k < 5; k++) f[k] = feat[(size_t)n * 5 + k];
#pragma unroll
    for (int j = 0; j < 20; j++) {
      float a = b_s[j];
#pragma unroll
      for (int k = 0; k < 5; k++) a += f[k] * w_s[j * 5 + k];
      fwout[(size_t)n * 20 + j] = a;
    }
  }
}

// ---------------------------------------------------------------------------
// SAGE-1: LSTM + fused projection — R7: 128-thread blocks, grid N/128 = 256
// -> one block per CU (was 128 blocks of 256: half the CUs idle). Math
// byte-identical; only the LDS staging loops and n-derivation change.
// ---------------------------------------------------------------------------
__global__ __attribute__((amdgpu_waves_per_eu(1, 4))) __launch_bounds__(128)
void lstm1s_kernel(const float* __restrict__ FW, const int* __restrict__ src,
                   const float* __restrict__ whh, const float* __restrict__ feat,
                   const float* __restrict__ wself, const float* __restrict__ wneigh,
                   const float* __restrict__ bias, float* __restrict__ x1out) {
  __shared__ float w_s[100];   // whh [20][5]
  __shared__ float ws_s[160];  // wself [5][32]
  __shared__ float wn_s[160];  // wneigh [5][32]
  __shared__ float b_s[32];
  if (threadIdx.x < 100) w_s[threadIdx.x] = whh[threadIdx.x];
  for (int i = threadIdx.x; i < 160; i += 128) {
    ws_s[i] = wself[i];
    wn_s[i] = wneigh[i];
  }
  if (threadIdx.x < 32) b_s[threadIdx.x] = bias[threadIdx.x];
  __syncthreads();
  const int n = blockIdx.x * 128 + threadIdx.x;
  const int* sp = src + (size_t)n * DEG;
  float f[5];
#pragma unroll
  for (int k = 0; k < 5; k++) f[k] = feat[(size_t)n * 5 + k];
  float h[5] = {0, 0, 0, 0, 0}, c[5] = {0, 0, 0, 0, 0};
  int sd = sp[0];
  float4 p0 = *(const float4*)&FW[(size_t)sd * 20 + 0];
  float4 p1 = *(const float4*)&FW[(size_t)sd * 20 + 4];
  float4 p2 = *(const float4*)&FW[(size_t)sd * 20 + 8];
  float4 p3 = *(const float4*)&FW[(size_t)sd * 20 + 12];
  float4 p4 = *(const float4*)&FW[(size_t)sd * 20 + 16];
  for (int d = 0; d < DEG; d++) {
    float g[20];
    g[0] = p0.x; g[1] = p0.y; g[2] = p0.z; g[3] = p0.w;
    g[4] = p1.x; g[5] = p1.y; g[6] = p1.z; g[7] = p1.w;
    g[8] = p2.x; g[9] = p2.y; g[10] = p2.z; g[11] = p2.w;
    g[12] = p3.x; g[13] = p3.y; g[14] = p3.z; g[15] = p3.w;
    g[16] = p4.x; g[17] = p4.y; g[18] = p4.z; g[19] = p4.w;
    if (d < DEG - 1) {
      int sn = sp[d + 1];
      p0 = *(const float4*)&FW[(size_t)sn * 20 + 0];
      p1 = *(const float4*)&FW[(size_t)sn * 20 + 4];
      p2 = *(const float4*)&FW[(size_t)sn * 20 + 8];
      p3 = *(const float4*)&FW[(size_t)sn * 20 + 12];
      p4 = *(const float4*)&FW[(size_t)sn * 20 + 16];
    }
#pragma unroll
    for (int j = 0; j < 20; j++) {
#pragma unroll
      for (int k = 0; k < 5; k++) g[j] += h[k] * w_s[j * 5 + k];
    }
#pragma unroll
    for (int k = 0; k < 5; k++) {
      float iv = sigmoidf_(g[k]);
      float fv = sigmoidf_(g[5 + k]);
      float gv = tanhf_(g[10 + k]);
      float ov = sigmoidf_(g[15 + k]);
      c[k] = fv * c[k] + iv * gv;
      h[k] = ov * tanhf_(c[k]);
    }
  }
#pragma unroll
  for (int j = 0; j < 32; j++) {
    float a = b_s[j];
#pragma unroll
    for (int k = 0; k < 5; k++) a += f[k] * ws_s[k * 32 + j] + h[k] * wn_s[k * 32 + j];
    x1out[(size_t)n * 32 + j] = fmaxf(a, 0.f);
  }
}

// ---------------------------------------------------------------------------
// SAGE-2 LSTM (MFMA) — R6-exact structure; benefits from fast pack_hilo_
// (called every step for the h repack — was ~25% of its VALU issue).
// ---------------------------------------------------------------------------
__global__ __launch_bounds__(256) __attribute__((amdgpu_waves_per_eu(1, 4)))
void lstm2_mfma_kernel(const _Float16* __restrict__ XW, const int* __restrict__ src,
                       const float* __restrict__ whh, float* __restrict__ hn_out) {
  __shared__ float h_lds_all[4 * 16 * 36];
  __shared__ int src_lds_all[4 * 256];
  const int tid = threadIdx.x;
  const int wid = tid >> 6;
  const int lane = tid & 63;
  const int q = lane >> 4;   // quad
  const int n = lane & 15;   // node within group / fragment col
  const int n0 = (blockIdx.x * 4 + wid) * 16;
  float* h_lds = &h_lds_all[wid * 16 * 36];
  int* src_lds = &src_lds_all[wid * 256];

  {
    int4 sv = *(const int4*)&src[(size_t)(n0 + (lane >> 2)) * DEG + 4 * (lane & 3)];
    src_lds[(4 * (lane & 3) + 0) * 16 + (lane >> 2)] = sv.x;
    src_lds[(4 * (lane & 3) + 1) * 16 + (lane >> 2)] = sv.y;
    src_lds[(4 * (lane & 3) + 2) * 16 + (lane >> 2)] = sv.z;
    src_lds[(4 * (lane & 3) + 3) * 16 + (lane >> 2)] = sv.w;
  }

  bf16x8 Whi[8], Wlo[8];
#pragma unroll
  for (int gt = 0; gt < 8; gt++) {
    float wv[8];
    *(float4*)&wv[0] = *(const float4*)&whh[(size_t)(16 * gt + n) * 32 + 8 * q];
    *(float4*)&wv[4] = *(const float4*)&whh[(size_t)(16 * gt + n) * 32 + 8 * q + 4];
    pack_hilo_(wv, Whi[gt], Wlo[gt]);
  }

  bf16x8 Bhi, Blo;
#pragma unroll
  for (int j = 0; j < 8; j++) { Bhi[j] = 0; Blo[j] = 0; }
  float cst[8];
#pragma unroll
  for (int i = 0; i < 8; i++) cst[i] = 0.f;

  f16x8 tch[4], tnh[4];
  {
    int s0 = src_lds[0 * 16 + n];
    const _Float16* gb = XW + (size_t)s0 * 128 + q * 32;
#pragma unroll
    for (int t = 0; t < 4; t++) tch[t] = *(const f16x8*)&gb[8 * t];
  }

  float hv[8];
#pragma unroll
  for (int d = 0; d < DEG; d++) {
    f32x4 D[4][2];
#pragma unroll
    for (int p = 0; p < 4; p++) {
#pragma unroll
      for (int hh = 0; hh < 2; hh++) {
        int gt = p * 2 + hh;
        f32x4 acc = {0.f, 0.f, 0.f, 0.f};
        acc = __builtin_amdgcn_mfma_f32_16x16x32_bf16(Whi[gt], Bhi, acc, 0, 0, 0);
        acc = __builtin_amdgcn_mfma_f32_16x16x32_bf16(Wlo[gt], Bhi, acc, 0, 0, 0);
        acc = __builtin_amdgcn_mfma_f32_16x16x32_bf16(Whi[gt], Blo, acc, 0, 0, 0);
        D[p][hh] = acc;
      }
    }
    if (d < DEG - 1) {
      int s = src_lds[(d + 1) * 16 + n];
      const _Float16* gb = XW + (size_t)s * 128 + q * 32;
#pragma unroll
      for (int t = 0; t < 4; t++) tnh[t] = *(const f16x8*)&gb[8 * t];
    }
#pragma unroll
    for (int hh = 0; hh < 2; hh++) {
#pragma unroll
      for (int r = 0; r < 4; r++) {
        int ci = hh * 4 + r;
        float xiv = (float)tch[0][hh * 4 + r];
        float xfv = (float)tch[1][hh * 4 + r];
        float xgv = (float)tch[2][hh * 4 + r];
        float xov = (float)tch[3][hh * 4 + r];
        float iv = sigmoidf_(D[0][hh][r] + xiv);
        float fv = sigmoidf_(D[1][hh][r] + xfv);
        float gv = tanhf_(D[2][hh][r] + xgv);
        float ov = sigmoidf_(D[3][hh][r] + xov);
        cst[ci] = fv * cst[ci] + iv * gv;
        hv[ci] = ov * tanhf_(cst[ci]);
      }
    }
    if (d < DEG - 1) {
      *(float4*)&h_lds[n * 36 + 0 + 4 * q] = make_float4(hv[0], hv[1], hv[2], hv[3]);
      *(float4*)&h_lds[n * 36 + 16 + 4 * q] = make_float4(hv[4], hv[5], hv[6], hv[7]);
      float hb[8];
      *(float4*)&hb[0] = *(const float4*)&h_lds[n * 36 + 8 * q];
      *(float4*)&hb[4] = *(const float4*)&h_lds[n * 36 + 8 * q + 4];
      pack_hilo_(hb, Bhi, Blo);
#pragma unroll
      for (int t = 0; t < 4; t++) tch[t] = tnh[t];
    }
  }
  *(float4*)&hn_out[(size_t)(n0 + n) * 32 + 0 + 4 * q] = make_float4(hv[0], hv[1], hv[2], hv[3]);
  *(float4*)&hn_out[(size_t)(n0 + n) * 32 + 16 + 4 * q] = make_float4(hv[4], hv[5], hv[6], hv[7]);
}

// ---------------------------------------------------------------------------
// Fused sage_out + final MLP (R4-exact).
// ---------------------------------------------------------------------------
__global__ __launch_bounds__(128) void sage_final_kernel(
    const float* __restrict__ x1, const float* __restrict__ hn,
    const float* __restrict__ wself, const float* __restrict__ wneigh,
    const float* __restrict__ sbias, const float* __restrict__ gat,
    const float* __restrict__ f1w, const float* __restrict__ f1b,
    const float* __restrict__ f2w, const float* __restrict__ f2b,
    float* __restrict__ out) {
  __shared__ float ws_s[32 * 32];
  __shared__ float wn_s[32 * 32];
  __shared__ float b_s[32];
  __shared__ float w1_s[64 * 16];
  __shared__ float b1_s[16];
  __shared__ float w2_s[16];
  for (int idx = threadIdx.x; idx < 1024; idx += 128) {
    ws_s[idx] = wself[idx];
    wn_s[idx] = wneigh[idx];
    w1_s[idx] = f1w[idx];
  }
  if (threadIdx.x < 32) b_s[threadIdx.x] = sbias[threadIdx.x];
  if (threadIdx.x < 16) {
    b1_s[threadIdx.x] = f1b[threadIdx.x];
    w2_s[threadIdx.x] = f2w[threadIdx.x];
  }
  __syncthreads();
  const int n = blockIdx.x * 128 + threadIdx.x;
  float xr[32], hr[32], z[64];
#pragma unroll
  for (int k = 0; k < 32; k += 4) {
    *(float4*)&xr[k] = *(const float4*)&x1[(size_t)n * 32 + k];
    *(float4*)&hr[k] = *(const float4*)&hn[(size_t)n * 32 + k];
    float4 a = *(const float4*)&gat[(size_t)n * 32 + k];
    z[k] = a.x; z[k + 1] = a.y; z[k + 2] = a.z; z[k + 3] = a.w;
  }
#pragma unroll
  for (int j = 0; j < 32; j++) {
    float a = b_s[j];
#pragma unroll
    for (int k = 0; k < 32; k++) a += xr[k] * ws_s[k * 32 + j];
#pragma unroll
    for (int k = 0; k < 32; k++) a += hr[k] * wn_s[k * 32 + j];
    z[32 + j] = fmaxf(a, 0.f);
  }
  float o = f2b[0];
#pragma unroll
  for (int j = 0; j < 16; j++) {
    float a = b1_s[j];
#pragma unroll
    for (int k = 0; k < 64; k++) a += z[k] * w1_s[k * 16 + j];
    o += fmaxf(a, 0.f) * w2_s[j];
  }
  out[n] = o;
}

extern "C" void kernel_launch(void* const* d_in, const int* in_sizes, int n_in,
                              void* d_out, int out_size, void* d_ws, size_t ws_size,
                              hipStream_t stream) {
  const int N = NNODES;
  const float* feat = (const float*)d_in[0];
  const int* src = (const int*)d_in[1];
  const float* g0_ws = (const float*)d_in[2];
  const float* g0_bs = (const float*)d_in[3];
  const float* g0_wd = (const float*)d_in[4];
  const float* g0_bd = (const float*)d_in[5];
  const float* g0_attn = (const float*)d_in[6];
  const float* g0_bias = (const float*)d_in[7];
  const float* l0_w = (const float*)d_in[8];
  const float* l0_b = (const float*)d_in[9];
  const float* g1_ws = (const float*)d_in[10];
  const float* g1_bs = (const float*)d_in[11];
  const float* g1_wd = (const float*)d_in[12];
  const float* g1_bd = (const float*)d_in[13];
  const float* g1_attn = (const float*)d_in[14];
  const float* g1_bias = (const float*)d_in[15];
  const float* l1_w = (const float*)d_in[16];
  const float* l1_b = (const float*)d_in[17];
  const float* g2_ws = (const float*)d_in[18];
  const float* g2_bs = (const float*)d_in[19];
  const float* g2_wd = (const float*)d_in[20];
  const float* g2_bd = (const float*)d_in[21];
  const float* g2_attn = (const float*)d_in[22];
  const float* g2_bias = (const float*)d_in[23];
  const float* l2_w = (const float*)d_in[24];
  const float* l2_b = (const float*)d_in[25];
  const float* s1_wih = (const float*)d_in[26];
  const float* s1_whh = (const float*)d_in[27];
  const float* s1_b = (const float*)d_in[28];
  const float* s1_wself = (const float*)d_in[29];
  const float* s1_wneigh = (const float*)d_in[30];
  const float* s1_bias = (const float*)d_in[31];
  const float* s2_wih = (const float*)d_in[32];
  const float* s2_whh = (const float*)d_in[33];
  const float* s2_b = (const float*)d_in[34];
  const float* s2_wself = (const float*)d_in[35];
  const float* s2_wneigh = (const float*)d_in[36];
  const float* s2_bias = (const float*)d_in[37];
  const float* f1_w = (const float*)d_in[38];
  const float* f1_b = (const float*)d_in[39];
  const float* f2_w = (const float*)d_in[40];
  const float* f2_b = (const float*)d_in[41];

  float* A = (float*)d_ws;                // N*128
  float* B = A + (size_t)N * 128;
  float* C = B + (size_t)N * 128;
  float* D = C + (size_t)N * 128;
  float* E = D + (size_t)N * 128;         // A..E = 84 MB
  short* Wp = (short*)(A + (size_t)5 * N * 128);  // packed bf16 weights, 262 KB

  // 1. startup: fc3 layer0 (A=fs[fp16], B=fd, C=lin) + repack 7 weights
  startup_kernel<<<6151, 256, 0, stream>>>(
      feat, g0_ws, g0_bs, g0_wd, g0_bd, l0_w, l0_b,
      (_Float16*)A, B, C,
      g1_ws, g1_wd, l1_w, g2_ws, g2_wd, l2_w, s2_wih, Wp);
  // 2. GAT layer 0 -> D = h1
  gat4_kernel<<<N / 4, 256, 0, stream>>>((const _Float16*)A, B, C, src,
                                         g0_attn, g0_bias, D);
  // 3. layer-1 FC trio (MFMA) -> A=fs[fp16], B, C
  mfma_fc_kernel<4, 8, 3, 1><<<N / 64, 256, 0, stream>>>(
      D, Wp + WP_G1, g1_bs, g1_bd, l1_b, A, B, C);
  // 4. GAT layer 1 -> E = h2
  gat4_kernel<<<N / 4, 256, 0, stream>>>((const _Float16*)A, B, C, src,
                                         g1_attn, g1_bias, E);
  // 5. layer-2 FC trio (MFMA) -> A,B,C  (N x 32 each, fp32)
  mfma_fc_kernel<4, 2, 3, 0><<<N / 64, 256, 0, stream>>>(
      E, Wp + WP_G2, g2_bs, g2_bd, l2_b, A, B, C);
  // 6. GAT layer 2 -> D = gat [N,32]; + fused fw1 -> E = FW1 [N,20]
  gat1_fw1_kernel<<<2048 + 128, 256, 0, stream>>>(
      A, B, C, src, g2_attn, g2_bias, D, feat, s1_wih, s1_b, E);
  // 7. SAGE-1 LSTM + projection -> C = x1 [N,32]   (R7: 256 blocks x 128)
  lstm1s_kernel<<<N / 128, 128, 0, stream>>>(E, src, s1_whh, feat, s1_wself,
                                             s1_wneigh, s1_bias, C);
  // 8. XW2 = x1 @ wih.T + b -> A as fp16 permuted [N,128]
  xw_half_kernel<<<N / 64, 256, 0, stream>>>(
      C, Wp + WP_S2WIH, s2_b, (_Float16*)A);
  // 9. SAGE-2 LSTM -> E = hn2 [N,32]
  lstm2_mfma_kernel<<<N / 64, 256, 0, stream>>>((const _Float16*)A, src, s2_whh, E);
  // 10. fused sage_out + final MLP -> out
  sage_final_kernel<<<N / 128, 128, 0, stream>>>(
      C, E, s2_wself, s2_wneigh, s2_bias, D, f1_w, f1_b, f2_w, f2_b,
      (float*)d_out);
}

// Round 9
// 370.535 us; speedup vs baseline: 1.3718x; 1.0005x over previous
//
#include <hip/hip_runtime.h>
#include <hip/hip_bf16.h>

#define NNODES 32768
#define DEG 16

// R5: fast sigmoid/tanh — v_rcp_f32 instead of IEEE div chain. ~1 ulp.
__device__ __forceinline__ float sigmoidf_(float x) {
  return __builtin_amdgcn_rcpf(1.f + __expf(-x));
}
__device__ __forceinline__ float tanhf_(float x) {
  return 1.f - 2.f * __builtin_amdgcn_rcpf(__expf(2.f * x) + 1.f);
}

typedef __attribute__((ext_vector_type(8))) short bf16x8;
typedef __attribute__((ext_vector_type(4))) float f32x4;
typedef __attribute__((ext_vector_type(8))) _Float16 f16x8;
typedef __attribute__((ext_vector_type(4))) _Float16 f16x4;
typedef __attribute__((ext_vector_type(2))) _Float16 f16x2;

__device__ __forceinline__ unsigned short f2bf_(float x) {
  __hip_bfloat16 b = __float2bfloat16(x);
  union { __hip_bfloat16 b; unsigned short u; } cv;
  cv.b = b;
  return cv.u;
}
__device__ __forceinline__ float bf2f_(unsigned short u) {
  union { unsigned short u; __hip_bfloat16 b; } cv;
  cv.u = u;
  return __bfloat162float(cv.b);
}

// R7: pack_hilo_ via gfx950 v_cvt_pk_bf16_f32. lo from exact residual.
__device__ __forceinline__ void pack_hilo_(const float* v, bf16x8& hi, bf16x8& lo) {
  union { unsigned w[4]; bf16x8 h; } uh, ul;
#pragma unroll
  for (int j = 0; j < 4; j++) {
    unsigned rh;
    asm("v_cvt_pk_bf16_f32 %0, %1, %2" : "=v"(rh) : "v"(v[2 * j]), "v"(v[2 * j + 1]));
    float h0 = __uint_as_float(rh << 16);
    float h1 = __uint_as_float(rh & 0xffff0000u);
    float r0 = v[2 * j] - h0;
    float r1 = v[2 * j + 1] - h1;
    unsigned rl;
    asm("v_cvt_pk_bf16_f32 %0, %1, %2" : "=v"(rl) : "v"(r0), "v"(r1));
    uh.w[j] = rh;
    ul.w[j] = rl;
  }
  hi = uh.h;
  lo = ul.h;
}

// Packed-weight offsets (shorts); hi block then lo block per matrix.
#define WP_G1    0        // 3 x (128x128): stride 32768
#define WP_G2    98304    // 3 x (128x32):  stride 8192
#define WP_S2WIH 122880   // 32x128 (transposed use)
#define WP_TOTAL 131072

// ---------------------------------------------------------------------------
// Startup mega-kernel (R5-exact): fc3 layer0 (fs fp16) + weight repack.
// ---------------------------------------------------------------------------
__global__ __launch_bounds__(256) void startup_kernel(
    const float* __restrict__ feat,
    const float* __restrict__ W0, const float* __restrict__ B0,
    const float* __restrict__ W1, const float* __restrict__ B1,
    const float* __restrict__ W2, const float* __restrict__ B2,
    _Float16* __restrict__ O0h, float* __restrict__ O1, float* __restrict__ O2,
    const float* __restrict__ g1ws, const float* __restrict__ g1wd,
    const float* __restrict__ l1w, const float* __restrict__ g2ws,
    const float* __restrict__ g2wd, const float* __restrict__ l2w,
    const float* __restrict__ s2wih, short* __restrict__ Wp) {
  __shared__ float w_s[5 * 64];
  __shared__ float in_s[32 * 8];
  __shared__ float b_s[64];
  const int bid = blockIdx.x;
  const int t = threadIdx.x;
  if (bid < 6144) {
    const int bz = bid >> 11, rem = bid & 2047, by = rem >> 10, bx = rem & 1023;
    const float* W = (bz == 0) ? W0 : (bz == 1) ? W1 : W2;
    const float* bias = (bz == 0) ? B0 : (bz == 1) ? B1 : B2;
    const int rowBase = bx * 32;
    const int colBase = by * 64;
    for (int idx = t; idx < 5 * 64; idx += 256) {
      int k = idx >> 6, jj = idx & 63;
      w_s[idx] = W[(size_t)k * 128 + colBase + jj];
    }
    if (t < 64) b_s[t] = bias[colBase + t];
    for (int idx = t; idx < 32 * 5; idx += 256) {
      int r = idx / 5, k = idx - r * 5;
      in_s[r * 8 + k] = feat[(size_t)(rowBase + r) * 5 + k];
    }
    __syncthreads();
    const int jj = t & 63;
    const int rslot = t >> 6;
    float acc[8];
#pragma unroll
    for (int r = 0; r < 8; r++) acc[r] = b_s[jj];
    {
      float wv0 = w_s[0 * 64 + jj], wv1 = w_s[1 * 64 + jj];
      float wv2 = w_s[2 * 64 + jj], wv3 = w_s[3 * 64 + jj];
#pragma unroll
      for (int r = 0; r < 8; r++) {
        float4 ip = *(const float4*)&in_s[(rslot * 8 + r) * 8];
        acc[r] += ip.x * wv0 + ip.y * wv1 + ip.z * wv2 + ip.w * wv3;
      }
      float wv4 = w_s[4 * 64 + jj];
#pragma unroll
      for (int r = 0; r < 8; r++) acc[r] += in_s[(rslot * 8 + r) * 8 + 4] * wv4;
    }
    if (bz == 0) {
#pragma unroll
      for (int r = 0; r < 8; r++)
        O0h[(size_t)(rowBase + rslot * 8 + r) * 128 + colBase + jj] =
            (_Float16)acc[r];
    } else {
      float* out = (bz == 1) ? O1 : O2;
#pragma unroll
      for (int r = 0; r < 8; r++)
        out[(size_t)(rowBase + rslot * 8 + r) * 128 + colBase + jj] = acc[r];
    }
  } else {
    const int mid = bid - 6144;
    const float* W;
    int FI, FO, TRANS;
    size_t base;
    if (mid == 0)      { W = g1ws;  FI = 128; FO = 128; TRANS = 0; base = WP_G1; }
    else if (mid == 1) { W = g1wd;  FI = 128; FO = 128; TRANS = 0; base = WP_G1 + 32768; }
    else if (mid == 2) { W = l1w;   FI = 128; FO = 128; TRANS = 0; base = WP_G1 + 65536; }
    else if (mid == 3) { W = g2ws;  FI = 128; FO = 32;  TRANS = 0; base = WP_G2; }
    else if (mid == 4) { W = g2wd;  FI = 128; FO = 32;  TRANS = 0; base = WP_G2 + 8192; }
    else if (mid == 5) { W = l2w;   FI = 128; FO = 32;  TRANS = 0; base = WP_G2 + 16384; }
    else               { W = s2wih; FI = 32;  FO = 128; TRANS = 1; base = WP_S2WIH; }
    const int KS = FI / 32;
    const int total = FI * FO;
    for (int p = t; p < total; p += 256) {
      int j = p & 7, lane = (p >> 3) & 63, rest = p >> 9;
      int ks = rest % KS, f = rest / KS;
      int n = lane & 15, q = lane >> 4;
      int k = 32 * ks + 8 * q + j, fo = 16 * f + n;
      float v = TRANS ? W[(size_t)fo * FI + k] : W[(size_t)k * FO + fo];
      unsigned short hi = f2bf_(v);
      float resid = v - bf2f_(hi);
      Wp[base + p] = (short)hi;
      Wp[base + total + p] = (short)f2bf_(resid);
    }
  }
}

// ---------------------------------------------------------------------------
// MFMA FC (HALF0 flag for fp16 z==0 output).
// ---------------------------------------------------------------------------
template <int KS, int FOT, int NZ, int HALF0>  // FI=32*KS, FO=16*FOT
__global__ __launch_bounds__(256) __attribute__((amdgpu_waves_per_eu(1, 4)))
void mfma_fc_kernel(const float* __restrict__ in, const short* __restrict__ Wp,
                    const float* __restrict__ B0, const float* __restrict__ B1,
                    const float* __restrict__ B2, float* __restrict__ O0,
                    float* __restrict__ O1, float* __restrict__ O2) {
  constexpr int FI = 32 * KS;
  constexpr int FO = 16 * FOT;
  const int tid = threadIdx.x;
  const int wid = tid >> 6;
  const int lane = tid & 63;
  const int q = lane >> 4, n = lane & 15;
  const int n0 = blockIdx.x * 64 + wid * 16;
  bf16x8 Ahi[KS], Alo[KS];
#pragma unroll
  for (int ks = 0; ks < KS; ks++) {
    float av[8];
    *(float4*)&av[0] = *(const float4*)&in[(size_t)(n0 + n) * FI + 32 * ks + 8 * q];
    *(float4*)&av[4] = *(const float4*)&in[(size_t)(n0 + n) * FI + 32 * ks + 8 * q + 4];
    pack_hilo_(av, Ahi[ks], Alo[ks]);
  }
#pragma unroll
  for (int z = 0; z < NZ; z++) {
    const short* wz = Wp + (size_t)z * FI * FO * 2;
    const float* bz = (z == 0) ? B0 : (z == 1) ? B1 : B2;
    float* oz = (z == 0) ? O0 : (z == 1) ? O1 : O2;
#pragma unroll
    for (int f = 0; f < FOT; f++) {
      float bv = bz[16 * f + n];
      f32x4 acc = {bv, bv, bv, bv};
#pragma unroll
      for (int ks = 0; ks < KS; ks++) {
        bf16x8 Bhi = *(const bf16x8*)&wz[((size_t)(f * KS + ks) * 64 + lane) * 8];
        bf16x8 Blo = *(const bf16x8*)&wz[(size_t)FI * FO + ((size_t)(f * KS + ks) * 64 + lane) * 8];
        acc = __builtin_amdgcn_mfma_f32_16x16x32_bf16(Ahi[ks], Bhi, acc, 0, 0, 0);
        acc = __builtin_amdgcn_mfma_f32_16x16x32_bf16(Alo[ks], Bhi, acc, 0, 0, 0);
        acc = __builtin_amdgcn_mfma_f32_16x16x32_bf16(Ahi[ks], Blo, acc, 0, 0, 0);
      }
      if (HALF0 && z == 0) {
#pragma unroll
        for (int r = 0; r < 4; r++)
          ((_Float16*)O0)[(size_t)(n0 + 4 * q + r) * FO + 16 * f + n] =
              (_Float16)acc[r];
      } else {
#pragma unroll
        for (int r = 0; r < 4; r++)
          oz[(size_t)(n0 + 4 * q + r) * FO + 16 * f + n] = acc[r];
      }
    }
  }
}

// ---------------------------------------------------------------------------
// XW writer (R4-exact structure): fp16 permuted XW.
// ---------------------------------------------------------------------------
__global__ __launch_bounds__(256) __attribute__((amdgpu_waves_per_eu(1, 4)))
void xw_half_kernel(const float* __restrict__ in, const short* __restrict__ Wp,
                    const float* __restrict__ bz, _Float16* __restrict__ XWh) {
  const int tid = threadIdx.x;
  const int wid = tid >> 6;
  const int lane = tid & 63;
  const int q = lane >> 4, n = lane & 15;
  const int n0 = blockIdx.x * 64 + wid * 16;
  bf16x8 Ahi, Alo;
  {
    float av[8];
    *(float4*)&av[0] = *(const float4*)&in[(size_t)(n0 + n) * 32 + 8 * q];
    *(float4*)&av[4] = *(const float4*)&in[(size_t)(n0 + n) * 32 + 8 * q + 4];
    pack_hilo_(av, Ahi, Alo);
  }
#pragma unroll
  for (int f = 0; f < 8; f++) {
    float bv = bz[16 * f + n];
    f32x4 acc = {bv, bv, bv, bv};
    bf16x8 Bhi = *(const bf16x8*)&Wp[((size_t)f * 64 + lane) * 8];
    bf16x8 Blo = *(const bf16x8*)&Wp[4096 + ((size_t)f * 64 + lane) * 8];
    acc = __builtin_amdgcn_mfma_f32_16x16x32_bf16(Ahi, Bhi, acc, 0, 0, 0);
    acc = __builtin_amdgcn_mfma_f32_16x16x32_bf16(Alo, Bhi, acc, 0, 0, 0);
    acc = __builtin_amdgcn_mfma_f32_16x16x32_bf16(Ahi, Blo, acc, 0, 0, 0);
    // gate dim g = 16*f + n; perm(g) = (n>>2)*32 + f*4 + (n&3)
#pragma unroll
    for (int r = 0; r < 4; r++)
      XWh[(size_t)(n0 + 4 * q + r) * 128 + ((n >> 2) * 32 + f * 4 + (n & 3))] =
          (_Float16)acc[r];
  }
}

// ---------------------------------------------------------------------------
// GATv2 H=4 (R6-exact: up-front 16-deep gather + two-pass softmax).
// ---------------------------------------------------------------------------
__global__ __launch_bounds__(256) void gat4_kernel(const _Float16* __restrict__ fs,
                                                   const float* __restrict__ fd,
                                                   const float* __restrict__ lin,
                                                   const int* __restrict__ src,
                                                   const float* __restrict__ attn,
                                                   const float* __restrict__ bias,
                                                   float* __restrict__ out) {
  constexpr int F = 128;
  const int lane = threadIdx.x & 63;
  const int wave = threadIdx.x >> 6;
  const int li = lane & 15;
  const int node = blockIdx.x * 4 + wave;
  const int f0 = 2 * lane;
  const int srcv = src[(size_t)node * DEG + li];
  const float2 fdv = *(const float2*)&fd[(size_t)node * F + f0];
  const float a0 = attn[f0];
  const float a1 = attn[f0 + 1];
  f16x2 curh[DEG];
#pragma unroll
  for (int d = 0; d < DEG; d++) {
    int sn = __shfl(srcv, (lane & 48) | d, 64);
    curh[d] = *(const f16x2*)&fs[(size_t)sn * F + f0];
  }
  float p[DEG];
  float m = -1e30f;
#pragma unroll
  for (int d = 0; d < DEG; d++) {
    float c0 = (float)curh[d][0], c1 = (float)curh[d][1];
    float e0 = c0 + fdv.x; e0 = (e0 > 0.f) ? e0 : 0.2f * e0;
    float e1 = c1 + fdv.y; e1 = (e1 > 0.f) ? e1 : 0.2f * e1;
    float pp = e0 * a0 + e1 * a1;
    pp += __shfl_xor(pp, 1, 64);
    pp += __shfl_xor(pp, 2, 64);
    pp += __shfl_xor(pp, 4, 64);
    pp += __shfl_xor(pp, 8, 64);
    p[d] = pp;
    m = fmaxf(m, pp);
  }
  float s = 0.f, acc0 = 0.f, acc1 = 0.f;
#pragma unroll
  for (int d = 0; d < DEG; d++) {
    float ex = __expf(p[d] - m);
    s += ex;
    acc0 += ex * (float)curh[d][0];
    acc1 += ex * (float)curh[d][1];
  }
  float inv = 1.f / s;
  float2 lv = *(const float2*)&lin[(size_t)node * F + f0];
  float o0 = acc0 * inv + lv.x + bias[f0];
  float o1 = acc1 * inv + lv.y + bias[f0 + 1];
  o0 = (o0 > 0.f) ? o0 : __expf(o0) - 1.f;
  o1 = (o1 > 0.f) ? o1 : __expf(o1) - 1.f;
  *(float2*)&out[(size_t)node * F + f0] = make_float2(o0, o1);
}

// ---------------------------------------------------------------------------
// GATv2 H=1 (no ELU) + fused fw1 — R8: fs gathered as fp16 [N,32] (64 B
// rows -> one 64B txn per row-gather, was two with fp32); fw1 output FW1
// stored fp16 with row stride 32 halves (64 B, line-aligned).
// ---------------------------------------------------------------------------
__global__ __launch_bounds__(256) void gat1_fw1_kernel(
    const _Float16* __restrict__ fs, const float* __restrict__ fd,
    const float* __restrict__ lin, const int* __restrict__ src,
    const float* __restrict__ attn, const float* __restrict__ bias,
    float* __restrict__ out, const float* __restrict__ feat,
    const float* __restrict__ wih, const float* __restrict__ wb,
    _Float16* __restrict__ fwout) {
  __shared__ float w_s[100];
  __shared__ float b_s[20];
  if (blockIdx.x < 2048) {
    constexpr int F = 32;
    const int lane = threadIdx.x & 63;
    const int wave = threadIdx.x >> 6;
    const int G = lane >> 4, li = lane & 15;
    const int node = blockIdx.x * 16 + wave * 4 + G;
    const int f0 = 2 * li;
    const int srcv = src[(size_t)node * DEG + li];
    const float2 fdv = *(const float2*)&fd[(size_t)node * F + f0];
    const float a0 = attn[f0];
    const float a1 = attn[f0 + 1];
    f16x2 cur[DEG];
#pragma unroll
    for (int d = 0; d < DEG; d++) {
      int sn = __shfl(srcv, (lane & 48) | d, 64);
      cur[d] = *(const f16x2*)&fs[(size_t)sn * F + f0];
    }
    float p[DEG];
    float m = -1e30f;
#pragma unroll
    for (int d = 0; d < DEG; d++) {
      float e0 = (float)cur[d][0] + fdv.x; e0 = (e0 > 0.f) ? e0 : 0.2f * e0;
      float e1 = (float)cur[d][1] + fdv.y; e1 = (e1 > 0.f) ? e1 : 0.2f * e1;
      float pp = e0 * a0 + e1 * a1;
      pp += __shfl_xor(pp, 1, 64);
      pp += __shfl_xor(pp, 2, 64);
      pp += __shfl_xor(pp, 4, 64);
      pp += __shfl_xor(pp, 8, 64);
      p[d] = pp;
      m = fmaxf(m, pp);
    }
    float s = 0.f, acc0 = 0.f, acc1 = 0.f;
#pragma unroll
    for (int d = 0; d < DEG; d++) {
      float ex = __expf(p[d] - m);
      s += ex;
      acc0 += ex * (float)cur[d][0];
      acc1 += ex * (float)cur[d][1];
    }
    float inv = 1.f / s;
    float2 lv = *(const float2*)&lin[(size_t)node * F + f0];
    float o0 = acc0 * inv + lv.x + bias[f0];
    float o1 = acc1 * inv + lv.y + bias[f0 + 1];
    *(float2*)&out[(size_t)node * F + f0] = make_float2(o0, o1);
  } else {
    if (threadIdx.x < 100) w_s[threadIdx.x] = wih[threadIdx.x];
    if (threadIdx.x < 20) b_s[threadIdx.x] = wb[threadIdx.x];
    __syncthreads();
    const int n = (blockIdx.x - 2048) * 256 + threadIdx.x;
    float f[5];
#pragma unroll
    for (int k = 0; k < 5; k++) f[k] = feat[(size_t)n * 5 + k];
#pragma unroll
    for (int j = 0; j < 20; j++) {
      float a = b_s[j];
#pragma unroll
      for (int k = 0; k < 5; k++) a += f[k] * w_s[j * 5 + k];
      fwout[(size_t)n * 32 + j] = (_Float16)a;
    }
  }
}

// ---------------------------------------------------------------------------
// SAGE-1: LSTM + fused projection — R8: FW gathered as fp16, row stride 32
// halves (64 B line-aligned rows -> 1 txn/row, was ~2.2 with fp32-80B).
// Gate math fp32 (FW rounds through fp16 — same class as XW-fp16, R4).
// ---------------------------------------------------------------------------
__global__ __attribute__((amdgpu_waves_per_eu(1, 4))) __launch_bounds__(128)
void lstm1s_kernel(const _Float16* __restrict__ FW, const int* __restrict__ src,
                   const float* __restrict__ whh, const float* __restrict__ feat,
                   const float* __restrict__ wself, const float* __restrict__ wneigh,
                   const float* __restrict__ bias, float* __restrict__ x1out) {
  __shared__ float w_s[100];   // whh [20][5]
  __shared__ float ws_s[160];  // wself [5][32]
  __shared__ float wn_s[160];  // wneigh [5][32]
  __shared__ float b_s[32];
  if (threadIdx.x < 100) w_s[threadIdx.x] = whh[threadIdx.x];
  for (int i = threadIdx.x; i < 160; i += 128) {
    ws_s[i] = wself[i];
    wn_s[i] = wneigh[i];
  }
  if (threadIdx.x < 32) b_s[threadIdx.x] = bias[threadIdx.x];
  __syncthreads();
  const int n = blockIdx.x * 128 + threadIdx.x;
  const int* sp = src + (size_t)n * DEG;
  float f[5];
#pragma unroll
  for (int k = 0; k < 5; k++) f[k] = feat[(size_t)n * 5 + k];
  float h[5] = {0, 0, 0, 0, 0}, c[5] = {0, 0, 0, 0, 0};
  int sd = sp[0];
  f16x8 q0 = *(const f16x8*)&FW[(size_t)sd * 32 + 0];
  f16x8 q1 = *(const f16x8*)&FW[(size_t)sd * 32 + 8];
  f16x4 q2 = *(const f16x4*)&FW[(size_t)sd * 32 + 16];
  for (int d = 0; d < DEG; d++) {
    float g[20];
#pragma unroll
    for (int j = 0; j < 8; j++) {
      g[j] = (float)q0[j];
      g[8 + j] = (float)q1[j];
    }
#pragma unroll
    for (int j = 0; j < 4; j++) g[16 + j] = (float)q2[j];
    if (d < DEG - 1) {
      int sn = sp[d + 1];
      q0 = *(const f16x8*)&FW[(size_t)sn * 32 + 0];
      q1 = *(const f16x8*)&FW[(size_t)sn * 32 + 8];
      q2 = *(const f16x4*)&FW[(size_t)sn * 32 + 16];
    }
#pragma unroll
    for (int j = 0; j < 20; j++) {
#pragma unroll
      for (int k = 0; k < 5; k++) g[j] += h[k] * w_s[j * 5 + k];
    }
#pragma unroll
    for (int k = 0; k < 5; k++) {
      float iv = sigmoidf_(g[k]);
      float fv = sigmoidf_(g[5 + k]);
      float gv = tanhf_(g[10 + k]);
      float ov = sigmoidf_(g[15 + k]);
      c[k] = fv * c[k] + iv * gv;
      h[k] = ov * tanhf_(c[k]);
    }
  }
#pragma unroll
  for (int j = 0; j < 32; j++) {
    float a = b_s[j];
#pragma unroll
    for (int k = 0; k < 5; k++) a += f[k] * ws_s[k * 32 + j] + h[k] * wn_s[k * 32 + j];
    x1out[(size_t)n * 32 + j] = fmaxf(a, 0.f);
  }
}

// ---------------------------------------------------------------------------
// SAGE-2 LSTM (MFMA) — R7-exact.
// ---------------------------------------------------------------------------
__global__ __launch_bounds__(256) __attribute__((amdgpu_waves_per_eu(1, 4)))
void lstm2_mfma_kernel(const _Float16* __restrict__ XW, const int* __restrict__ src,
                       const float* __restrict__ whh, float* __restrict__ hn_out) {
  __shared__ float h_lds_all[4 * 16 * 36];
  __shared__ int src_lds_all[4 * 256];
  const int tid = threadIdx.x;
  const int wid = tid >> 6;
  const int lane = tid & 63;
  const int q = lane >> 4;   // quad
  const int n = lane & 15;   // node within group / fragment col
  const int n0 = (blockIdx.x * 4 + wid) * 16;
  float* h_lds = &h_lds_all[wid * 16 * 36];
  int* src_lds = &src_lds_all[wid * 256];

  {
    int4 sv = *(const int4*)&src[(size_t)(n0 + (lane >> 2)) * DEG + 4 * (lane & 3)];
    src_lds[(4 * (lane & 3) + 0) * 16 + (lane >> 2)] = sv.x;
    src_lds[(4 * (lane & 3) + 1) * 16 + (lane >> 2)] = sv.y;
    src_lds[(4 * (lane & 3) + 2) * 16 + (lane >> 2)] = sv.z;
    src_lds[(4 * (lane & 3) + 3) * 16 + (lane >> 2)] = sv.w;
  }

  bf16x8 Whi[8], Wlo[8];
#pragma unroll
  for (int gt = 0; gt < 8; gt++) {
    float wv[8];
    *(float4*)&wv[0] = *(const float4*)&whh[(size_t)(16 * gt + n) * 32 + 8 * q];
    *(float4*)&wv[4] = *(const float4*)&whh[(size_t)(16 * gt + n) * 32 + 8 * q + 4];
    pack_hilo_(wv, Whi[gt], Wlo[gt]);
  }

  bf16x8 Bhi, Blo;
#pragma unroll
  for (int j = 0; j < 8; j++) { Bhi[j] = 0; Blo[j] = 0; }
  float cst[8];
#pragma unroll
  for (int i = 0; i < 8; i++) cst[i] = 0.f;

  f16x8 tch[4], tnh[4];
  {
    int s0 = src_lds[0 * 16 + n];
    const _Float16* gb = XW + (size_t)s0 * 128 + q * 32;
#pragma unroll
    for (int t = 0; t < 4; t++) tch[t] = *(const f16x8*)&gb[8 * t];
  }

  float hv[8];
#pragma unroll
  for (int d = 0; d < DEG; d++) {
    f32x4 D[4][2];
#pragma unroll
    for (int p = 0; p < 4; p++) {
#pragma unroll
      for (int hh = 0; hh < 2; hh++) {
        int gt = p * 2 + hh;
        f32x4 acc = {0.f, 0.f, 0.f, 0.f};
        acc = __builtin_amdgcn_mfma_f32_16x16x32_bf16(Whi[gt], Bhi, acc, 0, 0, 0);
        acc = __builtin_amdgcn_mfma_f32_16x16x32_bf16(Wlo[gt], Bhi, acc, 0, 0, 0);
        acc = __builtin_amdgcn_mfma_f32_16x16x32_bf16(Whi[gt], Blo, acc, 0, 0, 0);
        D[p][hh] = acc;
      }
    }
    if (d < DEG - 1) {
      int s = src_lds[(d + 1) * 16 + n];
      const _Float16* gb = XW + (size_t)s * 128 + q * 32;
#pragma unroll
      for (int t = 0; t < 4; t++) tnh[t] = *(const f16x8*)&gb[8 * t];
    }
#pragma unroll
    for (int hh = 0; hh < 2; hh++) {
#pragma unroll
      for (int r = 0; r < 4; r++) {
        int ci = hh * 4 + r;
        float xiv = (float)tch[0][hh * 4 + r];
        float xfv = (float)tch[1][hh * 4 + r];
        float xgv = (float)tch[2][hh * 4 + r];
        float xov = (float)tch[3][hh * 4 + r];
        float iv = sigmoidf_(D[0][hh][r] + xiv);
        float fv = sigmoidf_(D[1][hh][r] + xfv);
        float gv = tanhf_(D[2][hh][r] + xgv);
        float ov = sigmoidf_(D[3][hh][r] + xov);
        cst[ci] = fv * cst[ci] + iv * gv;
        hv[ci] = ov * tanhf_(cst[ci]);
      }
    }
    if (d < DEG - 1) {
      *(float4*)&h_lds[n * 36 + 0 + 4 * q] = make_float4(hv[0], hv[1], hv[2], hv[3]);
      *(float4*)&h_lds[n * 36 + 16 + 4 * q] = make_float4(hv[4], hv[5], hv[6], hv[7]);
      float hb[8];
      *(float4*)&hb[0] = *(const float4*)&h_lds[n * 36 + 8 * q];
      *(float4*)&hb[4] = *(const float4*)&h_lds[n * 36 + 8 * q + 4];
      pack_hilo_(hb, Bhi, Blo);
#pragma unroll
      for (int t = 0; t < 4; t++) tch[t] = tnh[t];
    }
  }
  *(float4*)&hn_out[(size_t)(n0 + n) * 32 + 0 + 4 * q] = make_float4(hv[0], hv[1], hv[2], hv[3]);
  *(float4*)&hn_out[(size_t)(n0 + n) * 32 + 16 + 4 * q] = make_float4(hv[4], hv[5], hv[6], hv[7]);
}

// ---------------------------------------------------------------------------
// Fused sage_out + final MLP (R4-exact).
// ---------------------------------------------------------------------------
__global__ __launch_bounds__(128) void sage_final_kernel(
    const float* __restrict__ x1, const float* __restrict__ hn,
    const float* __restrict__ wself, const float* __restrict__ wneigh,
    const float* __restrict__ sbias, const float* __restrict__ gat,
    const float* __restrict__ f1w, const float* __restrict__ f1b,
    const float* __restrict__ f2w, const float* __restrict__ f2b,
    float* __restrict__ out) {
  __shared__ float ws_s[32 * 32];
  __shared__ float wn_s[32 * 32];
  __shared__ float b_s[32];
  __shared__ float w1_s[64 * 16];
  __shared__ float b1_s[16];
  __shared__ float w2_s[16];
  for (int idx = threadIdx.x; idx < 1024; idx += 128) {
    ws_s[idx] = wself[idx];
    wn_s[idx] = wneigh[idx];
    w1_s[idx] = f1w[idx];
  }
  if (threadIdx.x < 32) b_s[threadIdx.x] = sbias[threadIdx.x];
  if (threadIdx.x < 16) {
    b1_s[threadIdx.x] = f1b[threadIdx.x];
    w2_s[threadIdx.x] = f2w[threadIdx.x];
  }
  __syncthreads();
  const int n = blockIdx.x * 128 + threadIdx.x;
  float xr[32], hr[32], z[64];
#pragma unroll
  for (int k = 0; k < 32; k += 4) {
    *(float4*)&xr[k] = *(const float4*)&x1[(size_t)n * 32 + k];
    *(float4*)&hr[k] = *(const float4*)&hn[(size_t)n * 32 + k];
    float4 a = *(const float4*)&gat[(size_t)n * 32 + k];
    z[k] = a.x; z[k + 1] = a.y; z[k + 2] = a.z; z[k + 3] = a.w;
  }
#pragma unroll
  for (int j = 0; j < 32; j++) {
    float a = b_s[j];
#pragma unroll
    for (int k = 0; k < 32; k++) a += xr[k] * ws_s[k * 32 + j];
#pragma unroll
    for (int k = 0; k < 32; k++) a += hr[k] * wn_s[k * 32 + j];
    z[32 + j] = fmaxf(a, 0.f);
  }
  float o = f2b[0];
#pragma unroll
  for (int j = 0; j < 16; j++) {
    float a = b1_s[j];
#pragma unroll
    for (int k = 0; k < 64; k++) a += z[k] * w1_s[k * 16 + j];
    o += fmaxf(a, 0.f) * w2_s[j];
  }
  out[n] = o;
}

extern "C" void kernel_launch(void* const* d_in, const int* in_sizes, int n_in,
                              void* d_out, int out_size, void* d_ws, size_t ws_size,
                              hipStream_t stream) {
  const int N = NNODES;
  const float* feat = (const float*)d_in[0];
  const int* src = (const int*)d_in[1];
  const float* g0_ws = (const float*)d_in[2];
  const float* g0_bs = (const float*)d_in[3];
  const float* g0_wd = (const float*)d_in[4];
  const float* g0_bd = (const float*)d_in[5];
  const float* g0_attn = (const float*)d_in[6];
  const float* g0_bias = (const float*)d_in[7];
  const float* l0_w = (const float*)d_in[8];
  const float* l0_b = (const float*)d_in[9];
  const float* g1_ws = (const float*)d_in[10];
  const float* g1_bs = (const float*)d_in[11];
  const float* g1_wd = (const float*)d_in[12];
  const float* g1_bd = (const float*)d_in[13];
  const float* g1_attn = (const float*)d_in[14];
  const float* g1_bias = (const float*)d_in[15];
  const float* l1_w = (const float*)d_in[16];
  const float* l1_b = (const float*)d_in[17];
  const float* g2_ws = (const float*)d_in[18];
  const float* g2_bs = (const float*)d_in[19];
  const float* g2_wd = (const float*)d_in[20];
  const float* g2_bd = (const float*)d_in[21];
  const float* g2_attn = (const float*)d_in[22];
  const float* g2_bias = (const float*)d_in[23];
  const float* l2_w = (const float*)d_in[24];
  const float* l2_b = (const float*)d_in[25];
  const float* s1_wih = (const float*)d_in[26];
  const float* s1_whh = (const float*)d_in[27];
  const float* s1_b = (const float*)d_in[28];
  const float* s1_wself = (const float*)d_in[29];
  const float* s1_wneigh = (const float*)d_in[30];
  const float* s1_bias = (const float*)d_in[31];
  const float* s2_wih = (const float*)d_in[32];
  const float* s2_whh = (const float*)d_in[33];
  const float* s2_b = (const float*)d_in[34];
  const float* s2_wself = (const float*)d_in[35];
  const float* s2_wneigh = (const float*)d_in[36];
  const float* s2_bias = (const float*)d_in[37];
  const float* f1_w = (const float*)d_in[38];
  const float* f1_b = (const float*)d_in[39];
  const float* f2_w = (const float*)d_in[40];
  const float* f2_b = (const float*)d_in[41];

  float* A = (float*)d_ws;                // N*128
  float* B = A + (size_t)N * 128;
  float* C = B + (size_t)N * 128;
  float* D = C + (size_t)N * 128;
  float* E = D + (size_t)N * 128;         // A..E = 84 MB
  short* Wp = (short*)(A + (size_t)5 * N * 128);  // packed bf16 weights, 262 KB

  // 1. startup: fc3 layer0 (A=fs[fp16], B=fd, C=lin) + repack 7 weights
  startup_kernel<<<6151, 256, 0, stream>>>(
      feat, g0_ws, g0_bs, g0_wd, g0_bd, l0_w, l0_b,
      (_Float16*)A, B, C,
      g1_ws, g1_wd, l1_w, g2_ws, g2_wd, l2_w, s2_wih, Wp);
  // 2. GAT layer 0 -> D = h1
  gat4_kernel<<<N / 4, 256, 0, stream>>>((const _Float16*)A, B, C, src,
                                         g0_attn, g0_bias, D);
  // 3. layer-1 FC trio (MFMA) -> A=fs[fp16], B, C
  mfma_fc_kernel<4, 8, 3, 1><<<N / 64, 256, 0, stream>>>(
      D, Wp + WP_G1, g1_bs, g1_bd, l1_b, A, B, C);
  // 4. GAT layer 1 -> E = h2
  gat4_kernel<<<N / 4, 256, 0, stream>>>((const _Float16*)A, B, C, src,
                                         g1_attn, g1_bias, E);
  // 5. layer-2 FC trio (MFMA) -> A=fs[fp16, N x 32], B, C (fp32)
  mfma_fc_kernel<4, 2, 3, 1><<<N / 64, 256, 0, stream>>>(
      E, Wp + WP_G2, g2_bs, g2_bd, l2_b, A, B, C);
  // 6. GAT layer 2 (fp16 fs) -> D = gat [N,32]; fw1 -> E = FW1 [N,32] fp16
  gat1_fw1_kernel<<<2048 + 128, 256, 0, stream>>>(
      (const _Float16*)A, B, C, src, g2_attn, g2_bias, D, feat, s1_wih, s1_b,
      (_Float16*)E);
  // 7. SAGE-1 LSTM + projection (fp16 FW gather) -> C = x1 [N,32]
  lstm1s_kernel<<<N / 128, 128, 0, stream>>>((const _Float16*)E, src, s1_whh,
                                             feat, s1_wself, s1_wneigh,
                                             s1_bias, C);
  // 8. XW2 = x1 @ wih.T + b -> A as fp16 permuted [N,128]
  xw_half_kernel<<<N / 64, 256, 0, stream>>>(
      C, Wp + WP_S2WIH, s2_b, (_Float16*)A);
  // 9. SAGE-2 LSTM -> E = hn2 [N,32]
  lstm2_mfma_kernel<<<N / 64, 256, 0, stream>>>((const _Float16*)A, src, s2_whh, E);
  // 10. fused sage_out + final MLP -> out
  sage_final_kernel<<<N / 128, 128, 0, stream>>>(
      C, E, s2_wself, s2_wneigh, s2_bias, D, f1_w, f1_b, f2_w, f2_b,
      (float*)d_out);
}